// Round 1
// baseline (2752.947 us; speedup 1.0000x reference)
//
#include <hip/hip_runtime.h>
#include <math.h>

#define NSP 32768   // H*W*D = 32*32*32
#define NCH 64

// ---------------------------------------------------------------------------
// K1: xv = transpose(x) ; U = gelu(proj1_w @ xv + b)   (U layout: [C][N])
// block: 256 thr, handles 64 positions; stages x tile in LDS.
__global__ __launch_bounds__(256) void k_proj1(const float* __restrict__ x,
        const float* __restrict__ w, const float* __restrict__ b,
        float* __restrict__ U) {
    __shared__ float xs[64 * 65];
    int t = threadIdx.x;
    int n0 = blockIdx.x * 64;
    for (int i = 0; i < 16; ++i) {
        int idx = i * 256 + t;
        int p = idx >> 6, c = idx & 63;
        xs[p * 65 + c] = x[(size_t)(n0 + p) * 64 + c];
    }
    __syncthreads();
    int l = t & 63;        // position lane
    int q = t >> 6;        // output-channel quarter
    for (int oi = 0; oi < 16; ++oi) {
        int o = q * 16 + oi;
        float acc = b[o];
        const float* wr = w + o * 64;
        #pragma unroll
        for (int c = 0; c < 64; ++c) acc += wr[c] * xs[l * 65 + c];
        float g = 0.5f * acc * (1.0f + erff(acc * 0.70710678118654752f));
        U[(size_t)o * NSP + n0 + l] = g;
    }
}

// ---------------------------------------------------------------------------
// K2: depthwise 5x5x5, pad 2.  in/out layout [C][N]
__global__ __launch_bounds__(256) void k_dw5(const float* __restrict__ in,
        const float* __restrict__ w, const float* __restrict__ b,
        float* __restrict__ out) {
    int tid = blockIdx.x * 256 + threadIdx.x;   // 64*32768 threads
    int c = tid >> 15, n = tid & 32767;
    int h = n >> 10, ww = (n >> 5) & 31, d = n & 31;
    const float* src = in + (size_t)c * NSP;
    const float* wc = w + c * 125;
    float acc = b[c];
    #pragma unroll
    for (int i = 0; i < 5; ++i) {
        int hh = h + i - 2;
        if ((unsigned)hh >= 32u) continue;
        #pragma unroll
        for (int j = 0; j < 5; ++j) {
            int wj = ww + j - 2;
            if ((unsigned)wj >= 32u) continue;
            const float* row = src + (hh << 10) + (wj << 5);
            const float* wr = wc + i * 25 + j * 5;
            #pragma unroll
            for (int l = 0; l < 5; ++l) {
                int dd = d + l - 2;
                if ((unsigned)dd >= 32u) continue;
                acc += wr[l] * row[dd];
            }
        }
    }
    out[tid] = acc;
}

// ---------------------------------------------------------------------------
// K3: depthwise 7x7x7, dilation 3, pad 9.  in/out layout [C][N]
__global__ __launch_bounds__(256) void k_dw7(const float* __restrict__ in,
        const float* __restrict__ w, const float* __restrict__ b,
        float* __restrict__ out) {
    int tid = blockIdx.x * 256 + threadIdx.x;
    int c = tid >> 15, n = tid & 32767;
    int h = n >> 10, ww = (n >> 5) & 31, d = n & 31;
    const float* src = in + (size_t)c * NSP;
    const float* wc = w + c * 343;
    float acc = b[c];
    for (int i = 0; i < 7; ++i) {
        int hh = h + 3 * i - 9;
        if ((unsigned)hh >= 32u) continue;
        for (int j = 0; j < 7; ++j) {
            int wj = ww + 3 * j - 9;
            if ((unsigned)wj >= 32u) continue;
            const float* row = src + (hh << 10) + (wj << 5);
            const float* wr = wc + i * 49 + j * 7;
            #pragma unroll
            for (int l = 0; l < 7; ++l) {
                int dd = d + 3 * l - 9;
                if ((unsigned)dd >= 32u) continue;
                acc += wr[l] * row[dd];
            }
        }
    }
    out[tid] = acc;
}

// ---------------------------------------------------------------------------
// K4: transpose [C][N] -> [N][C]  (LDS-tiled, both sides coalesced)
__global__ __launch_bounds__(256) void k_tr(const float* __restrict__ in,
        float* __restrict__ out) {
    __shared__ float tile[64 * 65];
    int t = threadIdx.x;
    int n0 = blockIdx.x * 64;
    for (int i = 0; i < 16; ++i) {
        int idx = i * 256 + t;
        int c = idx >> 6, nl = idx & 63;
        tile[c * 65 + nl] = in[(size_t)c * NSP + n0 + nl];
    }
    __syncthreads();
    for (int i = 0; i < 16; ++i) {
        int idx = i * 256 + t;
        int nl = idx >> 6, c = idx & 63;
        out[(size_t)(n0 + nl) * 64 + c] = tile[c * 65 + nl];
    }
}

// ---------------------------------------------------------------------------
// K5: offset conv 3x3x3, 64 -> 81 channels.  in [C][N], out [81][N]
__global__ __launch_bounds__(256) void k_off(const float* __restrict__ in,
        const float* __restrict__ ow, const float* __restrict__ ob,
        float* __restrict__ off) {
    int tid = blockIdx.x * 256 + threadIdx.x;   // 81*32768 threads
    int ko = tid >> 15, n = tid & 32767;
    int h = n >> 10, ww = (n >> 5) & 31, d = n & 31;
    int nn[27];
    float mk[27];
    #pragma unroll
    for (int k = 0; k < 27; ++k) {
        int kh = k / 9 - 1, kw = (k / 3) % 3 - 1, kd = k % 3 - 1;
        int hh = h + kh, wj = ww + kw, dd = d + kd;
        bool ok = ((unsigned)hh < 32u) & ((unsigned)wj < 32u) & ((unsigned)dd < 32u);
        nn[k] = ok ? (hh << 10) + (wj << 5) + dd : 0;
        mk[k] = ok ? 1.0f : 0.0f;
    }
    float acc = ob[ko];
    const float* wb = ow + (size_t)ko * 1728;
    for (int c = 0; c < 64; ++c) {
        const float* tc = in + (size_t)c * NSP;
        const float* wc = wb + c * 27;
        float s = 0.f;
        #pragma unroll
        for (int k = 0; k < 27; ++k) s += wc[k] * (mk[k] * tc[nn[k]]);
        acc += s;
    }
    off[tid] = acc;
}

// ---------------------------------------------------------------------------
// K6: deformable gather + 27-tap GEMM.
//  aT: [N][C] (position-major, for coalesced channel gathers)
//  off: [81][N];  dw: [O=64][C=64][K=27];  out DCN: [C][N]
//  Block: 256 thr, 8 positions.  Phase B: trilinear sample -> LDS S[p][c*27+k]
//  Phase C: per-thread (o, 2 positions) dot over 1728.
__global__ __launch_bounds__(256) void k_deform(const float* __restrict__ aT,
        const float* __restrict__ off, const float* __restrict__ dw,
        const float* __restrict__ db, float* __restrict__ dcn) {
    __shared__ float S[8][1728];
    int t = threadIdx.x;
    int n0 = blockIdx.x * 8;
    int lane = t & 63, wv = t >> 6;
    for (int j = wv; j < 216; j += 4) {         // 8 pos * 27 taps
        int p = j / 27, k = j % 27;
        int n = n0 + p;
        int h = n >> 10, w = (n >> 5) & 31, d = n & 31;
        float ph = (float)(h + k / 9 - 1)       + off[(size_t)(k * 3 + 0) * NSP + n];
        float pw = (float)(w + (k / 3) % 3 - 1) + off[(size_t)(k * 3 + 1) * NSP + n];
        float pd = (float)(d + k % 3 - 1)       + off[(size_t)(k * 3 + 2) * NSP + n];
        float fh = floorf(ph), fw = floorf(pw), fd = floorf(pd);
        int ih = (int)fh, iw = (int)fw, id = (int)fd;
        float rh = ph - fh, rw = pw - fw, rd = pd - fd;
        float acc = 0.f;
        #pragma unroll
        for (int cb = 0; cb < 8; ++cb) {
            int hh = ih + ((cb >> 2) & 1);
            int wq = iw + ((cb >> 1) & 1);
            int dq = id + (cb & 1);
            float wg = ((cb & 4) ? rh : 1.f - rh) * ((cb & 2) ? rw : 1.f - rw)
                     * ((cb & 1) ? rd : 1.f - rd);
            bool ok = ((unsigned)hh < 32u) & ((unsigned)wq < 32u) & ((unsigned)dq < 32u);
            int fl = ok ? ((hh << 5) + wq) * 32 + dq : 0;
            float v = aT[(size_t)fl * 64 + lane];   // coalesced across lanes
            acc += (ok ? wg : 0.f) * v;
        }
        S[p][lane * 27 + k] = acc;                  // 27 coprime 32: conflict-free
    }
    __syncthreads();
    int o = lane, pg = wv;
    const float* wo = dw + (size_t)o * 1728;
    int p0 = pg * 2, p1 = p0 + 1;
    float a0 = 0.f, a1 = 0.f;
    for (int ck = 0; ck < 1728; ++ck) {
        float wv2 = wo[ck];
        a0 += wv2 * S[p0][ck];                      // broadcast LDS reads
        a1 += wv2 * S[p1][ck];
    }
    float bb = db[o];
    dcn[(size_t)o * NSP + n0 + p0] = a0 + bb;
    dcn[(size_t)o * NSP + n0 + p1] = a1 + bb;
}

// ---------------------------------------------------------------------------
// K7: a2 = conv1_w @ dcn + b ; h = U * a2 ; out = proj2_w @ h + b2 + x  (-> [N][C])
__global__ __launch_bounds__(256) void k_final(const float* __restrict__ dcn,
        const float* __restrict__ U, const float* __restrict__ x,
        const float* __restrict__ c1w, const float* __restrict__ c1b,
        const float* __restrict__ p2w, const float* __restrict__ p2b,
        float* __restrict__ out) {
    __shared__ float w1[64 * 65];
    __shared__ float w2[64 * 65];
    __shared__ float dv[4][64];
    __shared__ float hv[4][64];
    int t = threadIdx.x;
    int n0 = blockIdx.x * 4;
    for (int i = 0; i < 16; ++i) {
        int idx = i * 256 + t;
        int o = idx >> 6, c = idx & 63;
        w1[o * 65 + c] = c1w[idx];
        w2[o * 65 + c] = p2w[idx];
    }
    int o = t & 63, p = t >> 6;
    int n = n0 + p;
    dv[p][o] = dcn[(size_t)o * NSP + n];
    __syncthreads();
    float acc = c1b[o];
    #pragma unroll
    for (int c = 0; c < 64; ++c) acc += w1[o * 65 + c] * dv[p][c];
    hv[p][o] = U[(size_t)o * NSP + n] * acc;
    __syncthreads();
    float acc2 = p2b[o];
    #pragma unroll
    for (int c = 0; c < 64; ++c) acc2 += w2[o * 65 + c] * hv[p][c];
    acc2 += x[(size_t)n * 64 + o];
    out[(size_t)n * 64 + o] = acc2;
}

// ---------------------------------------------------------------------------
extern "C" void kernel_launch(void* const* d_in, const int* in_sizes, int n_in,
                              void* d_out, int out_size, void* d_ws, size_t ws_size,
                              hipStream_t stream) {
    const float* x   = (const float*)d_in[0];
    const float* p1w = (const float*)d_in[1];
    const float* p1b = (const float*)d_in[2];
    const float* c0w = (const float*)d_in[3];
    const float* c0b = (const float*)d_in[4];
    const float* csw = (const float*)d_in[5];
    const float* csb = (const float*)d_in[6];
    const float* ofw = (const float*)d_in[7];
    const float* ofb = (const float*)d_in[8];
    const float* dcw = (const float*)d_in[9];
    const float* dcb = (const float*)d_in[10];
    const float* c1w = (const float*)d_in[11];
    const float* c1b = (const float*)d_in[12];
    const float* p2w = (const float*)d_in[13];
    const float* p2b = (const float*)d_in[14];
    float* out = (float*)d_out;

    char* ws = (char*)d_ws;
    const size_t CN4 = (size_t)NCH * NSP * 4;       // 8 MiB per [C][N] f32
    float* U    = (float*)(ws);
    float* T0   = (float*)(ws + CN4);
    float* T1   = (float*)(ws + 2 * CN4);
    float* T1T  = (float*)(ws + 3 * CN4);
    float* OFFp = (float*)(ws + 4 * CN4);           // 81*N f32 = 10.125 MiB
    float* DCN  = (float*)(ws + 4 * CN4 + (size_t)81 * NSP * 4);

    k_proj1 <<<NSP / 64, 256, 0, stream>>>(x, p1w, p1b, U);
    k_dw5   <<<(NCH * NSP) / 256, 256, 0, stream>>>(U, c0w, c0b, T0);
    k_dw7   <<<(NCH * NSP) / 256, 256, 0, stream>>>(T0, csw, csb, T1);
    k_tr    <<<NSP / 64, 256, 0, stream>>>(T1, T1T);
    k_off   <<<(81 * NSP) / 256, 256, 0, stream>>>(T1, ofw, ofb, OFFp);
    k_deform<<<NSP / 8, 256, 0, stream>>>(T1T, OFFp, dcw, dcb, DCN);
    k_final <<<NSP / 4, 256, 0, stream>>>(DCN, U, x, c1w, c1b, p2w, p2b, out);
}

// Round 2
// 1625.991 us; speedup vs baseline: 1.6931x; 1.6931x over previous
//
#include <hip/hip_runtime.h>
#include <math.h>

#define NSP 32768   // H*W*D = 32*32*32
#define NCH 64

// ---------------------------------------------------------------------------
// K1: xv = transpose(x) ; U = gelu(proj1_w @ xv + b)   (U layout: [C][N])
__global__ __launch_bounds__(256) void k_proj1(const float* __restrict__ x,
        const float* __restrict__ w, const float* __restrict__ b,
        float* __restrict__ U) {
    __shared__ float xs[64 * 65];
    int t = threadIdx.x;
    int n0 = blockIdx.x * 64;
    for (int i = 0; i < 16; ++i) {
        int idx = i * 256 + t;
        int p = idx >> 6, c = idx & 63;
        xs[p * 65 + c] = x[(size_t)(n0 + p) * 64 + c];
    }
    __syncthreads();
    int l = t & 63;        // position lane
    int q = t >> 6;        // output-channel quarter
    for (int oi = 0; oi < 16; ++oi) {
        int o = q * 16 + oi;
        float acc = b[o];
        const float* wr = w + o * 64;
        #pragma unroll
        for (int c = 0; c < 64; ++c) acc += wr[c] * xs[l * 65 + c];
        float g = 0.5f * acc * (1.0f + erff(acc * 0.70710678118654752f));
        U[(size_t)o * NSP + n0 + l] = g;
    }
}

// ---------------------------------------------------------------------------
// K2: depthwise 5x5x5, pad 2.  in/out layout [C][N]
__global__ __launch_bounds__(256) void k_dw5(const float* __restrict__ in,
        const float* __restrict__ w, const float* __restrict__ b,
        float* __restrict__ out) {
    int tid = blockIdx.x * 256 + threadIdx.x;
    int c = tid >> 15, n = tid & 32767;
    int h = n >> 10, ww = (n >> 5) & 31, d = n & 31;
    const float* src = in + (size_t)c * NSP;
    const float* wc = w + c * 125;
    float acc = b[c];
    #pragma unroll
    for (int i = 0; i < 5; ++i) {
        int hh = h + i - 2;
        if ((unsigned)hh >= 32u) continue;
        #pragma unroll
        for (int j = 0; j < 5; ++j) {
            int wj = ww + j - 2;
            if ((unsigned)wj >= 32u) continue;
            const float* row = src + (hh << 10) + (wj << 5);
            const float* wr = wc + i * 25 + j * 5;
            #pragma unroll
            for (int l = 0; l < 5; ++l) {
                int dd = d + l - 2;
                if ((unsigned)dd >= 32u) continue;
                acc += wr[l] * row[dd];
            }
        }
    }
    out[tid] = acc;
}

// ---------------------------------------------------------------------------
// K3: depthwise 7x7x7, dilation 3, pad 9.  in/out layout [C][N]
__global__ __launch_bounds__(256) void k_dw7(const float* __restrict__ in,
        const float* __restrict__ w, const float* __restrict__ b,
        float* __restrict__ out) {
    int tid = blockIdx.x * 256 + threadIdx.x;
    int c = tid >> 15, n = tid & 32767;
    int h = n >> 10, ww = (n >> 5) & 31, d = n & 31;
    const float* src = in + (size_t)c * NSP;
    const float* wc = w + c * 343;
    float acc = b[c];
    for (int i = 0; i < 7; ++i) {
        int hh = h + 3 * i - 9;
        if ((unsigned)hh >= 32u) continue;
        for (int j = 0; j < 7; ++j) {
            int wj = ww + 3 * j - 9;
            if ((unsigned)wj >= 32u) continue;
            const float* row = src + (hh << 10) + (wj << 5);
            const float* wr = wc + i * 49 + j * 7;
            #pragma unroll
            for (int l = 0; l < 7; ++l) {
                int dd = d + 3 * l - 9;
                if ((unsigned)dd >= 32u) continue;
                acc += wr[l] * row[dd];
            }
        }
    }
    out[tid] = acc;
}

// ---------------------------------------------------------------------------
// K4: transpose [C][N] -> [N][C]
__global__ __launch_bounds__(256) void k_tr(const float* __restrict__ in,
        float* __restrict__ out) {
    __shared__ float tile[64 * 65];
    int t = threadIdx.x;
    int n0 = blockIdx.x * 64;
    for (int i = 0; i < 16; ++i) {
        int idx = i * 256 + t;
        int c = idx >> 6, nl = idx & 63;
        tile[c * 65 + nl] = in[(size_t)c * NSP + n0 + nl];
    }
    __syncthreads();
    for (int i = 0; i < 16; ++i) {
        int idx = i * 256 + t;
        int nl = idx >> 6, c = idx & 63;
        out[(size_t)(n0 + nl) * 64 + c] = tile[c * 65 + nl];
    }
}

// ---------------------------------------------------------------------------
// K5 (new): offset conv 3x3x3, 64 -> 81 channels.  in [C][N], out [81][N]
// One block per (h,w) row of 32 d-positions. 16 channel-chunks of 4.
// Per chunk: stage input halo [9 rows][4 ch][34 d-padded] + weights
// [81][4][28-padded] in LDS. Thread = (ko-slot s in 0..7, d in 0..31);
// slot s computes kos {s, s+8, ...}. Input taps cached in regs per channel
// and reused across all kos; weights read as float4 LDS broadcasts.
__global__ __launch_bounds__(256) void k_off(const float* __restrict__ in,
        const float* __restrict__ ow, const float* __restrict__ ob,
        float* __restrict__ off) {
    __shared__ __align__(16) float ins4[9 * 4 * 34];    // 4896 B
    __shared__ __align__(16) float wl[81 * 4 * 28];     // 36288 B
    int t = threadIdx.x;
    int h0 = blockIdx.x >> 5, w0 = blockIdx.x & 31;
    int d = t & 31, s = t >> 5;           // s in 0..7
    int n0 = (h0 << 10) + (w0 << 5);

    float acc[11];
    #pragma unroll
    for (int i = 0; i < 11; ++i) {
        int ko = s + 8 * i;
        acc[i] = (ko < 81) ? ob[ko] : 0.f;
    }

    for (int cc = 0; cc < 16; ++cc) {     // channel chunks of 4
        __syncthreads();                  // WAR: prior chunk's readers done
        // --- stage input halo chunk: rows (h0+kh-1, w0+kw-1), ch cc*4..+3
        for (int i = t; i < 9 * 4 * 32; i += 256) {
            int nb = i >> 7;              // 0..8
            int c  = (i >> 5) & 3;
            int dd = i & 31;
            int hh = h0 + nb / 3 - 1;
            int wj = w0 + nb % 3 - 1;
            float v = 0.f;
            if (((unsigned)hh < 32u) & ((unsigned)wj < 32u))
                v = in[((size_t)(cc * 4 + c) << 15) + (hh << 10) + (wj << 5) + dd];
            ins4[(nb * 4 + c) * 34 + 1 + dd] = v;
        }
        for (int i = t; i < 9 * 4 * 2; i += 256) {        // d-edge zero pads
            int rc = i >> 1;
            ins4[rc * 34 + (i & 1) * 33] = 0.f;
        }
        // --- stage weight chunk [81][4][27] (+pad col 27 = 0)
        for (int i = t; i < 81 * 4 * 27; i += 256) {
            int ko = i / 108;
            int jj = i - ko * 108;
            int c  = jj / 27;
            int k  = jj - c * 27;
            wl[(ko * 4 + c) * 28 + k] = ow[(size_t)ko * 1728 + (cc * 4 + c) * 27 + k];
        }
        for (int i = t; i < 81 * 4; i += 256) wl[i * 28 + 27] = 0.f;
        __syncthreads();

        // --- compute
        #pragma unroll
        for (int c = 0; c < 4; ++c) {
            float ir[28];
            #pragma unroll
            for (int k = 0; k < 27; ++k) {
                int kh = k / 9, kw = (k / 3) % 3, kd = k % 3;
                int nb = kh * 3 + kw;
                ir[k] = ins4[(nb * 4 + c) * 34 + d + kd];
            }
            ir[27] = 0.f;
            #pragma unroll
            for (int i = 0; i < 11; ++i) {
                int ko = s + 8 * i;
                if (ko < 81) {
                    const float4* wr = (const float4*)&wl[(ko * 4 + c) * 28];
                    #pragma unroll
                    for (int q = 0; q < 7; ++q) {
                        float4 wq = wr[q];
                        acc[i] += wq.x * ir[4 * q]     + wq.y * ir[4 * q + 1]
                                + wq.z * ir[4 * q + 2] + wq.w * ir[4 * q + 3];
                    }
                }
            }
        }
    }
    #pragma unroll
    for (int i = 0; i < 11; ++i) {
        int ko = s + 8 * i;
        if (ko < 81) off[(size_t)ko * NSP + n0 + d] = acc[i];
    }
}

// ---------------------------------------------------------------------------
// K6: deformable gather + 27-tap GEMM.
//  Phase B: trilinear sample -> LDS S[p][c*27+k]   (unchanged)
//  Phase C (new): weights staged to LDS in 64x64 chunks (pad 65 ->
//  (o+kk)%32 banks, 2-way = free); S reads are wave-uniform broadcasts.
__global__ __launch_bounds__(256) void k_deform(const float* __restrict__ aT,
        const float* __restrict__ off, const float* __restrict__ dw,
        const float* __restrict__ db, float* __restrict__ dcn) {
    __shared__ float S[8][1728];          // 55296 B
    __shared__ float wc[64 * 65];         // 16640 B
    int t = threadIdx.x;
    int n0 = blockIdx.x * 8;
    int lane = t & 63, wv = t >> 6;
    for (int j = wv; j < 216; j += 4) {   // 8 pos * 27 taps
        int p = j / 27, k = j % 27;
        int n = n0 + p;
        int h = n >> 10, w = (n >> 5) & 31, d = n & 31;
        float ph = (float)(h + k / 9 - 1)       + off[(size_t)(k * 3 + 0) * NSP + n];
        float pw = (float)(w + (k / 3) % 3 - 1) + off[(size_t)(k * 3 + 1) * NSP + n];
        float pd = (float)(d + k % 3 - 1)       + off[(size_t)(k * 3 + 2) * NSP + n];
        float fh = floorf(ph), fw = floorf(pw), fd = floorf(pd);
        int ih = (int)fh, iw = (int)fw, id = (int)fd;
        float rh = ph - fh, rw = pw - fw, rd = pd - fd;
        float acc = 0.f;
        #pragma unroll
        for (int cb = 0; cb < 8; ++cb) {
            int hh = ih + ((cb >> 2) & 1);
            int wq = iw + ((cb >> 1) & 1);
            int dq = id + (cb & 1);
            float wg = ((cb & 4) ? rh : 1.f - rh) * ((cb & 2) ? rw : 1.f - rw)
                     * ((cb & 1) ? rd : 1.f - rd);
            bool ok = ((unsigned)hh < 32u) & ((unsigned)wq < 32u) & ((unsigned)dq < 32u);
            int fl = ok ? ((hh << 5) + wq) * 32 + dq : 0;
            float v = aT[(size_t)fl * 64 + lane];   // coalesced across lanes
            acc += (ok ? wg : 0.f) * v;
        }
        S[p][lane * 27 + k] = acc;
    }
    int o = lane, pg = wv;
    int p0 = pg * 2, p1 = p0 + 1;
    float a0 = 0.f, a1 = 0.f;
    for (int cc = 0; cc < 27; ++cc) {     // 1728 / 64 weight chunks
        __syncthreads();                  // S ready (cc=0) / WAR on wc
        for (int i = 0; i < 16; ++i) {
            int idx = i * 256 + t;        // 0..4095
            int oo = idx >> 6, kk = idx & 63;
            wc[oo * 65 + kk] = dw[(size_t)oo * 1728 + cc * 64 + kk];
        }
        __syncthreads();
        #pragma unroll
        for (int kk = 0; kk < 64; ++kk) {
            float wv2 = wc[o * 65 + kk];  // bank (o+kk)%32: 2-way, free
            int ck = cc * 64 + kk;
            a0 += wv2 * S[p0][ck];        // wave-uniform broadcasts
            a1 += wv2 * S[p1][ck];
        }
    }
    float bb = db[o];
    dcn[(size_t)o * NSP + n0 + p0] = a0 + bb;
    dcn[(size_t)o * NSP + n0 + p1] = a1 + bb;
}

// ---------------------------------------------------------------------------
// K7: a2 = conv1_w @ dcn + b ; h = U * a2 ; out = proj2_w @ h + b2 + x
__global__ __launch_bounds__(256) void k_final(const float* __restrict__ dcn,
        const float* __restrict__ U, const float* __restrict__ x,
        const float* __restrict__ c1w, const float* __restrict__ c1b,
        const float* __restrict__ p2w, const float* __restrict__ p2b,
        float* __restrict__ out) {
    __shared__ float w1[64 * 65];
    __shared__ float w2[64 * 65];
    __shared__ float dv[4][64];
    __shared__ float hv[4][64];
    int t = threadIdx.x;
    int n0 = blockIdx.x * 4;
    for (int i = 0; i < 16; ++i) {
        int idx = i * 256 + t;
        int o = idx >> 6, c = idx & 63;
        w1[o * 65 + c] = c1w[idx];
        w2[o * 65 + c] = p2w[idx];
    }
    int o = t & 63, p = t >> 6;
    int n = n0 + p;
    dv[p][o] = dcn[(size_t)o * NSP + n];
    __syncthreads();
    float acc = c1b[o];
    #pragma unroll
    for (int c = 0; c < 64; ++c) acc += w1[o * 65 + c] * dv[p][c];
    hv[p][o] = U[(size_t)o * NSP + n] * acc;
    __syncthreads();
    float acc2 = p2b[o];
    #pragma unroll
    for (int c = 0; c < 64; ++c) acc2 += w2[o * 65 + c] * hv[p][c];
    acc2 += x[(size_t)n * 64 + o];
    out[(size_t)n * 64 + o] = acc2;
}

// ---------------------------------------------------------------------------
extern "C" void kernel_launch(void* const* d_in, const int* in_sizes, int n_in,
                              void* d_out, int out_size, void* d_ws, size_t ws_size,
                              hipStream_t stream) {
    const float* x   = (const float*)d_in[0];
    const float* p1w = (const float*)d_in[1];
    const float* p1b = (const float*)d_in[2];
    const float* c0w = (const float*)d_in[3];
    const float* c0b = (const float*)d_in[4];
    const float* csw = (const float*)d_in[5];
    const float* csb = (const float*)d_in[6];
    const float* ofw = (const float*)d_in[7];
    const float* ofb = (const float*)d_in[8];
    const float* dcw = (const float*)d_in[9];
    const float* dcb = (const float*)d_in[10];
    const float* c1w = (const float*)d_in[11];
    const float* c1b = (const float*)d_in[12];
    const float* p2w = (const float*)d_in[13];
    const float* p2b = (const float*)d_in[14];
    float* out = (float*)d_out;

    char* ws = (char*)d_ws;
    const size_t CN4 = (size_t)NCH * NSP * 4;       // 8 MiB per [C][N] f32
    float* U    = (float*)(ws);
    float* T0   = (float*)(ws + CN4);
    float* T1   = (float*)(ws + 2 * CN4);
    float* T1T  = (float*)(ws + 3 * CN4);
    float* OFFp = (float*)(ws + 4 * CN4);           // 81*N f32
    float* DCN  = (float*)(ws + 4 * CN4 + (size_t)81 * NSP * 4);

    k_proj1 <<<NSP / 64, 256, 0, stream>>>(x, p1w, p1b, U);
    k_dw5   <<<(NCH * NSP) / 256, 256, 0, stream>>>(U, c0w, c0b, T0);
    k_dw7   <<<(NCH * NSP) / 256, 256, 0, stream>>>(T0, csw, csb, T1);
    k_tr    <<<NSP / 64, 256, 0, stream>>>(T1, T1T);
    k_off   <<<1024, 256, 0, stream>>>(T1, ofw, ofb, OFFp);
    k_deform<<<NSP / 8, 256, 0, stream>>>(T1T, OFFp, dcw, dcb, DCN);
    k_final <<<NSP / 4, 256, 0, stream>>>(DCN, U, x, c1w, c1b, p2w, p2b, out);
}

// Round 3
// 1004.263 us; speedup vs baseline: 2.7413x; 1.6191x over previous
//
#include <hip/hip_runtime.h>
#include <math.h>

#define NSP 32768   // H*W*D = 32*32*32
#define NCH 64

typedef _Float16 half8 __attribute__((ext_vector_type(8)));
typedef float f32x4 __attribute__((ext_vector_type(4)));

// ---------------------------------------------------------------------------
// K1: xv = transpose(x) ; U = gelu(proj1_w @ xv + b)   (U layout: [C][N])
__global__ __launch_bounds__(256) void k_proj1(const float* __restrict__ x,
        const float* __restrict__ w, const float* __restrict__ b,
        float* __restrict__ U) {
    __shared__ float xs[64 * 65];
    int t = threadIdx.x;
    int n0 = blockIdx.x * 64;
    for (int i = 0; i < 16; ++i) {
        int idx = i * 256 + t;
        int p = idx >> 6, c = idx & 63;
        xs[p * 65 + c] = x[(size_t)(n0 + p) * 64 + c];
    }
    __syncthreads();
    int l = t & 63;
    int q = t >> 6;
    for (int oi = 0; oi < 16; ++oi) {
        int o = q * 16 + oi;
        float acc = b[o];
        const float* wr = w + o * 64;
        #pragma unroll
        for (int c = 0; c < 64; ++c) acc += wr[c] * xs[l * 65 + c];
        float g = 0.5f * acc * (1.0f + erff(acc * 0.70710678118654752f));
        U[(size_t)o * NSP + n0 + l] = g;
    }
}

// ---------------------------------------------------------------------------
// K2: depthwise 5x5x5, pad 2.  in/out layout [C][N]
__global__ __launch_bounds__(256) void k_dw5(const float* __restrict__ in,
        const float* __restrict__ w, const float* __restrict__ b,
        float* __restrict__ out) {
    int tid = blockIdx.x * 256 + threadIdx.x;
    int c = tid >> 15, n = tid & 32767;
    int h = n >> 10, ww = (n >> 5) & 31, d = n & 31;
    const float* src = in + (size_t)c * NSP;
    const float* wc = w + c * 125;
    float acc = b[c];
    #pragma unroll
    for (int i = 0; i < 5; ++i) {
        int hh = h + i - 2;
        if ((unsigned)hh >= 32u) continue;
        #pragma unroll
        for (int j = 0; j < 5; ++j) {
            int wj = ww + j - 2;
            if ((unsigned)wj >= 32u) continue;
            const float* row = src + (hh << 10) + (wj << 5);
            const float* wr = wc + i * 25 + j * 5;
            #pragma unroll
            for (int l = 0; l < 5; ++l) {
                int dd = d + l - 2;
                if ((unsigned)dd >= 32u) continue;
                acc += wr[l] * row[dd];
            }
        }
    }
    out[tid] = acc;
}

// ---------------------------------------------------------------------------
// K3: depthwise 7x7x7, dilation 3, pad 9.  in/out layout [C][N]
__global__ __launch_bounds__(256) void k_dw7(const float* __restrict__ in,
        const float* __restrict__ w, const float* __restrict__ b,
        float* __restrict__ out) {
    int tid = blockIdx.x * 256 + threadIdx.x;
    int c = tid >> 15, n = tid & 32767;
    int h = n >> 10, ww = (n >> 5) & 31, d = n & 31;
    const float* src = in + (size_t)c * NSP;
    const float* wc = w + c * 343;
    float acc = b[c];
    for (int i = 0; i < 7; ++i) {
        int hh = h + 3 * i - 9;
        if ((unsigned)hh >= 32u) continue;
        for (int j = 0; j < 7; ++j) {
            int wj = ww + 3 * j - 9;
            if ((unsigned)wj >= 32u) continue;
            const float* row = src + (hh << 10) + (wj << 5);
            const float* wr = wc + i * 49 + j * 7;
            #pragma unroll
            for (int l = 0; l < 7; ++l) {
                int dd = d + 3 * l - 9;
                if ((unsigned)dd >= 32u) continue;
                acc += wr[l] * row[dd];
            }
        }
    }
    out[tid] = acc;
}

// ---------------------------------------------------------------------------
// K4: transpose [C][N] -> [N][C]
__global__ __launch_bounds__(256) void k_tr(const float* __restrict__ in,
        float* __restrict__ out) {
    __shared__ float tile[64 * 65];
    int t = threadIdx.x;
    int n0 = blockIdx.x * 64;
    for (int i = 0; i < 16; ++i) {
        int idx = i * 256 + t;
        int c = idx >> 6, nl = idx & 63;
        tile[c * 65 + nl] = in[(size_t)c * NSP + n0 + nl];
    }
    __syncthreads();
    for (int i = 0; i < 16; ++i) {
        int idx = i * 256 + t;
        int nl = idx >> 6, c = idx & 63;
        out[(size_t)(n0 + nl) * 64 + c] = tile[c * 65 + nl];
    }
}

// ---------------------------------------------------------------------------
// K5: offset conv 3x3x3, 64 -> 81 channels.  in [C][N], out [81][N]
__global__ __launch_bounds__(256) void k_off(const float* __restrict__ in,
        const float* __restrict__ ow, const float* __restrict__ ob,
        float* __restrict__ off) {
    __shared__ __align__(16) float ins4[9 * 4 * 34];
    __shared__ __align__(16) float wl[81 * 4 * 28];
    int t = threadIdx.x;
    int h0 = blockIdx.x >> 5, w0 = blockIdx.x & 31;
    int d = t & 31, s = t >> 5;
    int n0 = (h0 << 10) + (w0 << 5);

    float acc[11];
    #pragma unroll
    for (int i = 0; i < 11; ++i) {
        int ko = s + 8 * i;
        acc[i] = (ko < 81) ? ob[ko] : 0.f;
    }

    for (int cc = 0; cc < 16; ++cc) {
        __syncthreads();
        for (int i = t; i < 9 * 4 * 32; i += 256) {
            int nb = i >> 7;
            int c  = (i >> 5) & 3;
            int dd = i & 31;
            int hh = h0 + nb / 3 - 1;
            int wj = w0 + nb % 3 - 1;
            float v = 0.f;
            if (((unsigned)hh < 32u) & ((unsigned)wj < 32u))
                v = in[((size_t)(cc * 4 + c) << 15) + (hh << 10) + (wj << 5) + dd];
            ins4[(nb * 4 + c) * 34 + 1 + dd] = v;
        }
        for (int i = t; i < 9 * 4 * 2; i += 256) {
            int rc = i >> 1;
            ins4[rc * 34 + (i & 1) * 33] = 0.f;
        }
        for (int i = t; i < 81 * 4 * 27; i += 256) {
            int ko = i / 108;
            int jj = i - ko * 108;
            int c  = jj / 27;
            int k  = jj - c * 27;
            wl[(ko * 4 + c) * 28 + k] = ow[(size_t)ko * 1728 + (cc * 4 + c) * 27 + k];
        }
        for (int i = t; i < 81 * 4; i += 256) wl[i * 28 + 27] = 0.f;
        __syncthreads();

        #pragma unroll
        for (int c = 0; c < 4; ++c) {
            float ir[28];
            #pragma unroll
            for (int k = 0; k < 27; ++k) {
                int kh = k / 9, kw = (k / 3) % 3, kd = k % 3;
                int nb = kh * 3 + kw;
                ir[k] = ins4[(nb * 4 + c) * 34 + d + kd];
            }
            ir[27] = 0.f;
            #pragma unroll
            for (int i = 0; i < 11; ++i) {
                int ko = s + 8 * i;
                if (ko < 81) {
                    const float4* wr = (const float4*)&wl[(ko * 4 + c) * 28];
                    #pragma unroll
                    for (int q = 0; q < 7; ++q) {
                        float4 wq = wr[q];
                        acc[i] += wq.x * ir[4 * q]     + wq.y * ir[4 * q + 1]
                                + wq.z * ir[4 * q + 2] + wq.w * ir[4 * q + 3];
                    }
                }
            }
        }
    }
    #pragma unroll
    for (int i = 0; i < 11; ++i) {
        int ko = s + 8 * i;
        if (ko < 81) off[(size_t)ko * NSP + n0 + d] = acc[i];
    }
}

// ---------------------------------------------------------------------------
// K5b: pre-pack dcn weights into f16 MFMA A-fragment order.
// Wp[((kb*4 + ob)*64 + l)*8 + j] = dw[o][c*27+k], o = ob*16 + (l&15),
// K' = kb*32 + (l>>4)*8 + j, k = K'>>6 (tap), c = K'&63 (channel).
__global__ __launch_bounds__(256) void k_wpack(const float* __restrict__ dw,
        _Float16* __restrict__ Wp) {
    int idx = blockIdx.x * 256 + threadIdx.x;   // 0 .. 110591
    int j = idx & 7;
    int l = (idx >> 3) & 63;
    int obk = idx >> 9;
    int ob = obk & 3, kb = obk >> 2;
    int o = ob * 16 + (l & 15);
    int Kp = kb * 32 + (l >> 4) * 8 + j;
    int k = Kp >> 6, c = Kp & 63;
    Wp[idx] = (_Float16)dw[(size_t)o * 1728 + c * 27 + k];
}

// ---------------------------------------------------------------------------
// K6: deformable gather + MFMA GEMM.
// Block = 16 positions, 4 waves. Phase B: 432 taps (p,k); wave-wide gather of
// 64 channels per tap -> f16 into S[p][k*64+c] (row stride 1736 f16 ==
// 868 words == 4 mod 32 -> b128 B-frag reads are 2-way = free).
// Phase C: wave wv owns o-block wv; 54 x mfma_f32_16x16x32_f16 with A-frags
// streamed straight from the pre-packed global Wp (coalesced dwordx4).
__global__ __launch_bounds__(256) void k_deform(const float* __restrict__ aT,
        const float* __restrict__ off, const half8* __restrict__ Wp,
        const float* __restrict__ db, float* __restrict__ dcn) {
    __shared__ __align__(16) _Float16 S[16 * 1736];   // 55552 B
    int t = threadIdx.x;
    int n0 = blockIdx.x * 16;
    int lane = t & 63, wv = t >> 6;
    for (int j = wv; j < 432; j += 4) {     // 16 pos * 27 taps
        int p = j / 27, k = j - p * 27;
        int n = n0 + p;
        int h = n >> 10, w = (n >> 5) & 31, d = n & 31;
        float ph = (float)(h + k / 9 - 1)       + off[(size_t)(k * 3 + 0) * NSP + n];
        float pw = (float)(w + (k / 3) % 3 - 1) + off[(size_t)(k * 3 + 1) * NSP + n];
        float pd = (float)(d + k % 3 - 1)       + off[(size_t)(k * 3 + 2) * NSP + n];
        float fh = floorf(ph), fw = floorf(pw), fd = floorf(pd);
        int ih = (int)fh, iw = (int)fw, id = (int)fd;
        float rh = ph - fh, rw = pw - fw, rd = pd - fd;
        float acc = 0.f;
        #pragma unroll
        for (int cb = 0; cb < 8; ++cb) {
            int hh = ih + ((cb >> 2) & 1);
            int wq = iw + ((cb >> 1) & 1);
            int dq = id + (cb & 1);
            float wg = ((cb & 4) ? rh : 1.f - rh) * ((cb & 2) ? rw : 1.f - rw)
                     * ((cb & 1) ? rd : 1.f - rd);
            bool ok = ((unsigned)hh < 32u) & ((unsigned)wq < 32u) & ((unsigned)dq < 32u);
            int fl = ok ? ((hh << 5) + wq) * 32 + dq : 0;
            float v = aT[(size_t)fl * 64 + lane];   // coalesced across lanes
            acc += (ok ? wg : 0.f) * v;
        }
        S[p * 1736 + k * 64 + lane] = (_Float16)acc;
    }
    __syncthreads();
    // GEMM: D[o=wv*16..+15][p=0..15], K = 1728
    f32x4 acc4 = {0.f, 0.f, 0.f, 0.f};
    const half8* wbase = Wp + wv * 64 + lane;                   // +256 per kb
    const _Float16* sbase = &S[(lane & 15) * 1736 + (lane >> 4) * 8];
    #pragma unroll 9
    for (int kb = 0; kb < 54; ++kb) {
        half8 af = wbase[(size_t)kb * 256];
        half8 bf = *(const half8*)(sbase + kb * 32);
        acc4 = __builtin_amdgcn_mfma_f32_16x16x32_f16(af, bf, acc4, 0, 0, 0);
    }
    int pl = lane & 15, g = lane >> 4;
    #pragma unroll
    for (int r = 0; r < 4; ++r) {
        int o = wv * 16 + g * 4 + r;
        dcn[(size_t)o * NSP + n0 + pl] = acc4[r] + db[o];
    }
}

// ---------------------------------------------------------------------------
// K7: a2 = conv1_w @ dcn + b ; h = U * a2 ; out = proj2_w @ h + b2 + x
__global__ __launch_bounds__(256) void k_final(const float* __restrict__ dcn,
        const float* __restrict__ U, const float* __restrict__ x,
        const float* __restrict__ c1w, const float* __restrict__ c1b,
        const float* __restrict__ p2w, const float* __restrict__ p2b,
        float* __restrict__ out) {
    __shared__ float w1[64 * 65];
    __shared__ float w2[64 * 65];
    __shared__ float dv[4][64];
    __shared__ float hv[4][64];
    int t = threadIdx.x;
    int n0 = blockIdx.x * 4;
    for (int i = 0; i < 16; ++i) {
        int idx = i * 256 + t;
        int o = idx >> 6, c = idx & 63;
        w1[o * 65 + c] = c1w[idx];
        w2[o * 65 + c] = p2w[idx];
    }
    int o = t & 63, p = t >> 6;
    int n = n0 + p;
    dv[p][o] = dcn[(size_t)o * NSP + n];
    __syncthreads();
    float acc = c1b[o];
    #pragma unroll
    for (int c = 0; c < 64; ++c) acc += w1[o * 65 + c] * dv[p][c];
    hv[p][o] = U[(size_t)o * NSP + n] * acc;
    __syncthreads();
    float acc2 = p2b[o];
    #pragma unroll
    for (int c = 0; c < 64; ++c) acc2 += w2[o * 65 + c] * hv[p][c];
    acc2 += x[(size_t)n * 64 + o];
    out[(size_t)n * 64 + o] = acc2;
}

// ---------------------------------------------------------------------------
extern "C" void kernel_launch(void* const* d_in, const int* in_sizes, int n_in,
                              void* d_out, int out_size, void* d_ws, size_t ws_size,
                              hipStream_t stream) {
    const float* x   = (const float*)d_in[0];
    const float* p1w = (const float*)d_in[1];
    const float* p1b = (const float*)d_in[2];
    const float* c0w = (const float*)d_in[3];
    const float* c0b = (const float*)d_in[4];
    const float* csw = (const float*)d_in[5];
    const float* csb = (const float*)d_in[6];
    const float* ofw = (const float*)d_in[7];
    const float* ofb = (const float*)d_in[8];
    const float* dcw = (const float*)d_in[9];
    const float* dcb = (const float*)d_in[10];
    const float* c1w = (const float*)d_in[11];
    const float* c1b = (const float*)d_in[12];
    const float* p2w = (const float*)d_in[13];
    const float* p2b = (const float*)d_in[14];
    float* out = (float*)d_out;

    char* ws = (char*)d_ws;
    const size_t CN4 = (size_t)NCH * NSP * 4;       // 8 MiB per [C][N] f32
    float* U    = (float*)(ws);
    float* T0   = (float*)(ws + CN4);
    float* T1   = (float*)(ws + 2 * CN4);
    float* T1T  = (float*)(ws + 3 * CN4);
    float* OFFp = (float*)(ws + 4 * CN4);           // 81*N f32
    float* DCN  = (float*)(ws + 4 * CN4 + (size_t)81 * NSP * 4);
    _Float16* Wp = (_Float16*)(ws + 5 * CN4 + (size_t)81 * NSP * 4);

    k_proj1 <<<NSP / 64, 256, 0, stream>>>(x, p1w, p1b, U);
    k_dw5   <<<(NCH * NSP) / 256, 256, 0, stream>>>(U, c0w, c0b, T0);
    k_dw7   <<<(NCH * NSP) / 256, 256, 0, stream>>>(T0, csw, csb, T1);
    k_tr    <<<NSP / 64, 256, 0, stream>>>(T1, T1T);
    k_off   <<<1024, 256, 0, stream>>>(T1, ofw, ofb, OFFp);
    k_wpack <<<432, 256, 0, stream>>>(dcw, Wp);
    k_deform<<<NSP / 16, 256, 0, stream>>>(T1T, OFFp, (const half8*)Wp, dcb, DCN);
    k_final <<<NSP / 4, 256, 0, stream>>>(DCN, U, x, c1w, c1b, p2w, p2b, out);
}

// Round 4
// 779.764 us; speedup vs baseline: 3.5305x; 1.2879x over previous
//
#include <hip/hip_runtime.h>
#include <math.h>

#define NSP 32768   // H*W*D = 32*32*32
#define NCH 64

typedef _Float16 half8 __attribute__((ext_vector_type(8)));
typedef float f32x4 __attribute__((ext_vector_type(4)));

// ---------------------------------------------------------------------------
// K1: xv = transpose(x) ; U = gelu(proj1_w @ xv + b)   (U layout: [C][N])
__global__ __launch_bounds__(256) void k_proj1(const float* __restrict__ x,
        const float* __restrict__ w, const float* __restrict__ b,
        float* __restrict__ U) {
    __shared__ float xs[64 * 65];
    int t = threadIdx.x;
    int n0 = blockIdx.x * 64;
    for (int i = 0; i < 16; ++i) {
        int idx = i * 256 + t;
        int p = idx >> 6, c = idx & 63;
        xs[p * 65 + c] = x[(size_t)(n0 + p) * 64 + c];
    }
    __syncthreads();
    int l = t & 63;
    int q = t >> 6;
    for (int oi = 0; oi < 16; ++oi) {
        int o = q * 16 + oi;
        float acc = b[o];
        const float* wr = w + o * 64;
        #pragma unroll
        for (int c = 0; c < 64; ++c) acc += wr[c] * xs[l * 65 + c];
        float g = 0.5f * acc * (1.0f + erff(acc * 0.70710678118654752f));
        U[(size_t)o * NSP + n0 + l] = g;
    }
}

// ---------------------------------------------------------------------------
// K2: depthwise 5x5x5, pad 2.  in/out layout [C][N]
__global__ __launch_bounds__(256) void k_dw5(const float* __restrict__ in,
        const float* __restrict__ w, const float* __restrict__ b,
        float* __restrict__ out) {
    int tid = blockIdx.x * 256 + threadIdx.x;
    int c = tid >> 15, n = tid & 32767;
    int h = n >> 10, ww = (n >> 5) & 31, d = n & 31;
    const float* src = in + (size_t)c * NSP;
    const float* wc = w + c * 125;
    float acc = b[c];
    #pragma unroll
    for (int i = 0; i < 5; ++i) {
        int hh = h + i - 2;
        if ((unsigned)hh >= 32u) continue;
        #pragma unroll
        for (int j = 0; j < 5; ++j) {
            int wj = ww + j - 2;
            if ((unsigned)wj >= 32u) continue;
            const float* row = src + (hh << 10) + (wj << 5);
            const float* wr = wc + i * 25 + j * 5;
            #pragma unroll
            for (int l = 0; l < 5; ++l) {
                int dd = d + l - 2;
                if ((unsigned)dd >= 32u) continue;
                acc += wr[l] * row[dd];
            }
        }
    }
    out[tid] = acc;
}

// ---------------------------------------------------------------------------
// K3: depthwise 7x7x7, dilation 3, pad 9.  in/out layout [C][N]
__global__ __launch_bounds__(256) void k_dw7(const float* __restrict__ in,
        const float* __restrict__ w, const float* __restrict__ b,
        float* __restrict__ out) {
    int tid = blockIdx.x * 256 + threadIdx.x;
    int c = tid >> 15, n = tid & 32767;
    int h = n >> 10, ww = (n >> 5) & 31, d = n & 31;
    const float* src = in + (size_t)c * NSP;
    const float* wc = w + c * 343;
    float acc = b[c];
    for (int i = 0; i < 7; ++i) {
        int hh = h + 3 * i - 9;
        if ((unsigned)hh >= 32u) continue;
        for (int j = 0; j < 7; ++j) {
            int wj = ww + 3 * j - 9;
            if ((unsigned)wj >= 32u) continue;
            const float* row = src + (hh << 10) + (wj << 5);
            const float* wr = wc + i * 49 + j * 7;
            #pragma unroll
            for (int l = 0; l < 7; ++l) {
                int dd = d + 3 * l - 9;
                if ((unsigned)dd >= 32u) continue;
                acc += wr[l] * row[dd];
            }
        }
    }
    out[tid] = acc;
}

// ---------------------------------------------------------------------------
// K4: transpose [C][N] -> [N][C]
__global__ __launch_bounds__(256) void k_tr(const float* __restrict__ in,
        float* __restrict__ out) {
    __shared__ float tile[64 * 65];
    int t = threadIdx.x;
    int n0 = blockIdx.x * 64;
    for (int i = 0; i < 16; ++i) {
        int idx = i * 256 + t;
        int c = idx >> 6, nl = idx & 63;
        tile[c * 65 + nl] = in[(size_t)c * NSP + n0 + nl];
    }
    __syncthreads();
    for (int i = 0; i < 16; ++i) {
        int idx = i * 256 + t;
        int nl = idx >> 6, c = idx & 63;
        out[(size_t)(n0 + nl) * 64 + c] = tile[c * 65 + nl];
    }
}

// ---------------------------------------------------------------------------
// K5a: pre-pack deform weights into f16 MFMA A-fragment order.
// Wp[((kb*4 + ob)*64 + l)*8 + j] = dw[o][c*27+k], o = ob*16 + (l&15),
// K' = kb*32 + (l>>4)*8 + j, k = K'>>6 (tap), c = K'&63 (channel).
__global__ __launch_bounds__(256) void k_wpack(const float* __restrict__ dw,
        _Float16* __restrict__ Wp) {
    int idx = blockIdx.x * 256 + threadIdx.x;   // 0 .. 110591
    int j = idx & 7;
    int l = (idx >> 3) & 63;
    int obk = idx >> 9;
    int ob = obk & 3, kb = obk >> 2;
    int o = ob * 16 + (l & 15);
    int Kp = kb * 32 + (l >> 4) * 8 + j;
    int k = Kp >> 6, c = Kp & 63;
    Wp[idx] = (_Float16)dw[(size_t)o * 1728 + c * 27 + k];
}

// ---------------------------------------------------------------------------
// K5b: pre-pack offset-conv weights, 6 o-blocks of 16 (rows 81..95 = 0).
// Wp2[((kb*6 + ob)*64 + l)*8 + j] = ow[o][c*27+k], same K' mapping.
__global__ __launch_bounds__(256) void k_wpack_off(const float* __restrict__ ow,
        _Float16* __restrict__ Wp2) {
    int idx = blockIdx.x * 256 + threadIdx.x;   // 0 .. 165887
    int j = idx & 7;
    int l = (idx >> 3) & 63;
    int obk = idx >> 9;                          // 0 .. 323
    int ob = obk % 6, kb = obk / 6;
    int o = ob * 16 + (l & 15);
    int Kp = kb * 32 + (l >> 4) * 8 + j;
    int k = Kp >> 6, c = Kp & 63;
    Wp2[idx] = (o < 81) ? (_Float16)ow[(size_t)o * 1728 + c * 27 + k]
                        : (_Float16)0.f;
}

// ---------------------------------------------------------------------------
// K5c: offset conv as im2col + MFMA GEMM.  out off[81][N].
// Block = 16 positions, 4 waves. Phase B: 432 integer taps, wave-wide gather
// of 64 channels from aT [N][C] -> f16 S[p][k*64+c] (stride 1736: b128
// B-frag reads 2-way = free). Phase C: 6 o-blocks of 16; wave wv does
// o-blocks {wv, wv+4}; 54 x mfma_f32_16x16x32_f16 each, A streamed from Wp2.
__global__ __launch_bounds__(256) void k_offg(const float* __restrict__ aT,
        const half8* __restrict__ Wp2, const float* __restrict__ obias,
        float* __restrict__ off) {
    __shared__ __align__(16) _Float16 S[16 * 1736];   // 55552 B
    int t = threadIdx.x;
    int n0 = blockIdx.x * 16;
    int lane = t & 63, wv = t >> 6;
    for (int j = wv; j < 432; j += 4) {     // 16 pos * 27 taps
        int p = j / 27, k = j - p * 27;
        int n = n0 + p;
        int h = n >> 10, w = (n >> 5) & 31, d = n & 31;
        int hh = h + k / 9 - 1;
        int wj = w + (k / 3) % 3 - 1;
        int dd = d + k % 3 - 1;
        bool ok = ((unsigned)hh < 32u) & ((unsigned)wj < 32u) & ((unsigned)dd < 32u);
        int fl = ok ? ((hh << 5) + wj) * 32 + dd : 0;
        float v = ok ? aT[(size_t)fl * 64 + lane] : 0.f;
        S[p * 1736 + k * 64 + lane] = (_Float16)v;
    }
    __syncthreads();
    const _Float16* sbase = &S[(lane & 15) * 1736 + (lane >> 4) * 8];
    int pl = lane & 15, g = lane >> 4;
    for (int obi = wv; obi < 6; obi += 4) {
        f32x4 acc4 = {0.f, 0.f, 0.f, 0.f};
        const half8* wbase = Wp2 + obi * 64 + lane;
        #pragma unroll 9
        for (int kb = 0; kb < 54; ++kb) {
            half8 af = wbase[(size_t)kb * 384];          // 6 o-blocks * 64
            half8 bf = *(const half8*)(sbase + kb * 32);
            acc4 = __builtin_amdgcn_mfma_f32_16x16x32_f16(af, bf, acc4, 0, 0, 0);
        }
        #pragma unroll
        for (int r = 0; r < 4; ++r) {
            int o = obi * 16 + g * 4 + r;
            if (o < 81) off[(size_t)o * NSP + n0 + pl] = acc4[r] + obias[o];
        }
    }
}

// ---------------------------------------------------------------------------
// K6: deformable gather + MFMA GEMM.
__global__ __launch_bounds__(256) void k_deform(const float* __restrict__ aT,
        const float* __restrict__ off, const half8* __restrict__ Wp,
        const float* __restrict__ db, float* __restrict__ dcn) {
    __shared__ __align__(16) _Float16 S[16 * 1736];   // 55552 B
    int t = threadIdx.x;
    int n0 = blockIdx.x * 16;
    int lane = t & 63, wv = t >> 6;
    for (int j = wv; j < 432; j += 4) {     // 16 pos * 27 taps
        int p = j / 27, k = j - p * 27;
        int n = n0 + p;
        int h = n >> 10, w = (n >> 5) & 31, d = n & 31;
        float ph = (float)(h + k / 9 - 1)       + off[(size_t)(k * 3 + 0) * NSP + n];
        float pw = (float)(w + (k / 3) % 3 - 1) + off[(size_t)(k * 3 + 1) * NSP + n];
        float pd = (float)(d + k % 3 - 1)       + off[(size_t)(k * 3 + 2) * NSP + n];
        float fh = floorf(ph), fw = floorf(pw), fd = floorf(pd);
        int ih = (int)fh, iw = (int)fw, id = (int)fd;
        float rh = ph - fh, rw = pw - fw, rd = pd - fd;
        float acc = 0.f;
        #pragma unroll
        for (int cb = 0; cb < 8; ++cb) {
            int hh = ih + ((cb >> 2) & 1);
            int wq = iw + ((cb >> 1) & 1);
            int dq = id + (cb & 1);
            float wg = ((cb & 4) ? rh : 1.f - rh) * ((cb & 2) ? rw : 1.f - rw)
                     * ((cb & 1) ? rd : 1.f - rd);
            bool ok = ((unsigned)hh < 32u) & ((unsigned)wq < 32u) & ((unsigned)dq < 32u);
            int fl = ok ? ((hh << 5) + wq) * 32 + dq : 0;
            float v = aT[(size_t)fl * 64 + lane];   // coalesced across lanes
            acc += (ok ? wg : 0.f) * v;
        }
        S[p * 1736 + k * 64 + lane] = (_Float16)acc;
    }
    __syncthreads();
    // GEMM: D[o=wv*16..+15][p=0..15], K = 1728
    f32x4 acc4 = {0.f, 0.f, 0.f, 0.f};
    const half8* wbase = Wp + wv * 64 + lane;                   // +256 per kb
    const _Float16* sbase = &S[(lane & 15) * 1736 + (lane >> 4) * 8];
    #pragma unroll 9
    for (int kb = 0; kb < 54; ++kb) {
        half8 af = wbase[(size_t)kb * 256];
        half8 bf = *(const half8*)(sbase + kb * 32);
        acc4 = __builtin_amdgcn_mfma_f32_16x16x32_f16(af, bf, acc4, 0, 0, 0);
    }
    int pl = lane & 15, g = lane >> 4;
    #pragma unroll
    for (int r = 0; r < 4; ++r) {
        int o = wv * 16 + g * 4 + r;
        dcn[(size_t)o * NSP + n0 + pl] = acc4[r] + db[o];
    }
}

// ---------------------------------------------------------------------------
// K7: a2 = conv1_w @ dcn + b ; h = U * a2 ; out = proj2_w @ h + b2 + x
__global__ __launch_bounds__(256) void k_final(const float* __restrict__ dcn,
        const float* __restrict__ U, const float* __restrict__ x,
        const float* __restrict__ c1w, const float* __restrict__ c1b,
        const float* __restrict__ p2w, const float* __restrict__ p2b,
        float* __restrict__ out) {
    __shared__ float w1[64 * 65];
    __shared__ float w2[64 * 65];
    __shared__ float dv[4][64];
    __shared__ float hv[4][64];
    int t = threadIdx.x;
    int n0 = blockIdx.x * 4;
    for (int i = 0; i < 16; ++i) {
        int idx = i * 256 + t;
        int o = idx >> 6, c = idx & 63;
        w1[o * 65 + c] = c1w[idx];
        w2[o * 65 + c] = p2w[idx];
    }
    int o = t & 63, p = t >> 6;
    int n = n0 + p;
    dv[p][o] = dcn[(size_t)o * NSP + n];
    __syncthreads();
    float acc = c1b[o];
    #pragma unroll
    for (int c = 0; c < 64; ++c) acc += w1[o * 65 + c] * dv[p][c];
    hv[p][o] = U[(size_t)o * NSP + n] * acc;
    __syncthreads();
    float acc2 = p2b[o];
    #pragma unroll
    for (int c = 0; c < 64; ++c) acc2 += w2[o * 65 + c] * hv[p][c];
    acc2 += x[(size_t)n * 64 + o];
    out[(size_t)n * 64 + o] = acc2;
}

// ---------------------------------------------------------------------------
extern "C" void kernel_launch(void* const* d_in, const int* in_sizes, int n_in,
                              void* d_out, int out_size, void* d_ws, size_t ws_size,
                              hipStream_t stream) {
    const float* x   = (const float*)d_in[0];
    const float* p1w = (const float*)d_in[1];
    const float* p1b = (const float*)d_in[2];
    const float* c0w = (const float*)d_in[3];
    const float* c0b = (const float*)d_in[4];
    const float* csw = (const float*)d_in[5];
    const float* csb = (const float*)d_in[6];
    const float* ofw = (const float*)d_in[7];
    const float* ofb = (const float*)d_in[8];
    const float* dcw = (const float*)d_in[9];
    const float* dcb = (const float*)d_in[10];
    const float* c1w = (const float*)d_in[11];
    const float* c1b = (const float*)d_in[12];
    const float* p2w = (const float*)d_in[13];
    const float* p2b = (const float*)d_in[14];
    float* out = (float*)d_out;

    char* ws = (char*)d_ws;
    const size_t CN4 = (size_t)NCH * NSP * 4;       // 8 MiB per [C][N] f32
    float* U    = (float*)(ws);
    float* T0   = (float*)(ws + CN4);
    float* T1   = (float*)(ws + 2 * CN4);
    float* T1T  = (float*)(ws + 3 * CN4);
    float* OFFp = (float*)(ws + 4 * CN4);           // 81*N f32
    float* DCN  = (float*)(ws + 4 * CN4 + (size_t)81 * NSP * 4);
    _Float16* Wp  = (_Float16*)(ws + 5 * CN4 + (size_t)81 * NSP * 4);
    _Float16* Wp2 = Wp + 110592;

    k_proj1    <<<NSP / 64, 256, 0, stream>>>(x, p1w, p1b, U);
    k_dw5      <<<(NCH * NSP) / 256, 256, 0, stream>>>(U, c0w, c0b, T0);
    k_dw7      <<<(NCH * NSP) / 256, 256, 0, stream>>>(T0, csw, csb, T1);
    k_tr       <<<NSP / 64, 256, 0, stream>>>(T1, T1T);
    k_wpack    <<<432, 256, 0, stream>>>(dcw, Wp);
    k_wpack_off<<<648, 256, 0, stream>>>(ofw, Wp2);
    k_offg     <<<NSP / 16, 256, 0, stream>>>(T1T, (const half8*)Wp2, ofb, OFFp);
    k_deform   <<<NSP / 16, 256, 0, stream>>>(T1T, OFFp, (const half8*)Wp, dcb, DCN);
    k_final    <<<NSP / 4, 256, 0, stream>>>(DCN, U, x, c1w, c1b, p2w, p2b, out);
}

// Round 5
// 621.765 us; speedup vs baseline: 4.4276x; 1.2541x over previous
//
#include <hip/hip_runtime.h>
#include <math.h>

#define NSP 32768   // H*W*D = 32*32*32
#define NCH 64

typedef _Float16 half8 __attribute__((ext_vector_type(8)));
typedef float f32x4 __attribute__((ext_vector_type(4)));

// ---------------------------------------------------------------------------
// K1: xv = transpose(x) ; U = gelu(proj1_w @ xv + b)   (U layout: [C][N])
__global__ __launch_bounds__(256) void k_proj1(const float* __restrict__ x,
        const float* __restrict__ w, const float* __restrict__ b,
        float* __restrict__ U) {
    __shared__ float xs[64 * 65];
    int t = threadIdx.x;
    int n0 = blockIdx.x * 64;
    for (int i = 0; i < 16; ++i) {
        int idx = i * 256 + t;
        int p = idx >> 6, c = idx & 63;
        xs[p * 65 + c] = x[(size_t)(n0 + p) * 64 + c];
    }
    __syncthreads();
    int l = t & 63;
    int q = t >> 6;
    for (int oi = 0; oi < 16; ++oi) {
        int o = q * 16 + oi;
        float acc = b[o];
        const float* wr = w + o * 64;
        #pragma unroll
        for (int c = 0; c < 64; ++c) acc += wr[c] * xs[l * 65 + c];
        float g = 0.5f * acc * (1.0f + erff(acc * 0.70710678118654752f));
        U[(size_t)o * NSP + n0 + l] = g;
    }
}

// ---------------------------------------------------------------------------
// K2: depthwise 5x5x5, pad 2.  in/out layout [C][N]
__global__ __launch_bounds__(256) void k_dw5(const float* __restrict__ in,
        const float* __restrict__ w, const float* __restrict__ b,
        float* __restrict__ out) {
    int tid = blockIdx.x * 256 + threadIdx.x;
    int c = tid >> 15, n = tid & 32767;
    int h = n >> 10, ww = (n >> 5) & 31, d = n & 31;
    const float* src = in + (size_t)c * NSP;
    const float* wc = w + c * 125;
    float acc = b[c];
    #pragma unroll
    for (int i = 0; i < 5; ++i) {
        int hh = h + i - 2;
        if ((unsigned)hh >= 32u) continue;
        #pragma unroll
        for (int j = 0; j < 5; ++j) {
            int wj = ww + j - 2;
            if ((unsigned)wj >= 32u) continue;
            const float* row = src + (hh << 10) + (wj << 5);
            const float* wr = wc + i * 25 + j * 5;
            #pragma unroll
            for (int l = 0; l < 5; ++l) {
                int dd = d + l - 2;
                if ((unsigned)dd >= 32u) continue;
                acc += wr[l] * row[dd];
            }
        }
    }
    out[tid] = acc;
}

// ---------------------------------------------------------------------------
// K3: depthwise 7x7x7, dilation 3, pad 9.  in/out layout [C][N]
__global__ __launch_bounds__(256) void k_dw7(const float* __restrict__ in,
        const float* __restrict__ w, const float* __restrict__ b,
        float* __restrict__ out) {
    int tid = blockIdx.x * 256 + threadIdx.x;
    int c = tid >> 15, n = tid & 32767;
    int h = n >> 10, ww = (n >> 5) & 31, d = n & 31;
    const float* src = in + (size_t)c * NSP;
    const float* wc = w + c * 343;
    float acc = b[c];
    for (int i = 0; i < 7; ++i) {
        int hh = h + 3 * i - 9;
        if ((unsigned)hh >= 32u) continue;
        for (int j = 0; j < 7; ++j) {
            int wj = ww + 3 * j - 9;
            if ((unsigned)wj >= 32u) continue;
            const float* row = src + (hh << 10) + (wj << 5);
            const float* wr = wc + i * 49 + j * 7;
            #pragma unroll
            for (int l = 0; l < 7; ++l) {
                int dd = d + 3 * l - 9;
                if ((unsigned)dd >= 32u) continue;
                acc += wr[l] * row[dd];
            }
        }
    }
    out[tid] = acc;
}

// ---------------------------------------------------------------------------
// K4: transpose [C][N] -> [N][C]
__global__ __launch_bounds__(256) void k_tr(const float* __restrict__ in,
        float* __restrict__ out) {
    __shared__ float tile[64 * 65];
    int t = threadIdx.x;
    int n0 = blockIdx.x * 64;
    for (int i = 0; i < 16; ++i) {
        int idx = i * 256 + t;
        int c = idx >> 6, nl = idx & 63;
        tile[c * 65 + nl] = in[(size_t)c * NSP + n0 + nl];
    }
    __syncthreads();
    for (int i = 0; i < 16; ++i) {
        int idx = i * 256 + t;
        int nl = idx >> 6, c = idx & 63;
        out[(size_t)(n0 + nl) * 64 + c] = tile[c * 65 + nl];
    }
}

// ---------------------------------------------------------------------------
// K5a: pre-pack deform weights into f16 MFMA A-fragment order.
// Wp[((kb*4 + ob)*64 + l)*8 + j] = dw[o][c*27+k], o = ob*16 + (l&15),
// K' = kb*32 + (l>>4)*8 + j, k = K'>>6 (tap), c = K'&63 (channel).
__global__ __launch_bounds__(256) void k_wpack(const float* __restrict__ dw,
        _Float16* __restrict__ Wp) {
    int idx = blockIdx.x * 256 + threadIdx.x;   // 0 .. 110591
    int j = idx & 7;
    int l = (idx >> 3) & 63;
    int obk = idx >> 9;
    int ob = obk & 3, kb = obk >> 2;
    int o = ob * 16 + (l & 15);
    int Kp = kb * 32 + (l >> 4) * 8 + j;
    int k = Kp >> 6, c = Kp & 63;
    Wp[idx] = (_Float16)dw[(size_t)o * 1728 + c * 27 + k];
}

// ---------------------------------------------------------------------------
// K5b: pre-pack offset-conv weights, 6 o-blocks of 16 (rows 81..95 = 0).
__global__ __launch_bounds__(256) void k_wpack_off(const float* __restrict__ ow,
        _Float16* __restrict__ Wp2) {
    int idx = blockIdx.x * 256 + threadIdx.x;   // 0 .. 165887
    int j = idx & 7;
    int l = (idx >> 3) & 63;
    int obk = idx >> 9;                          // 0 .. 323
    int ob = obk % 6, kb = obk / 6;
    int o = ob * 16 + (l & 15);
    int Kp = kb * 32 + (l >> 4) * 8 + j;
    int k = Kp >> 6, c = Kp & 63;
    Wp2[idx] = (o < 81) ? (_Float16)ow[(size_t)o * 1728 + c * 27 + k]
                        : (_Float16)0.f;
}

// ---------------------------------------------------------------------------
// K5c: offset conv as im2col + MFMA GEMM.  out off[81][N].
__global__ __launch_bounds__(256) void k_offg(const float* __restrict__ aT,
        const half8* __restrict__ Wp2, const float* __restrict__ obias,
        float* __restrict__ off) {
    __shared__ __align__(16) _Float16 S[16 * 1736];   // 55552 B
    int t = threadIdx.x;
    int n0 = blockIdx.x * 16;
    int lane = t & 63, wv = t >> 6;
    for (int j = wv; j < 432; j += 4) {     // 16 pos * 27 taps
        int p = j / 27, k = j - p * 27;
        int n = n0 + p;
        int h = n >> 10, w = (n >> 5) & 31, d = n & 31;
        int hh = h + k / 9 - 1;
        int wj = w + (k / 3) % 3 - 1;
        int dd = d + k % 3 - 1;
        bool ok = ((unsigned)hh < 32u) & ((unsigned)wj < 32u) & ((unsigned)dd < 32u);
        int fl = ok ? ((hh << 5) + wj) * 32 + dd : 0;
        float v = ok ? aT[(size_t)fl * 64 + lane] : 0.f;
        S[p * 1736 + k * 64 + lane] = (_Float16)v;
    }
    __syncthreads();
    const _Float16* sbase = &S[(lane & 15) * 1736 + (lane >> 4) * 8];
    int pl = lane & 15, g = lane >> 4;
    for (int obi = wv; obi < 6; obi += 4) {
        f32x4 acc4 = {0.f, 0.f, 0.f, 0.f};
        const half8* wbase = Wp2 + obi * 64 + lane;
        #pragma unroll 9
        for (int kb = 0; kb < 54; ++kb) {
            half8 af = wbase[(size_t)kb * 384];          // 6 o-blocks * 64
            half8 bf = *(const half8*)(sbase + kb * 32);
            acc4 = __builtin_amdgcn_mfma_f32_16x16x32_f16(af, bf, acc4, 0, 0, 0);
        }
        #pragma unroll
        for (int r = 0; r < 4; ++r) {
            int o = obi * 16 + g * 4 + r;
            if (o < 81) off[(size_t)o * NSP + n0 + pl] = acc4[r] + obias[o];
        }
    }
}

// ---------------------------------------------------------------------------
// K6: deformable gather + MFMA GEMM, tap-precompute restructure.
// Block = 8 positions, 4 waves.
//  Phase A (lane-parallel): thread t < 216 fully resolves tap (p=t&7, k=t>>3):
//    3 offset reads, floor/frac, 8x {flat*64, trilinear wgt} with validity
//    folded (invalid -> fl=0, wg=0). Stored to TP[t][20] (16B-aligned rows).
//  Phase B: wave-uniform taps: 4x ds_read_b128 broadcast + 8 coalesced
//    aT loads + 8 FMA -> f16 S[p][k*64+c]  (stride 1736: frag reads cheap).
//  Phase C: wave wv = o-block wv; 54 x mfma_f32_16x16x32_f16, A from Wp.
__global__ __launch_bounds__(256) void k_deform(const float* __restrict__ aT,
        const float* __restrict__ off, const half8* __restrict__ Wp,
        const float* __restrict__ db, float* __restrict__ dcn) {
    __shared__ __align__(16) _Float16 S[8 * 1736];    // 27776 B
    __shared__ __align__(16) int TP[216 * 20];        // 17280 B (fl*64 x8, wg x8)
    int t = threadIdx.x;
    int n0 = blockIdx.x * 8;
    int lane = t & 63, wv = t >> 6;

    if (t < 216) {                       // Phase A: per-tap precompute
        int p = t & 7, k = t >> 3;       // k in 0..26
        int n = n0 + p;
        int h = n >> 10, w = (n >> 5) & 31, d = n & 31;
        float ph = (float)(h + k / 9 - 1)       + off[(size_t)(k * 3 + 0) * NSP + n];
        float pw = (float)(w + (k / 3) % 3 - 1) + off[(size_t)(k * 3 + 1) * NSP + n];
        float pd = (float)(d + k % 3 - 1)       + off[(size_t)(k * 3 + 2) * NSP + n];
        float fh = floorf(ph), fw = floorf(pw), fd = floorf(pd);
        int ih = (int)fh, iw = (int)fw, id = (int)fd;
        float rh = ph - fh, rw = pw - fw, rd = pd - fd;
        int* tp = &TP[t * 20];
        #pragma unroll
        for (int cb = 0; cb < 8; ++cb) {
            int hh = ih + ((cb >> 2) & 1);
            int wq = iw + ((cb >> 1) & 1);
            int dq = id + (cb & 1);
            float wg = ((cb & 4) ? rh : 1.f - rh) * ((cb & 2) ? rw : 1.f - rw)
                     * ((cb & 1) ? rd : 1.f - rd);
            bool ok = ((unsigned)hh < 32u) & ((unsigned)wq < 32u) & ((unsigned)dq < 32u);
            tp[cb]     = ok ? (((hh << 5) + wq) * 32 + dq) * 64 : 0;
            ((float*)tp)[8 + cb] = ok ? wg : 0.f;
        }
    }
    __syncthreads();

    for (int j = wv * 54; j < wv * 54 + 54; ++j) {    // Phase B: gather
        int p = j & 7, k = j >> 3;
        const int* tp = &TP[j * 20];
        int4  fa = *(const int4*)(tp);
        int4  fb = *(const int4*)(tp + 4);
        float4 wa = *(const float4*)(tp + 8);
        float4 wb = *(const float4*)(tp + 12);
        float acc = wa.x * aT[fa.x + lane] + wa.y * aT[fa.y + lane]
                  + wa.z * aT[fa.z + lane] + wa.w * aT[fa.w + lane]
                  + wb.x * aT[fb.x + lane] + wb.y * aT[fb.y + lane]
                  + wb.z * aT[fb.z + lane] + wb.w * aT[fb.w + lane];
        S[p * 1736 + k * 64 + lane] = (_Float16)acc;
    }
    __syncthreads();

    // Phase C: GEMM  D[o=wv*16..+15][p=0..7], K = 1728
    f32x4 acc4 = {0.f, 0.f, 0.f, 0.f};
    const half8* wbase = Wp + wv * 64 + lane;                   // +256 per kb
    const _Float16* sbase = &S[(lane & 7) * 1736 + (lane >> 4) * 8];
    #pragma unroll 9
    for (int kb = 0; kb < 54; ++kb) {
        half8 af = wbase[(size_t)kb * 256];
        half8 bf = *(const half8*)(sbase + kb * 32);
        acc4 = __builtin_amdgcn_mfma_f32_16x16x32_f16(af, bf, acc4, 0, 0, 0);
    }
    int pl = lane & 15, g = lane >> 4;
    if (pl < 8) {
        #pragma unroll
        for (int r = 0; r < 4; ++r) {
            int o = wv * 16 + g * 4 + r;
            dcn[(size_t)o * NSP + n0 + pl] = acc4[r] + db[o];
        }
    }
}

// ---------------------------------------------------------------------------
// K7: a2 = conv1_w @ dcn + b ; h = U * a2 ; out = proj2_w @ h + b2 + x
__global__ __launch_bounds__(256) void k_final(const float* __restrict__ dcn,
        const float* __restrict__ U, const float* __restrict__ x,
        const float* __restrict__ c1w, const float* __restrict__ c1b,
        const float* __restrict__ p2w, const float* __restrict__ p2b,
        float* __restrict__ out) {
    __shared__ float w1[64 * 65];
    __shared__ float w2[64 * 65];
    __shared__ float dv[4][64];
    __shared__ float hv[4][64];
    int t = threadIdx.x;
    int n0 = blockIdx.x * 4;
    for (int i = 0; i < 16; ++i) {
        int idx = i * 256 + t;
        int o = idx >> 6, c = idx & 63;
        w1[o * 65 + c] = c1w[idx];
        w2[o * 65 + c] = p2w[idx];
    }
    int o = t & 63, p = t >> 6;
    int n = n0 + p;
    dv[p][o] = dcn[(size_t)o * NSP + n];
    __syncthreads();
    float acc = c1b[o];
    #pragma unroll
    for (int c = 0; c < 64; ++c) acc += w1[o * 65 + c] * dv[p][c];
    hv[p][o] = U[(size_t)o * NSP + n] * acc;
    __syncthreads();
    float acc2 = p2b[o];
    #pragma unroll
    for (int c = 0; c < 64; ++c) acc2 += w2[o * 65 + c] * hv[p][c];
    acc2 += x[(size_t)n * 64 + o];
    out[(size_t)n * 64 + o] = acc2;
}

// ---------------------------------------------------------------------------
extern "C" void kernel_launch(void* const* d_in, const int* in_sizes, int n_in,
                              void* d_out, int out_size, void* d_ws, size_t ws_size,
                              hipStream_t stream) {
    const float* x   = (const float*)d_in[0];
    const float* p1w = (const float*)d_in[1];
    const float* p1b = (const float*)d_in[2];
    const float* c0w = (const float*)d_in[3];
    const float* c0b = (const float*)d_in[4];
    const float* csw = (const float*)d_in[5];
    const float* csb = (const float*)d_in[6];
    const float* ofw = (const float*)d_in[7];
    const float* ofb = (const float*)d_in[8];
    const float* dcw = (const float*)d_in[9];
    const float* dcb = (const float*)d_in[10];
    const float* c1w = (const float*)d_in[11];
    const float* c1b = (const float*)d_in[12];
    const float* p2w = (const float*)d_in[13];
    const float* p2b = (const float*)d_in[14];
    float* out = (float*)d_out;

    char* ws = (char*)d_ws;
    const size_t CN4 = (size_t)NCH * NSP * 4;       // 8 MiB per [C][N] f32
    float* U    = (float*)(ws);
    float* T0   = (float*)(ws + CN4);
    float* T1   = (float*)(ws + 2 * CN4);
    float* T1T  = (float*)(ws + 3 * CN4);
    float* OFFp = (float*)(ws + 4 * CN4);           // 81*N f32
    float* DCN  = (float*)(ws + 4 * CN4 + (size_t)81 * NSP * 4);
    _Float16* Wp  = (_Float16*)(ws + 5 * CN4 + (size_t)81 * NSP * 4);
    _Float16* Wp2 = Wp + 110592;

    k_proj1    <<<NSP / 64, 256, 0, stream>>>(x, p1w, p1b, U);
    k_dw5      <<<(NCH * NSP) / 256, 256, 0, stream>>>(U, c0w, c0b, T0);
    k_dw7      <<<(NCH * NSP) / 256, 256, 0, stream>>>(T0, csw, csb, T1);
    k_tr       <<<NSP / 64, 256, 0, stream>>>(T1, T1T);
    k_wpack    <<<432, 256, 0, stream>>>(dcw, Wp);
    k_wpack_off<<<648, 256, 0, stream>>>(ofw, Wp2);
    k_offg     <<<NSP / 16, 256, 0, stream>>>(T1T, (const half8*)Wp2, ofb, OFFp);
    k_deform   <<<NSP / 8, 256, 0, stream>>>(T1T, OFFp, (const half8*)Wp, dcb, DCN);
    k_final    <<<NSP / 4, 256, 0, stream>>>(DCN, U, x, c1w, c1b, p2w, p2b, out);
}

// Round 6
// 415.229 us; speedup vs baseline: 6.6300x; 1.4974x over previous
//
#include <hip/hip_runtime.h>
#include <math.h>

#define NSP 32768   // H*W*D = 32*32*32
#define NCH 64

typedef _Float16 half8 __attribute__((ext_vector_type(8)));
typedef float f32x4 __attribute__((ext_vector_type(4)));

// ---------------------------------------------------------------------------
// K1: xv = transpose(x) ; U = gelu(proj1_w @ xv + b)   (U layout: [C][N])
__global__ __launch_bounds__(256) void k_proj1(const float* __restrict__ x,
        const float* __restrict__ w, const float* __restrict__ b,
        float* __restrict__ U) {
    __shared__ float xs[64 * 65];
    int t = threadIdx.x;
    int n0 = blockIdx.x * 64;
    for (int i = 0; i < 16; ++i) {
        int idx = i * 256 + t;
        int p = idx >> 6, c = idx & 63;
        xs[p * 65 + c] = x[(size_t)(n0 + p) * 64 + c];
    }
    __syncthreads();
    int l = t & 63;
    int q = t >> 6;
    for (int oi = 0; oi < 16; ++oi) {
        int o = q * 16 + oi;
        float acc = b[o];
        const float* wr = w + o * 64;
        #pragma unroll
        for (int c = 0; c < 64; ++c) acc += wr[c] * xs[l * 65 + c];
        float g = 0.5f * acc * (1.0f + erff(acc * 0.70710678118654752f));
        U[(size_t)o * NSP + n0 + l] = g;
    }
}

// ---------------------------------------------------------------------------
// K2 (new): depthwise 5x5x5, pad 2, register-blocked 4h x 2w.
// Thread = (c, hq, wb, d): outputs h = 4hq+a (a<4), w = 2wb+b (b<2), depth d.
// Per input row m (h' = 4hq+m-2): load v[6 cols][5 dtaps] once, FMA into
// up to 4 h-accs x 2 w-accs. Weights staged in LDS [5][5][8] (b128 reads).
__global__ __launch_bounds__(256) void k_dw5(const float* __restrict__ in,
        const float* __restrict__ w, const float* __restrict__ b,
        float* __restrict__ out) {
    __shared__ __align__(16) float wl[5 * 5 * 8];   // [i][j][l], l padded to 8
    int t = threadIdx.x;
    int blk = blockIdx.x;            // 64c * 8hq * 2wq = 1024
    int c  = blk >> 4;
    int hq = (blk >> 1) & 7;
    int wq = blk & 1;
    int d  = t & 31;
    int wb = wq * 8 + (t >> 5);      // 0..15 ; outputs w = 2wb, 2wb+1
    const float* wc = w + c * 125;
    for (int i = t; i < 125; i += 256) {
        int ii = i / 25, jj = (i / 5) % 5, ll = i % 5;
        wl[ii * 40 + jj * 8 + ll] = wc[i];
    }
    __syncthreads();

    float bc = b[c];
    float acc[4][2];
    #pragma unroll
    for (int a = 0; a < 4; ++a) { acc[a][0] = bc; acc[a][1] = bc; }
    const float* src = in + (size_t)c * NSP;

    #pragma unroll 1
    for (int m = 0; m < 8; ++m) {
        int hh = 4 * hq + m - 2;
        if ((unsigned)hh >= 32u) continue;          // uniform skip
        const float* row = src + (hh << 10);
        float v[6][5];
        #pragma unroll
        for (int jc = 0; jc < 6; ++jc) {
            int wj = 2 * wb + jc - 2;
            bool okw = (unsigned)wj < 32u;
            #pragma unroll
            for (int l = 0; l < 5; ++l) {
                int dd = d + l - 2;
                bool ok = okw && ((unsigned)dd < 32u);
                int off = ok ? (wj << 5) + dd : 0;
                float vv = row[off];
                v[jc][l] = ok ? vv : 0.f;
            }
        }
        #pragma unroll
        for (int a = 0; a < 4; ++a) {
            if (a <= m && m <= a + 4) {             // uniform guard, i = m-a
                const float* wr = &wl[(m - a) * 40];
                float s0 = 0.f, s1 = 0.f;
                #pragma unroll
                for (int j = 0; j < 5; ++j) {
                    float4 wA = *(const float4*)&wr[j * 8];
                    float w4 = wr[j * 8 + 4];
                    s0 += wA.x * v[j][0] + wA.y * v[j][1] + wA.z * v[j][2]
                        + wA.w * v[j][3] + w4 * v[j][4];
                    s1 += wA.x * v[j + 1][0] + wA.y * v[j + 1][1] + wA.z * v[j + 1][2]
                        + wA.w * v[j + 1][3] + w4 * v[j + 1][4];
                }
                acc[a][0] += s0;
                acc[a][1] += s1;
            }
        }
    }
    #pragma unroll
    for (int a = 0; a < 4; ++a)
        #pragma unroll
        for (int bb = 0; bb < 2; ++bb)
            out[(size_t)c * NSP + ((4 * hq + a) << 10) + ((2 * wb + bb) << 5) + d]
                = acc[a][bb];
}

// ---------------------------------------------------------------------------
// K3 (new): depthwise 7x7x7 dilation 3, pad 9, h-residue-class blocked.
// Thread = (c, h0, w, d): computes ALL outputs h = h0+3a (a<11) of its
// residue class. Per valid input row m (h' = h0+3m-9): load v[7][7] once,
// FMA into up to 7 accs. Weights staged in LDS [7][7][8] (b128 reads).
__global__ __launch_bounds__(256) void k_dw7(const float* __restrict__ in,
        const float* __restrict__ w, const float* __restrict__ b,
        float* __restrict__ out) {
    __shared__ __align__(16) float wl[7 * 7 * 8];   // [i][jw][l], l padded to 8
    int t = threadIdx.x;
    int blk = blockIdx.x;            // 64c * 3h0 * 4wq = 768
    int c  = blk / 12;
    int h0 = (blk % 12) >> 2;
    int wq = blk & 3;
    int d  = t & 31;
    int w_ = wq * 8 + (t >> 5);      // 0..31
    const float* wc = w + c * 343;
    for (int i = t; i < 343; i += 256) {
        int ii = i / 49, jj = (i / 7) % 7, ll = i % 7;
        wl[ii * 56 + jj * 8 + ll] = wc[i];
    }
    __syncthreads();

    float bc = b[c];
    float acc[11];
    #pragma unroll
    for (int a = 0; a < 11; ++a) acc[a] = bc;
    const float* src = in + (size_t)c * NSP;

    #pragma unroll 1
    for (int m = 0; m < 17; ++m) {
        int hh = h0 + 3 * m - 9;
        if ((unsigned)hh >= 32u) continue;          // uniform skip (zero-pad rows)
        const float* row = src + (hh << 10);
        float v[7][7];
        #pragma unroll
        for (int jw = 0; jw < 7; ++jw) {
            int wj = w_ + 3 * jw - 9;
            bool okw = (unsigned)wj < 32u;
            #pragma unroll
            for (int l = 0; l < 7; ++l) {
                int dd = d + 3 * l - 9;
                bool ok = okw && ((unsigned)dd < 32u);
                int off = ok ? (wj << 5) + dd : 0;
                float vv = row[off];
                v[jw][l] = ok ? vv : 0.f;
            }
        }
        #pragma unroll
        for (int a = 0; a < 11; ++a) {
            if (a <= m && m <= a + 6) {             // uniform guard, i = m-a
                const float4* wp = (const float4*)&wl[(m - a) * 56];
                float s = 0.f;
                #pragma unroll
                for (int jw = 0; jw < 7; ++jw) {
                    float4 wA = wp[jw * 2];
                    float4 wB = wp[jw * 2 + 1];
                    s += wA.x * v[jw][0] + wA.y * v[jw][1] + wA.z * v[jw][2]
                       + wA.w * v[jw][3] + wB.x * v[jw][4] + wB.y * v[jw][5]
                       + wB.z * v[jw][6];
                }
                acc[a] += s;
            }
        }
    }
    #pragma unroll
    for (int a = 0; a < 11; ++a) {
        int h = h0 + 3 * a;
        if (h < 32)
            out[(size_t)c * NSP + (h << 10) + (w_ << 5) + d] = acc[a];
    }
}

// ---------------------------------------------------------------------------
// K4: transpose [C][N] -> [N][C]
__global__ __launch_bounds__(256) void k_tr(const float* __restrict__ in,
        float* __restrict__ out) {
    __shared__ float tile[64 * 65];
    int t = threadIdx.x;
    int n0 = blockIdx.x * 64;
    for (int i = 0; i < 16; ++i) {
        int idx = i * 256 + t;
        int c = idx >> 6, nl = idx & 63;
        tile[c * 65 + nl] = in[(size_t)c * NSP + n0 + nl];
    }
    __syncthreads();
    for (int i = 0; i < 16; ++i) {
        int idx = i * 256 + t;
        int nl = idx >> 6, c = idx & 63;
        out[(size_t)(n0 + nl) * 64 + c] = tile[c * 65 + nl];
    }
}

// ---------------------------------------------------------------------------
// K5a: pre-pack deform weights into f16 MFMA A-fragment order.
__global__ __launch_bounds__(256) void k_wpack(const float* __restrict__ dw,
        _Float16* __restrict__ Wp) {
    int idx = blockIdx.x * 256 + threadIdx.x;   // 0 .. 110591
    int j = idx & 7;
    int l = (idx >> 3) & 63;
    int obk = idx >> 9;
    int ob = obk & 3, kb = obk >> 2;
    int o = ob * 16 + (l & 15);
    int Kp = kb * 32 + (l >> 4) * 8 + j;
    int k = Kp >> 6, c = Kp & 63;
    Wp[idx] = (_Float16)dw[(size_t)o * 1728 + c * 27 + k];
}

// ---------------------------------------------------------------------------
// K5b: pre-pack offset-conv weights, 6 o-blocks of 16 (rows 81..95 = 0).
__global__ __launch_bounds__(256) void k_wpack_off(const float* __restrict__ ow,
        _Float16* __restrict__ Wp2) {
    int idx = blockIdx.x * 256 + threadIdx.x;   // 0 .. 165887
    int j = idx & 7;
    int l = (idx >> 3) & 63;
    int obk = idx >> 9;                          // 0 .. 323
    int ob = obk % 6, kb = obk / 6;
    int o = ob * 16 + (l & 15);
    int Kp = kb * 32 + (l >> 4) * 8 + j;
    int k = Kp >> 6, c = Kp & 63;
    Wp2[idx] = (o < 81) ? (_Float16)ow[(size_t)o * 1728 + c * 27 + k]
                        : (_Float16)0.f;
}

// ---------------------------------------------------------------------------
// K5c: offset conv as im2col + MFMA GEMM.  out off[81][N].
__global__ __launch_bounds__(256) void k_offg(const float* __restrict__ aT,
        const half8* __restrict__ Wp2, const float* __restrict__ obias,
        float* __restrict__ off) {
    __shared__ __align__(16) _Float16 S[16 * 1736];   // 55552 B
    int t = threadIdx.x;
    int n0 = blockIdx.x * 16;
    int lane = t & 63, wv = t >> 6;
    for (int j = wv; j < 432; j += 4) {     // 16 pos * 27 taps
        int p = j / 27, k = j - p * 27;
        int n = n0 + p;
        int h = n >> 10, w = (n >> 5) & 31, d = n & 31;
        int hh = h + k / 9 - 1;
        int wj = w + (k / 3) % 3 - 1;
        int dd = d + k % 3 - 1;
        bool ok = ((unsigned)hh < 32u) & ((unsigned)wj < 32u) & ((unsigned)dd < 32u);
        int fl = ok ? ((hh << 5) + wj) * 32 + dd : 0;
        float v = ok ? aT[(size_t)fl * 64 + lane] : 0.f;
        S[p * 1736 + k * 64 + lane] = (_Float16)v;
    }
    __syncthreads();
    const _Float16* sbase = &S[(lane & 15) * 1736 + (lane >> 4) * 8];
    int pl = lane & 15, g = lane >> 4;
    for (int obi = wv; obi < 6; obi += 4) {
        f32x4 acc4 = {0.f, 0.f, 0.f, 0.f};
        const half8* wbase = Wp2 + obi * 64 + lane;
        #pragma unroll 9
        for (int kb = 0; kb < 54; ++kb) {
            half8 af = wbase[(size_t)kb * 384];          // 6 o-blocks * 64
            half8 bf = *(const half8*)(sbase + kb * 32);
            acc4 = __builtin_amdgcn_mfma_f32_16x16x32_f16(af, bf, acc4, 0, 0, 0);
        }
        #pragma unroll
        for (int r = 0; r < 4; ++r) {
            int o = obi * 16 + g * 4 + r;
            if (o < 81) off[(size_t)o * NSP + n0 + pl] = acc4[r] + obias[o];
        }
    }
}

// ---------------------------------------------------------------------------
// K6: deformable gather + MFMA GEMM, tap-precompute structure.
__global__ __launch_bounds__(256) void k_deform(const float* __restrict__ aT,
        const float* __restrict__ off, const half8* __restrict__ Wp,
        const float* __restrict__ db, float* __restrict__ dcn) {
    __shared__ __align__(16) _Float16 S[8 * 1736];    // 27776 B
    __shared__ __align__(16) int TP[216 * 20];        // 17280 B (fl*64 x8, wg x8)
    int t = threadIdx.x;
    int n0 = blockIdx.x * 8;
    int lane = t & 63, wv = t >> 6;

    if (t < 216) {                       // Phase A: per-tap precompute
        int p = t & 7, k = t >> 3;       // k in 0..26
        int n = n0 + p;
        int h = n >> 10, w = (n >> 5) & 31, d = n & 31;
        float ph = (float)(h + k / 9 - 1)       + off[(size_t)(k * 3 + 0) * NSP + n];
        float pw = (float)(w + (k / 3) % 3 - 1) + off[(size_t)(k * 3 + 1) * NSP + n];
        float pd = (float)(d + k % 3 - 1)       + off[(size_t)(k * 3 + 2) * NSP + n];
        float fh = floorf(ph), fw = floorf(pw), fd = floorf(pd);
        int ih = (int)fh, iw = (int)fw, id = (int)fd;
        float rh = ph - fh, rw = pw - fw, rd = pd - fd;
        int* tp = &TP[t * 20];
        #pragma unroll
        for (int cb = 0; cb < 8; ++cb) {
            int hh = ih + ((cb >> 2) & 1);
            int wq = iw + ((cb >> 1) & 1);
            int dq = id + (cb & 1);
            float wg = ((cb & 4) ? rh : 1.f - rh) * ((cb & 2) ? rw : 1.f - rw)
                     * ((cb & 1) ? rd : 1.f - rd);
            bool ok = ((unsigned)hh < 32u) & ((unsigned)wq < 32u) & ((unsigned)dq < 32u);
            tp[cb]     = ok ? (((hh << 5) + wq) * 32 + dq) * 64 : 0;
            ((float*)tp)[8 + cb] = ok ? wg : 0.f;
        }
    }
    __syncthreads();

    for (int j = wv * 54; j < wv * 54 + 54; ++j) {    // Phase B: gather
        int p = j & 7, k = j >> 3;
        const int* tp = &TP[j * 20];
        int4  fa = *(const int4*)(tp);
        int4  fb = *(const int4*)(tp + 4);
        float4 wa = *(const float4*)(tp + 8);
        float4 wb = *(const float4*)(tp + 12);
        float acc = wa.x * aT[fa.x + lane] + wa.y * aT[fa.y + lane]
                  + wa.z * aT[fa.z + lane] + wa.w * aT[fa.w + lane]
                  + wb.x * aT[fb.x + lane] + wb.y * aT[fb.y + lane]
                  + wb.z * aT[fb.z + lane] + wb.w * aT[fb.w + lane];
        S[p * 1736 + k * 64 + lane] = (_Float16)acc;
    }
    __syncthreads();

    // Phase C: GEMM  D[o=wv*16..+15][p=0..7], K = 1728
    f32x4 acc4 = {0.f, 0.f, 0.f, 0.f};
    const half8* wbase = Wp + wv * 64 + lane;                   // +256 per kb
    const _Float16* sbase = &S[(lane & 7) * 1736 + (lane >> 4) * 8];
    #pragma unroll 9
    for (int kb = 0; kb < 54; ++kb) {
        half8 af = wbase[(size_t)kb * 256];
        half8 bf = *(const half8*)(sbase + kb * 32);
        acc4 = __builtin_amdgcn_mfma_f32_16x16x32_f16(af, bf, acc4, 0, 0, 0);
    }
    int pl = lane & 15, g = lane >> 4;
    if (pl < 8) {
        #pragma unroll
        for (int r = 0; r < 4; ++r) {
            int o = wv * 16 + g * 4 + r;
            dcn[(size_t)o * NSP + n0 + pl] = acc4[r] + db[o];
        }
    }
}

// ---------------------------------------------------------------------------
// K7: a2 = conv1_w @ dcn + b ; h = U * a2 ; out = proj2_w @ h + b2 + x
__global__ __launch_bounds__(256) void k_final(const float* __restrict__ dcn,
        const float* __restrict__ U, const float* __restrict__ x,
        const float* __restrict__ c1w, const float* __restrict__ c1b,
        const float* __restrict__ p2w, const float* __restrict__ p2b,
        float* __restrict__ out) {
    __shared__ float w1[64 * 65];
    __shared__ float w2[64 * 65];
    __shared__ float dv[4][64];
    __shared__ float hv[4][64];
    int t = threadIdx.x;
    int n0 = blockIdx.x * 4;
    for (int i = 0; i < 16; ++i) {
        int idx = i * 256 + t;
        int o = idx >> 6, c = idx & 63;
        w1[o * 65 + c] = c1w[idx];
        w2[o * 65 + c] = p2w[idx];
    }
    int o = t & 63, p = t >> 6;
    int n = n0 + p;
    dv[p][o] = dcn[(size_t)o * NSP + n];
    __syncthreads();
    float acc = c1b[o];
    #pragma unroll
    for (int c = 0; c < 64; ++c) acc += w1[o * 65 + c] * dv[p][c];
    hv[p][o] = U[(size_t)o * NSP + n] * acc;
    __syncthreads();
    float acc2 = p2b[o];
    #pragma unroll
    for (int c = 0; c < 64; ++c) acc2 += w2[o * 65 + c] * hv[p][c];
    acc2 += x[(size_t)n * 64 + o];
    out[(size_t)n * 64 + o] = acc2;
}

// ---------------------------------------------------------------------------
extern "C" void kernel_launch(void* const* d_in, const int* in_sizes, int n_in,
                              void* d_out, int out_size, void* d_ws, size_t ws_size,
                              hipStream_t stream) {
    const float* x   = (const float*)d_in[0];
    const float* p1w = (const float*)d_in[1];
    const float* p1b = (const float*)d_in[2];
    const float* c0w = (const float*)d_in[3];
    const float* c0b = (const float*)d_in[4];
    const float* csw = (const float*)d_in[5];
    const float* csb = (const float*)d_in[6];
    const float* ofw = (const float*)d_in[7];
    const float* ofb = (const float*)d_in[8];
    const float* dcw = (const float*)d_in[9];
    const float* dcb = (const float*)d_in[10];
    const float* c1w = (const float*)d_in[11];
    const float* c1b = (const float*)d_in[12];
    const float* p2w = (const float*)d_in[13];
    const float* p2b = (const float*)d_in[14];
    float* out = (float*)d_out;

    char* ws = (char*)d_ws;
    const size_t CN4 = (size_t)NCH * NSP * 4;       // 8 MiB per [C][N] f32
    float* U    = (float*)(ws);
    float* T0   = (float*)(ws + CN4);
    float* T1   = (float*)(ws + 2 * CN4);
    float* T1T  = (float*)(ws + 3 * CN4);
    float* OFFp = (float*)(ws + 4 * CN4);           // 81*N f32
    float* DCN  = (float*)(ws + 4 * CN4 + (size_t)81 * NSP * 4);
    _Float16* Wp  = (_Float16*)(ws + 5 * CN4 + (size_t)81 * NSP * 4);
    _Float16* Wp2 = Wp + 110592;

    k_proj1    <<<NSP / 64, 256, 0, stream>>>(x, p1w, p1b, U);
    k_dw5      <<<1024, 256, 0, stream>>>(U, c0w, c0b, T0);
    k_dw7      <<<768, 256, 0, stream>>>(T0, csw, csb, T1);
    k_tr       <<<NSP / 64, 256, 0, stream>>>(T1, T1T);
    k_wpack    <<<432, 256, 0, stream>>>(dcw, Wp);
    k_wpack_off<<<648, 256, 0, stream>>>(ofw, Wp2);
    k_offg     <<<NSP / 16, 256, 0, stream>>>(T1T, (const half8*)Wp2, ofb, OFFp);
    k_deform   <<<NSP / 8, 256, 0, stream>>>(T1T, OFFp, (const half8*)Wp, dcb, DCN);
    k_final    <<<NSP / 4, 256, 0, stream>>>(DCN, U, x, c1w, c1b, p2w, p2b, out);
}

// Round 7
// 333.684 us; speedup vs baseline: 8.2502x; 1.2444x over previous
//
#include <hip/hip_runtime.h>
#include <math.h>

#define NSP 32768   // H*W*D = 32*32*32
#define NCH 64

typedef _Float16 half8 __attribute__((ext_vector_type(8)));
typedef float f32x4 __attribute__((ext_vector_type(4)));

// ---------------------------------------------------------------------------
// K1: xv = transpose(x) ; U = gelu(proj1_w @ xv + b)   (U layout: [C][N])
__global__ __launch_bounds__(256) void k_proj1(const float* __restrict__ x,
        const float* __restrict__ w, const float* __restrict__ b,
        float* __restrict__ U) {
    __shared__ float xs[64 * 65];
    int t = threadIdx.x;
    int n0 = blockIdx.x * 64;
    for (int i = 0; i < 16; ++i) {
        int idx = i * 256 + t;
        int p = idx >> 6, c = idx & 63;
        xs[p * 65 + c] = x[(size_t)(n0 + p) * 64 + c];
    }
    __syncthreads();
    int l = t & 63;
    int q = t >> 6;
    for (int oi = 0; oi < 16; ++oi) {
        int o = q * 16 + oi;
        float acc = b[o];
        const float* wr = w + o * 64;
        #pragma unroll
        for (int c = 0; c < 64; ++c) acc += wr[c] * xs[l * 65 + c];
        float g = 0.5f * acc * (1.0f + erff(acc * 0.70710678118654752f));
        U[(size_t)o * NSP + n0 + l] = g;
    }
}

// ---------------------------------------------------------------------------
// K2: depthwise 5x5x5, pad 2, register-blocked 4h x 2w.
__global__ __launch_bounds__(256) void k_dw5(const float* __restrict__ in,
        const float* __restrict__ w, const float* __restrict__ b,
        float* __restrict__ out) {
    __shared__ __align__(16) float wl[5 * 5 * 8];   // [i][j][l], l padded to 8
    int t = threadIdx.x;
    int blk = blockIdx.x;            // 64c * 8hq * 2wq = 1024
    int c  = blk >> 4;
    int hq = (blk >> 1) & 7;
    int wq = blk & 1;
    int d  = t & 31;
    int wb = wq * 8 + (t >> 5);      // 0..15 ; outputs w = 2wb, 2wb+1
    const float* wc = w + c * 125;
    for (int i = t; i < 125; i += 256) {
        int ii = i / 25, jj = (i / 5) % 5, ll = i % 5;
        wl[ii * 40 + jj * 8 + ll] = wc[i];
    }
    __syncthreads();

    float bc = b[c];
    float acc[4][2];
    #pragma unroll
    for (int a = 0; a < 4; ++a) { acc[a][0] = bc; acc[a][1] = bc; }
    const float* src = in + (size_t)c * NSP;

    #pragma unroll 1
    for (int m = 0; m < 8; ++m) {
        int hh = 4 * hq + m - 2;
        if ((unsigned)hh >= 32u) continue;          // uniform skip
        const float* row = src + (hh << 10);
        float v[6][5];
        #pragma unroll
        for (int jc = 0; jc < 6; ++jc) {
            int wj = 2 * wb + jc - 2;
            bool okw = (unsigned)wj < 32u;
            #pragma unroll
            for (int l = 0; l < 5; ++l) {
                int dd = d + l - 2;
                bool ok = okw && ((unsigned)dd < 32u);
                int off = ok ? (wj << 5) + dd : 0;
                float vv = row[off];
                v[jc][l] = ok ? vv : 0.f;
            }
        }
        #pragma unroll
        for (int a = 0; a < 4; ++a) {
            if (a <= m && m <= a + 4) {             // uniform guard, i = m-a
                const float* wr = &wl[(m - a) * 40];
                float s0 = 0.f, s1 = 0.f;
                #pragma unroll
                for (int j = 0; j < 5; ++j) {
                    float4 wA = *(const float4*)&wr[j * 8];
                    float w4 = wr[j * 8 + 4];
                    s0 += wA.x * v[j][0] + wA.y * v[j][1] + wA.z * v[j][2]
                        + wA.w * v[j][3] + w4 * v[j][4];
                    s1 += wA.x * v[j + 1][0] + wA.y * v[j + 1][1] + wA.z * v[j + 1][2]
                        + wA.w * v[j + 1][3] + w4 * v[j + 1][4];
                }
                acc[a][0] += s0;
                acc[a][1] += s1;
            }
        }
    }
    #pragma unroll
    for (int a = 0; a < 4; ++a)
        #pragma unroll
        for (int bb = 0; bb < 2; ++bb)
            out[(size_t)c * NSP + ((4 * hq + a) << 10) + ((2 * wb + bb) << 5) + d]
                = acc[a][bb];
}

// ---------------------------------------------------------------------------
// K3: depthwise 7x7x7 dilation 3, pad 9, h-residue-class blocked.
__global__ __launch_bounds__(256) void k_dw7(const float* __restrict__ in,
        const float* __restrict__ w, const float* __restrict__ b,
        float* __restrict__ out) {
    __shared__ __align__(16) float wl[7 * 7 * 8];   // [i][jw][l], l padded to 8
    int t = threadIdx.x;
    int blk = blockIdx.x;            // 64c * 3h0 * 4wq = 768
    int c  = blk / 12;
    int h0 = (blk % 12) >> 2;
    int wq = blk & 3;
    int d  = t & 31;
    int w_ = wq * 8 + (t >> 5);      // 0..31
    const float* wc = w + c * 343;
    for (int i = t; i < 343; i += 256) {
        int ii = i / 49, jj = (i / 7) % 7, ll = i % 7;
        wl[ii * 56 + jj * 8 + ll] = wc[i];
    }
    __syncthreads();

    float bc = b[c];
    float acc[11];
    #pragma unroll
    for (int a = 0; a < 11; ++a) acc[a] = bc;
    const float* src = in + (size_t)c * NSP;

    #pragma unroll 1
    for (int m = 0; m < 17; ++m) {
        int hh = h0 + 3 * m - 9;
        if ((unsigned)hh >= 32u) continue;          // uniform skip (zero-pad rows)
        const float* row = src + (hh << 10);
        float v[7][7];
        #pragma unroll
        for (int jw = 0; jw < 7; ++jw) {
            int wj = w_ + 3 * jw - 9;
            bool okw = (unsigned)wj < 32u;
            #pragma unroll
            for (int l = 0; l < 7; ++l) {
                int dd = d + 3 * l - 9;
                bool ok = okw && ((unsigned)dd < 32u);
                int off = ok ? (wj << 5) + dd : 0;
                float vv = row[off];
                v[jw][l] = ok ? vv : 0.f;
            }
        }
        #pragma unroll
        for (int a = 0; a < 11; ++a) {
            if (a <= m && m <= a + 6) {             // uniform guard, i = m-a
                const float4* wp = (const float4*)&wl[(m - a) * 56];
                float s = 0.f;
                #pragma unroll
                for (int jw = 0; jw < 7; ++jw) {
                    float4 wA = wp[jw * 2];
                    float4 wB = wp[jw * 2 + 1];
                    s += wA.x * v[jw][0] + wA.y * v[jw][1] + wA.z * v[jw][2]
                       + wA.w * v[jw][3] + wB.x * v[jw][4] + wB.y * v[jw][5]
                       + wB.z * v[jw][6];
                }
                acc[a] += s;
            }
        }
    }
    #pragma unroll
    for (int a = 0; a < 11; ++a) {
        int h = h0 + 3 * a;
        if (h < 32)
            out[(size_t)c * NSP + (h << 10) + (w_ << 5) + d] = acc[a];
    }
}

// ---------------------------------------------------------------------------
// K4: transpose [C][N] -> [N][C]
__global__ __launch_bounds__(256) void k_tr(const float* __restrict__ in,
        float* __restrict__ out) {
    __shared__ float tile[64 * 65];
    int t = threadIdx.x;
    int n0 = blockIdx.x * 64;
    for (int i = 0; i < 16; ++i) {
        int idx = i * 256 + t;
        int c = idx >> 6, nl = idx & 63;
        tile[c * 65 + nl] = in[(size_t)c * NSP + n0 + nl];
    }
    __syncthreads();
    for (int i = 0; i < 16; ++i) {
        int idx = i * 256 + t;
        int nl = idx >> 6, c = idx & 63;
        out[(size_t)(n0 + nl) * 64 + c] = tile[c * 65 + nl];
    }
}

// ---------------------------------------------------------------------------
// K5a: pre-pack deform weights into f16 MFMA A-fragment order.
__global__ __launch_bounds__(256) void k_wpack(const float* __restrict__ dw,
        _Float16* __restrict__ Wp) {
    int idx = blockIdx.x * 256 + threadIdx.x;   // 0 .. 110591
    int j = idx & 7;
    int l = (idx >> 3) & 63;
    int obk = idx >> 9;
    int ob = obk & 3, kb = obk >> 2;
    int o = ob * 16 + (l & 15);
    int Kp = kb * 32 + (l >> 4) * 8 + j;
    int k = Kp >> 6, c = Kp & 63;
    Wp[idx] = (_Float16)dw[(size_t)o * 1728 + c * 27 + k];
}

// ---------------------------------------------------------------------------
// K5b: pre-pack offset-conv weights, 6 o-blocks of 16 (rows 81..95 = 0).
__global__ __launch_bounds__(256) void k_wpack_off(const float* __restrict__ ow,
        _Float16* __restrict__ Wp2) {
    int idx = blockIdx.x * 256 + threadIdx.x;   // 0 .. 165887
    int j = idx & 7;
    int l = (idx >> 3) & 63;
    int obk = idx >> 9;                          // 0 .. 323
    int ob = obk % 6, kb = obk / 6;
    int o = ob * 16 + (l & 15);
    int Kp = kb * 32 + (l >> 4) * 8 + j;
    int k = Kp >> 6, c = Kp & 63;
    Wp2[idx] = (o < 81) ? (_Float16)ow[(size_t)o * 1728 + c * 27 + k]
                        : (_Float16)0.f;
}

// ---------------------------------------------------------------------------
// K5c (new): offset conv via non-duplicated halo tile + MFMA.
// Block = one full d-row (32 positions at fixed h,w), grid 1024.
// Phase B: stage S2[9 hw-nbrs][34 d][72-padded ch] f16 (44 KB) - only 306
//   wave-loads (vs 864 im2col-duplicated). Zero-filled at volume edges.
// Phase C: 12 units (6 o-blocks x 2 p-tiles) / 4 waves = 3 each (balanced).
//   Within one kb (K=32 slice), tap k = kb>>1 is CONSTANT -> B-frag is one
//   ds_read_b128 at compile-time offset (kb loop fully unrolled):
//   value = S2[hwn(k)][p + k%3][c], c = (kb&1)*32 + (lane>>4)*8 + j.
//   Row stride 72 f16 = 36 words (4 mod 32): lanes spread all banks evenly.
__global__ __launch_bounds__(256) void k_offg(const float* __restrict__ aT,
        const half8* __restrict__ Wp2, const float* __restrict__ obias,
        float* __restrict__ off) {
    __shared__ __align__(16) _Float16 S2[9 * 34 * 72];   // 44064 B
    int t = threadIdx.x;
    int blk = blockIdx.x;            // 32h * 32w
    int h = blk >> 5, w = blk & 31;
    int n0 = blk << 5;
    int lane = t & 63, wv = t >> 6;

    #pragma unroll
    for (int hwn = 0; hwn < 9; ++hwn) {          // Phase B
        int hh = h + hwn / 3 - 1;                // hwn literal -> folds
        int wj = w + hwn % 3 - 1;
        bool okhw = ((unsigned)hh < 32u) & ((unsigned)wj < 32u);
        int rowb = (hh << 5) + wj;               // spatial (h,w) row id
        for (int dd = wv; dd < 34; dd += 4) {
            int di = dd - 1;
            bool ok = okhw & ((unsigned)di < 32u);
            float v = ok ? aT[(size_t)((rowb << 5) + di) * 64 + lane] : 0.f;
            S2[(hwn * 34 + dd) * 72 + lane] = (_Float16)v;
        }
    }
    __syncthreads();

    int pl = lane & 15, g = lane >> 4;
    #pragma unroll 1
    for (int u = 0; u < 3; ++u) {
        int unit = wv * 3 + u;                   // 0..11
        int obi = unit >> 1, pt = unit & 1;
        f32x4 acc4 = {0.f, 0.f, 0.f, 0.f};
        const half8* wb = Wp2 + obi * 64 + lane;
        const _Float16* sb = &S2[(pt * 16 + pl) * 72 + g * 8];
        #pragma unroll
        for (int kb = 0; kb < 54; ++kb) {        // full unroll: offsets fold
            int k = kb >> 1;
            int hwn = (k / 9) * 3 + (k / 3) % 3;
            int kd = k % 3;
            half8 bf = *(const half8*)(sb + (hwn * 34 + kd) * 72 + (kb & 1) * 32);
            half8 af = wb[(size_t)kb * 384];     // 6 o-blocks * 64 lanes
            acc4 = __builtin_amdgcn_mfma_f32_16x16x32_f16(af, bf, acc4, 0, 0, 0);
        }
        #pragma unroll
        for (int r = 0; r < 4; ++r) {
            int o = obi * 16 + g * 4 + r;
            if (o < 81) off[(size_t)o * NSP + n0 + pt * 16 + pl] = acc4[r] + obias[o];
        }
    }
}

// ---------------------------------------------------------------------------
// K6: deformable gather + MFMA GEMM, tap-precompute structure.
__global__ __launch_bounds__(256) void k_deform(const float* __restrict__ aT,
        const float* __restrict__ off, const half8* __restrict__ Wp,
        const float* __restrict__ db, float* __restrict__ dcn) {
    __shared__ __align__(16) _Float16 S[8 * 1736];    // 27776 B
    __shared__ __align__(16) int TP[216 * 20];        // 17280 B (fl*64 x8, wg x8)
    int t = threadIdx.x;
    int n0 = blockIdx.x * 8;
    int lane = t & 63, wv = t >> 6;

    if (t < 216) {                       // Phase A: per-tap precompute
        int p = t & 7, k = t >> 3;       // k in 0..26
        int n = n0 + p;
        int h = n >> 10, w = (n >> 5) & 31, d = n & 31;
        float ph = (float)(h + k / 9 - 1)       + off[(size_t)(k * 3 + 0) * NSP + n];
        float pw = (float)(w + (k / 3) % 3 - 1) + off[(size_t)(k * 3 + 1) * NSP + n];
        float pd = (float)(d + k % 3 - 1)       + off[(size_t)(k * 3 + 2) * NSP + n];
        float fh = floorf(ph), fw = floorf(pw), fd = floorf(pd);
        int ih = (int)fh, iw = (int)fw, id = (int)fd;
        float rh = ph - fh, rw = pw - fw, rd = pd - fd;
        int* tp = &TP[t * 20];
        #pragma unroll
        for (int cb = 0; cb < 8; ++cb) {
            int hh = ih + ((cb >> 2) & 1);
            int wq = iw + ((cb >> 1) & 1);
            int dq = id + (cb & 1);
            float wg = ((cb & 4) ? rh : 1.f - rh) * ((cb & 2) ? rw : 1.f - rw)
                     * ((cb & 1) ? rd : 1.f - rd);
            bool ok = ((unsigned)hh < 32u) & ((unsigned)wq < 32u) & ((unsigned)dq < 32u);
            tp[cb]     = ok ? (((hh << 5) + wq) * 32 + dq) * 64 : 0;
            ((float*)tp)[8 + cb] = ok ? wg : 0.f;
        }
    }
    __syncthreads();

    for (int j = wv * 54; j < wv * 54 + 54; ++j) {    // Phase B: gather
        int p = j & 7, k = j >> 3;
        const int* tp = &TP[j * 20];
        int4  fa = *(const int4*)(tp);
        int4  fb = *(const int4*)(tp + 4);
        float4 wa = *(const float4*)(tp + 8);
        float4 wb = *(const float4*)(tp + 12);
        float acc = wa.x * aT[fa.x + lane] + wa.y * aT[fa.y + lane]
                  + wa.z * aT[fa.z + lane] + wa.w * aT[fa.w + lane]
                  + wb.x * aT[fb.x + lane] + wb.y * aT[fb.y + lane]
                  + wb.z * aT[fb.z + lane] + wb.w * aT[fb.w + lane];
        S[p * 1736 + k * 64 + lane] = (_Float16)acc;
    }
    __syncthreads();

    // Phase C: GEMM  D[o=wv*16..+15][p=0..7], K = 1728
    f32x4 acc4 = {0.f, 0.f, 0.f, 0.f};
    const half8* wbase = Wp + wv * 64 + lane;                   // +256 per kb
    const _Float16* sbase = &S[(lane & 7) * 1736 + (lane >> 4) * 8];
    #pragma unroll 9
    for (int kb = 0; kb < 54; ++kb) {
        half8 af = wbase[(size_t)kb * 256];
        half8 bf = *(const half8*)(sbase + kb * 32);
        acc4 = __builtin_amdgcn_mfma_f32_16x16x32_f16(af, bf, acc4, 0, 0, 0);
    }
    int pl = lane & 15, g = lane >> 4;
    if (pl < 8) {
        #pragma unroll
        for (int r = 0; r < 4; ++r) {
            int o = wv * 16 + g * 4 + r;
            dcn[(size_t)o * NSP + n0 + pl] = acc4[r] + db[o];
        }
    }
}

// ---------------------------------------------------------------------------
// K7: a2 = conv1_w @ dcn + b ; h = U * a2 ; out = proj2_w @ h + b2 + x
__global__ __launch_bounds__(256) void k_final(const float* __restrict__ dcn,
        const float* __restrict__ U, const float* __restrict__ x,
        const float* __restrict__ c1w, const float* __restrict__ c1b,
        const float* __restrict__ p2w, const float* __restrict__ p2b,
        float* __restrict__ out) {
    __shared__ float w1[64 * 65];
    __shared__ float w2[64 * 65];
    __shared__ float dv[4][64];
    __shared__ float hv[4][64];
    int t = threadIdx.x;
    int n0 = blockIdx.x * 4;
    for (int i = 0; i < 16; ++i) {
        int idx = i * 256 + t;
        int o = idx >> 6, c = idx & 63;
        w1[o * 65 + c] = c1w[idx];
        w2[o * 65 + c] = p2w[idx];
    }
    int o = t & 63, p = t >> 6;
    int n = n0 + p;
    dv[p][o] = dcn[(size_t)o * NSP + n];
    __syncthreads();
    float acc = c1b[o];
    #pragma unroll
    for (int c = 0; c < 64; ++c) acc += w1[o * 65 + c] * dv[p][c];
    hv[p][o] = U[(size_t)o * NSP + n] * acc;
    __syncthreads();
    float acc2 = p2b[o];
    #pragma unroll
    for (int c = 0; c < 64; ++c) acc2 += w2[o * 65 + c] * hv[p][c];
    acc2 += x[(size_t)n * 64 + o];
    out[(size_t)n * 64 + o] = acc2;
}

// ---------------------------------------------------------------------------
extern "C" void kernel_launch(void* const* d_in, const int* in_sizes, int n_in,
                              void* d_out, int out_size, void* d_ws, size_t ws_size,
                              hipStream_t stream) {
    const float* x   = (const float*)d_in[0];
    const float* p1w = (const float*)d_in[1];
    const float* p1b = (const float*)d_in[2];
    const float* c0w = (const float*)d_in[3];
    const float* c0b = (const float*)d_in[4];
    const float* csw = (const float*)d_in[5];
    const float* csb = (const float*)d_in[6];
    const float* ofw = (const float*)d_in[7];
    const float* ofb = (const float*)d_in[8];
    const float* dcw = (const float*)d_in[9];
    const float* dcb = (const float*)d_in[10];
    const float* c1w = (const float*)d_in[11];
    const float* c1b = (const float*)d_in[12];
    const float* p2w = (const float*)d_in[13];
    const float* p2b = (const float*)d_in[14];
    float* out = (float*)d_out;

    char* ws = (char*)d_ws;
    const size_t CN4 = (size_t)NCH * NSP * 4;       // 8 MiB per [C][N] f32
    float* U    = (float*)(ws);
    float* T0   = (float*)(ws + CN4);
    float* T1   = (float*)(ws + 2 * CN4);
    float* T1T  = (float*)(ws + 3 * CN4);
    float* OFFp = (float*)(ws + 4 * CN4);           // 81*N f32
    float* DCN  = (float*)(ws + 4 * CN4 + (size_t)81 * NSP * 4);
    _Float16* Wp  = (_Float16*)(ws + 5 * CN4 + (size_t)81 * NSP * 4);
    _Float16* Wp2 = Wp + 110592;

    k_proj1    <<<NSP / 64, 256, 0, stream>>>(x, p1w, p1b, U);
    k_dw5      <<<1024, 256, 0, stream>>>(U, c0w, c0b, T0);
    k_dw7      <<<768, 256, 0, stream>>>(T0, csw, csb, T1);
    k_tr       <<<NSP / 64, 256, 0, stream>>>(T1, T1T);
    k_wpack    <<<432, 256, 0, stream>>>(dcw, Wp);
    k_wpack_off<<<648, 256, 0, stream>>>(ofw, Wp2);
    k_offg     <<<1024, 256, 0, stream>>>(T1T, (const half8*)Wp2, ofb, OFFp);
    k_deform   <<<NSP / 8, 256, 0, stream>>>(T1T, OFFp, (const half8*)Wp, dcb, DCN);
    k_final    <<<NSP / 4, 256, 0, stream>>>(DCN, U, x, c1w, c1b, p2w, p2b, out);
}

// Round 8
// 260.933 us; speedup vs baseline: 10.5504x; 1.2788x over previous
//
#include <hip/hip_runtime.h>
#include <math.h>

#define NSP 32768   // H*W*D = 32*32*32
#define NCH 64

typedef _Float16 half8 __attribute__((ext_vector_type(8)));
typedef _Float16 half4 __attribute__((ext_vector_type(4)));
typedef _Float16 half2v __attribute__((ext_vector_type(2)));
typedef float f32x4 __attribute__((ext_vector_type(4)));

union h2u { half2v h; unsigned int u; };

// ---------------------------------------------------------------------------
// K1 (MFMA): U = gelu(proj1_w @ x^T + b)   (U layout: [C][N])
__global__ __launch_bounds__(256) void k_proj1m(const float* __restrict__ x,
        const half8* __restrict__ Wp1, const float* __restrict__ b,
        float* __restrict__ U) {
    __shared__ __align__(16) _Float16 Sx[64 * 72];   // 9216 B
    int t = threadIdx.x;
    int n0 = blockIdx.x * 64;
    int lane = t & 63, wv = t >> 6;
    for (int i = wv; i < 64; i += 4) {
        float v = x[(size_t)(n0 + i) * 64 + lane];
        Sx[i * 72 + lane] = (_Float16)v;
    }
    __syncthreads();
    int pl = lane & 15, g = lane >> 4;
    int ob = wv;
    const half8* wbase = Wp1 + ob * 64 + lane;       // +256 per kb
    #pragma unroll
    for (int nt = 0; nt < 4; ++nt) {
        f32x4 acc4 = {0.f, 0.f, 0.f, 0.f};
        const _Float16* sb = &Sx[(nt * 16 + pl) * 72 + g * 8];
        #pragma unroll
        for (int kb = 0; kb < 2; ++kb) {
            half8 af = wbase[kb * 256];
            half8 bf = *(const half8*)(sb + kb * 32);
            acc4 = __builtin_amdgcn_mfma_f32_16x16x32_f16(af, bf, acc4, 0, 0, 0);
        }
        int n = n0 + nt * 16 + pl;
        #pragma unroll
        for (int r = 0; r < 4; ++r) {
            int o = ob * 16 + g * 4 + r;
            float a = acc4[r] + b[o];
            float gv = 0.5f * a * (1.0f + erff(a * 0.70710678118654752f));
            U[(size_t)o * NSP + n] = gv;
        }
    }
}

// ---------------------------------------------------------------------------
// K2: depthwise 5x5x5, pad 2, register-blocked 4h x 2w.
__global__ __launch_bounds__(256) void k_dw5(const float* __restrict__ in,
        const float* __restrict__ w, const float* __restrict__ b,
        float* __restrict__ out) {
    __shared__ __align__(16) float wl[5 * 5 * 8];
    int t = threadIdx.x;
    int blk = blockIdx.x;            // 64c * 8hq * 2wq = 1024
    int c  = blk >> 4;
    int hq = (blk >> 1) & 7;
    int wq = blk & 1;
    int d  = t & 31;
    int wb = wq * 8 + (t >> 5);
    const float* wc = w + c * 125;
    for (int i = t; i < 125; i += 256) {
        int ii = i / 25, jj = (i / 5) % 5, ll = i % 5;
        wl[ii * 40 + jj * 8 + ll] = wc[i];
    }
    __syncthreads();

    float bc = b[c];
    float acc[4][2];
    #pragma unroll
    for (int a = 0; a < 4; ++a) { acc[a][0] = bc; acc[a][1] = bc; }
    const float* src = in + (size_t)c * NSP;

    #pragma unroll 1
    for (int m = 0; m < 8; ++m) {
        int hh = 4 * hq + m - 2;
        if ((unsigned)hh >= 32u) continue;
        const float* row = src + (hh << 10);
        float v[6][5];
        #pragma unroll
        for (int jc = 0; jc < 6; ++jc) {
            int wj = 2 * wb + jc - 2;
            bool okw = (unsigned)wj < 32u;
            #pragma unroll
            for (int l = 0; l < 5; ++l) {
                int dd = d + l - 2;
                bool ok = okw && ((unsigned)dd < 32u);
                int off = ok ? (wj << 5) + dd : 0;
                float vv = row[off];
                v[jc][l] = ok ? vv : 0.f;
            }
        }
        #pragma unroll
        for (int a = 0; a < 4; ++a) {
            if (a <= m && m <= a + 4) {
                const float* wr = &wl[(m - a) * 40];
                float s0 = 0.f, s1 = 0.f;
                #pragma unroll
                for (int j = 0; j < 5; ++j) {
                    float4 wA = *(const float4*)&wr[j * 8];
                    float w4 = wr[j * 8 + 4];
                    s0 += wA.x * v[j][0] + wA.y * v[j][1] + wA.z * v[j][2]
                        + wA.w * v[j][3] + w4 * v[j][4];
                    s1 += wA.x * v[j + 1][0] + wA.y * v[j + 1][1] + wA.z * v[j + 1][2]
                        + wA.w * v[j + 1][3] + w4 * v[j + 1][4];
                }
                acc[a][0] += s0;
                acc[a][1] += s1;
            }
        }
    }
    #pragma unroll
    for (int a = 0; a < 4; ++a)
        #pragma unroll
        for (int bb = 0; bb < 2; ++bb)
            out[(size_t)c * NSP + ((4 * hq + a) << 10) + ((2 * wb + bb) << 5) + d]
                = acc[a][bb];
}

// ---------------------------------------------------------------------------
// K3: depthwise 7x7x7 dilation 3, pad 9, h-residue-class blocked.
__global__ __launch_bounds__(256) void k_dw7(const float* __restrict__ in,
        const float* __restrict__ w, const float* __restrict__ b,
        float* __restrict__ out) {
    __shared__ __align__(16) float wl[7 * 7 * 8];
    int t = threadIdx.x;
    int blk = blockIdx.x;            // 64c * 3h0 * 4wq = 768
    int c  = blk / 12;
    int h0 = (blk % 12) >> 2;
    int wq = blk & 3;
    int d  = t & 31;
    int w_ = wq * 8 + (t >> 5);
    const float* wc = w + c * 343;
    for (int i = t; i < 343; i += 256) {
        int ii = i / 49, jj = (i / 7) % 7, ll = i % 7;
        wl[ii * 56 + jj * 8 + ll] = wc[i];
    }
    __syncthreads();

    float bc = b[c];
    float acc[11];
    #pragma unroll
    for (int a = 0; a < 11; ++a) acc[a] = bc;
    const float* src = in + (size_t)c * NSP;

    #pragma unroll 1
    for (int m = 0; m < 17; ++m) {
        int hh = h0 + 3 * m - 9;
        if ((unsigned)hh >= 32u) continue;
        const float* row = src + (hh << 10);
        float v[7][7];
        #pragma unroll
        for (int jw = 0; jw < 7; ++jw) {
            int wj = w_ + 3 * jw - 9;
            bool okw = (unsigned)wj < 32u;
            #pragma unroll
            for (int l = 0; l < 7; ++l) {
                int dd = d + 3 * l - 9;
                bool ok = okw && ((unsigned)dd < 32u);
                int off = ok ? (wj << 5) + dd : 0;
                float vv = row[off];
                v[jw][l] = ok ? vv : 0.f;
            }
        }
        #pragma unroll
        for (int a = 0; a < 11; ++a) {
            if (a <= m && m <= a + 6) {
                const float4* wp = (const float4*)&wl[(m - a) * 56];
                float s = 0.f;
                #pragma unroll
                for (int jw = 0; jw < 7; ++jw) {
                    float4 wA = wp[jw * 2];
                    float4 wB = wp[jw * 2 + 1];
                    s += wA.x * v[jw][0] + wA.y * v[jw][1] + wA.z * v[jw][2]
                       + wA.w * v[jw][3] + wB.x * v[jw][4] + wB.y * v[jw][5]
                       + wB.z * v[jw][6];
                }
                acc[a] += s;
            }
        }
    }
    #pragma unroll
    for (int a = 0; a < 11; ++a) {
        int h = h0 + 3 * a;
        if (h < 32)
            out[(size_t)c * NSP + (h << 10) + (w_ << 5) + d] = acc[a];
    }
}

// ---------------------------------------------------------------------------
// K4: transpose [C][N] -> [N][C] f32, plus f16 copy aTh [N][C]
__global__ __launch_bounds__(256) void k_tr(const float* __restrict__ in,
        float* __restrict__ out, _Float16* __restrict__ outh) {
    __shared__ float tile[64 * 65];
    int t = threadIdx.x;
    int n0 = blockIdx.x * 64;
    for (int i = 0; i < 16; ++i) {
        int idx = i * 256 + t;
        int c = idx >> 6, nl = idx & 63;
        tile[c * 65 + nl] = in[(size_t)c * NSP + n0 + nl];
    }
    __syncthreads();
    for (int i = 0; i < 16; ++i) {
        int idx = i * 256 + t;
        int nl = idx >> 6, c = idx & 63;
        float v = tile[c * 65 + nl];
        out[(size_t)(n0 + nl) * 64 + c] = v;
        outh[(size_t)(n0 + nl) * 64 + c] = (_Float16)v;
    }
}

// ---------------------------------------------------------------------------
// K5a: pre-pack deform weights into f16 MFMA A-fragment order.
__global__ __launch_bounds__(256) void k_wpack(const float* __restrict__ dw,
        _Float16* __restrict__ Wp) {
    int idx = blockIdx.x * 256 + threadIdx.x;   // 0 .. 110591
    int j = idx & 7;
    int l = (idx >> 3) & 63;
    int obk = idx >> 9;
    int ob = obk & 3, kb = obk >> 2;
    int o = ob * 16 + (l & 15);
    int Kp = kb * 32 + (l >> 4) * 8 + j;
    int k = Kp >> 6, c = Kp & 63;
    Wp[idx] = (_Float16)dw[(size_t)o * 1728 + c * 27 + k];
}

// ---------------------------------------------------------------------------
// K5b: pre-pack offset-conv weights, 6 o-blocks of 16 (rows 81..95 = 0).
__global__ __launch_bounds__(256) void k_wpack_off(const float* __restrict__ ow,
        _Float16* __restrict__ Wp2) {
    int idx = blockIdx.x * 256 + threadIdx.x;   // 0 .. 165887
    int j = idx & 7;
    int l = (idx >> 3) & 63;
    int obk = idx >> 9;                          // 0 .. 323
    int ob = obk % 6, kb = obk / 6;
    int o = ob * 16 + (l & 15);
    int Kp = kb * 32 + (l >> 4) * 8 + j;
    int k = Kp >> 6, c = Kp & 63;
    Wp2[idx] = (o < 81) ? (_Float16)ow[(size_t)o * 1728 + c * 27 + k]
                        : (_Float16)0.f;
}

// ---------------------------------------------------------------------------
// K5d: pack a 64x64 f32 weight matrix into A-frag order (4 ob x 2 kb).
__global__ __launch_bounds__(256) void k_wpack64(const float* __restrict__ w,
        _Float16* __restrict__ Wp) {
    int idx = blockIdx.x * 256 + threadIdx.x;   // 0 .. 4095
    int j = idx & 7;
    int l = (idx >> 3) & 63;
    int obk = idx >> 9;                          // 0..7
    int ob = obk & 3, kb = obk >> 2;
    int o = ob * 16 + (l & 15);
    int Kp = kb * 32 + (l >> 4) * 8 + j;
    Wp[idx] = (_Float16)w[o * 64 + Kp];
}

// ---------------------------------------------------------------------------
// K5c: offset conv via non-duplicated halo tile + MFMA.
__global__ __launch_bounds__(256) void k_offg(const float* __restrict__ aT,
        const half8* __restrict__ Wp2, const float* __restrict__ obias,
        float* __restrict__ off) {
    __shared__ __align__(16) _Float16 S2[9 * 34 * 72];   // 44064 B
    int t = threadIdx.x;
    int blk = blockIdx.x;            // 32h * 32w
    int h = blk >> 5, w = blk & 31;
    int n0 = blk << 5;
    int lane = t & 63, wv = t >> 6;

    #pragma unroll
    for (int hwn = 0; hwn < 9; ++hwn) {
        int hh = h + hwn / 3 - 1;
        int wj = w + hwn % 3 - 1;
        bool okhw = ((unsigned)hh < 32u) & ((unsigned)wj < 32u);
        int rowb = (hh << 5) + wj;
        for (int dd = wv; dd < 34; dd += 4) {
            int di = dd - 1;
            bool ok = okhw & ((unsigned)di < 32u);
            float v = ok ? aT[(size_t)((rowb << 5) + di) * 64 + lane] : 0.f;
            S2[(hwn * 34 + dd) * 72 + lane] = (_Float16)v;
        }
    }
    __syncthreads();

    int pl = lane & 15, g = lane >> 4;
    #pragma unroll 1
    for (int u = 0; u < 3; ++u) {
        int unit = wv * 3 + u;                   // 0..11
        int obi = unit >> 1, pt = unit & 1;
        f32x4 acc4 = {0.f, 0.f, 0.f, 0.f};
        const half8* wb = Wp2 + obi * 64 + lane;
        const _Float16* sb = &S2[(pt * 16 + pl) * 72 + g * 8];
        #pragma unroll
        for (int kb = 0; kb < 54; ++kb) {
            int k = kb >> 1;
            int hwn = (k / 9) * 3 + (k / 3) % 3;
            int kd = k % 3;
            half8 bf = *(const half8*)(sb + (hwn * 34 + kd) * 72 + (kb & 1) * 32);
            half8 af = wb[(size_t)kb * 384];
            acc4 = __builtin_amdgcn_mfma_f32_16x16x32_f16(af, bf, acc4, 0, 0, 0);
        }
        #pragma unroll
        for (int r = 0; r < 4; ++r) {
            int o = obi * 16 + g * 4 + r;
            if (o < 81) off[(size_t)o * NSP + n0 + pt * 16 + pl] = acc4[r] + obias[o];
        }
    }
}

// ---------------------------------------------------------------------------
// K6: deformable gather + MFMA GEMM.  Phase B: f16 source, one dwordx4
// wave-load = 8 d-consecutive taps x 1 corner; in-lane pk_fma accumulate;
// one ds_write_b128 per finished k-column.  No cross-lane ops.
__global__ __launch_bounds__(256) void k_deform(const _Float16* __restrict__ aTh,
        const float* __restrict__ off, const half8* __restrict__ Wp,
        const float* __restrict__ db, float* __restrict__ dcn) {
    __shared__ __align__(16) _Float16 S[8 * 1736];    // 27776 B
    __shared__ __align__(8) int2 TP2[8 * 216];        // 13824 B [corner][tap]
    int t = threadIdx.x;
    int n0 = blockIdx.x * 8;
    int lane = t & 63, wv = t >> 6;

    if (t < 216) {                       // Phase A: per-tap precompute
        int p = t & 7, k = t >> 3;       // k in 0..26
        int n = n0 + p;
        int h = n >> 10, w = (n >> 5) & 31, d = n & 31;
        float ph = (float)(h + k / 9 - 1)       + off[(size_t)(k * 3 + 0) * NSP + n];
        float pw = (float)(w + (k / 3) % 3 - 1) + off[(size_t)(k * 3 + 1) * NSP + n];
        float pd = (float)(d + k % 3 - 1)       + off[(size_t)(k * 3 + 2) * NSP + n];
        float fh = floorf(ph), fw = floorf(pw), fd = floorf(pd);
        int ih = (int)fh, iw = (int)fw, id = (int)fd;
        float rh = ph - fh, rw = pw - fw, rd = pd - fd;
        #pragma unroll
        for (int cb = 0; cb < 8; ++cb) {
            int hh = ih + ((cb >> 2) & 1);
            int wq = iw + ((cb >> 1) & 1);
            int dq = id + (cb & 1);
            float wg = ((cb & 4) ? rh : 1.f - rh) * ((cb & 2) ? rw : 1.f - rw)
                     * ((cb & 1) ? rd : 1.f - rd);
            bool ok = ((unsigned)hh < 32u) & ((unsigned)wq < 32u) & ((unsigned)dq < 32u);
            int fl = ok ? (((hh << 5) + wq) * 32 + dq) * 64 : 0;   // f16-elem units
            _Float16 wh = (_Float16)(ok ? wg : 0.f);
            h2u uu; uu.h = (half2v){wh, wh};
            TP2[cb * 216 + t] = make_int2(fl, (int)uu.u);
        }
    }
    __syncthreads();

    int p = lane >> 3, co = lane & 7;    // tap row, channel octet
    #pragma unroll 1
    for (int k = wv; k < 27; k += 4) {   // Phase B: gather, 8 taps per iter
        half2v a0 = (half2v)0, a1 = (half2v)0, a2 = (half2v)0, a3 = (half2v)0;
        #pragma unroll
        for (int i = 0; i < 8; ++i) {
            int2 tc = TP2[i * 216 + k * 8 + p];
            half8 v = *(const half8*)(aTh + tc.x + (co << 3));
            h2u uu; uu.u = (unsigned int)tc.y;
            half2v wg2 = uu.h;
            a0 += (half2v){v[0], v[1]} * wg2;
            a1 += (half2v){v[2], v[3]} * wg2;
            a2 += (half2v){v[4], v[5]} * wg2;
            a3 += (half2v){v[6], v[7]} * wg2;
        }
        half8 r;
        r[0] = a0[0]; r[1] = a0[1]; r[2] = a1[0]; r[3] = a1[1];
        r[4] = a2[0]; r[5] = a2[1]; r[6] = a3[0]; r[7] = a3[1];
        *(half8*)&S[p * 1736 + k * 64 + (co << 3)] = r;
    }
    __syncthreads();

    // Phase C: GEMM  D[o=wv*16..+15][p=0..7], K = 1728
    f32x4 acc4 = {0.f, 0.f, 0.f, 0.f};
    const half8* wbase = Wp + wv * 64 + lane;                   // +256 per kb
    const _Float16* sbase = &S[(lane & 7) * 1736 + (lane >> 4) * 8];
    #pragma unroll 9
    for (int kb = 0; kb < 54; ++kb) {
        half8 af = wbase[(size_t)kb * 256];
        half8 bf = *(const half8*)(sbase + kb * 32);
        acc4 = __builtin_amdgcn_mfma_f32_16x16x32_f16(af, bf, acc4, 0, 0, 0);
    }
    int pl = lane & 15, g = lane >> 4;
    if (pl < 8) {
        #pragma unroll
        for (int r = 0; r < 4; ++r) {
            int o = wv * 16 + g * 4 + r;
            dcn[(size_t)o * NSP + n0 + pl] = acc4[r] + db[o];
        }
    }
}

// ---------------------------------------------------------------------------
// K7 (MFMA): a2 = conv1_w @ dcn + b ; h = U * a2 ; out = proj2_w @ h + b2 + x
__global__ __launch_bounds__(256) void k_finalm(const float* __restrict__ dcn,
        const float* __restrict__ U, const float* __restrict__ x,
        const half8* __restrict__ Wc1, const float* __restrict__ c1b,
        const half8* __restrict__ Wp2f, const float* __restrict__ p2b,
        float* __restrict__ out) {
    __shared__ __align__(16) _Float16 Sd[64 * 72];   // 9216 B
    __shared__ __align__(16) _Float16 Sh[64 * 72];   // 9216 B
    int t = threadIdx.x;
    int n0 = blockIdx.x * 64;
    int lane = t & 63, wv = t >> 6;
    for (int i = wv; i < 64; i += 4) {               // transpose-stage dcn
        float v = dcn[(size_t)i * NSP + n0 + lane];  // c=i, n=lane
        Sd[lane * 72 + i] = (_Float16)v;
    }
    __syncthreads();

    int pl = lane & 15, g = lane >> 4;
    int ob = wv;
    const half8* w1 = Wc1 + ob * 64 + lane;
    #pragma unroll
    for (int nt = 0; nt < 4; ++nt) {                 // GEMM1 + gate
        f32x4 acc4 = {0.f, 0.f, 0.f, 0.f};
        const _Float16* sb = &Sd[(nt * 16 + pl) * 72 + g * 8];
        #pragma unroll
        for (int kb = 0; kb < 2; ++kb) {
            half8 af = w1[kb * 256];
            half8 bf = *(const half8*)(sb + kb * 32);
            acc4 = __builtin_amdgcn_mfma_f32_16x16x32_f16(af, bf, acc4, 0, 0, 0);
        }
        int n = n0 + nt * 16 + pl;
        int o0 = ob * 16 + g * 4;
        float4 bb = *(const float4*)&c1b[o0];
        half4 hv;
        hv[0] = (_Float16)(U[(size_t)(o0 + 0) * NSP + n] * (acc4[0] + bb.x));
        hv[1] = (_Float16)(U[(size_t)(o0 + 1) * NSP + n] * (acc4[1] + bb.y));
        hv[2] = (_Float16)(U[(size_t)(o0 + 2) * NSP + n] * (acc4[2] + bb.z));
        hv[3] = (_Float16)(U[(size_t)(o0 + 3) * NSP + n] * (acc4[3] + bb.w));
        *(half4*)&Sh[(nt * 16 + pl) * 72 + o0] = hv;
    }
    __syncthreads();

    const half8* w2 = Wp2f + ob * 64 + lane;
    #pragma unroll
    for (int nt = 0; nt < 4; ++nt) {                 // GEMM2 + residual
        f32x4 acc4 = {0.f, 0.f, 0.f, 0.f};
        const _Float16* sb = &Sh[(nt * 16 + pl) * 72 + g * 8];
        #pragma unroll
        for (int kb = 0; kb < 2; ++kb) {
            half8 af = w2[kb * 256];
            half8 bf = *(const half8*)(sb + kb * 32);
            acc4 = __builtin_amdgcn_mfma_f32_16x16x32_f16(af, bf, acc4, 0, 0, 0);
        }
        int n = n0 + nt * 16 + pl;
        int o0 = ob * 16 + g * 4;
        float4 bb = *(const float4*)&p2b[o0];
        float4 xr = *(const float4*)&x[(size_t)n * 64 + o0];
        float4 ov;
        ov.x = acc4[0] + bb.x + xr.x;
        ov.y = acc4[1] + bb.y + xr.y;
        ov.z = acc4[2] + bb.z + xr.z;
        ov.w = acc4[3] + bb.w + xr.w;
        *(float4*)&out[(size_t)n * 64 + o0] = ov;
    }
}

// ---------------------------------------------------------------------------
extern "C" void kernel_launch(void* const* d_in, const int* in_sizes, int n_in,
                              void* d_out, int out_size, void* d_ws, size_t ws_size,
                              hipStream_t stream) {
    const float* x   = (const float*)d_in[0];
    const float* p1w = (const float*)d_in[1];
    const float* p1b = (const float*)d_in[2];
    const float* c0w = (const float*)d_in[3];
    const float* c0b = (const float*)d_in[4];
    const float* csw = (const float*)d_in[5];
    const float* csb = (const float*)d_in[6];
    const float* ofw = (const float*)d_in[7];
    const float* ofb = (const float*)d_in[8];
    const float* dcw = (const float*)d_in[9];
    const float* dcb = (const float*)d_in[10];
    const float* c1w = (const float*)d_in[11];
    const float* c1b = (const float*)d_in[12];
    const float* p2w = (const float*)d_in[13];
    const float* p2b = (const float*)d_in[14];
    float* out = (float*)d_out;

    char* ws = (char*)d_ws;
    const size_t CN4 = (size_t)NCH * NSP * 4;       // 8 MiB per [C][N] f32
    float* U    = (float*)(ws);
    float* T0   = (float*)(ws + CN4);
    float* T1   = (float*)(ws + 2 * CN4);
    float* T1T  = (float*)(ws + 3 * CN4);
    float* OFFp = (float*)(ws + 4 * CN4);           // 81*N f32
    float* DCN  = (float*)(ws + 4 * CN4 + (size_t)81 * NSP * 4);
    _Float16* Wp   = (_Float16*)(ws + 5 * CN4 + (size_t)81 * NSP * 4);
    _Float16* Wp2  = Wp + 110592;
    _Float16* Wp1  = Wp2 + 165888;
    _Float16* Wc1  = Wp1 + 4096;
    _Float16* Wp2f = Wc1 + 4096;
    _Float16* aTh  = (_Float16*)T0;                 // reuses T0 (dead after dw7)

    k_wpack64  <<<16, 256, 0, stream>>>(p1w, Wp1);
    k_wpack64  <<<16, 256, 0, stream>>>(c1w, Wc1);
    k_wpack64  <<<16, 256, 0, stream>>>(p2w, Wp2f);
    k_wpack    <<<432, 256, 0, stream>>>(dcw, Wp);
    k_wpack_off<<<648, 256, 0, stream>>>(ofw, Wp2);
    k_proj1m   <<<NSP / 64, 256, 0, stream>>>(x, (const half8*)Wp1, p1b, U);
    k_dw5      <<<1024, 256, 0, stream>>>(U, c0w, c0b, T0);
    k_dw7      <<<768, 256, 0, stream>>>(T0, csw, csb, T1);
    k_tr       <<<NSP / 64, 256, 0, stream>>>(T1, T1T, aTh);
    k_offg     <<<1024, 256, 0, stream>>>(T1T, (const half8*)Wp2, ofb, OFFp);
    k_deform   <<<NSP / 8, 256, 0, stream>>>(aTh, OFFp, (const half8*)Wp, dcb, DCN);
    k_finalm   <<<NSP / 64, 256, 0, stream>>>(DCN, U, x, (const half8*)Wc1, c1b,
                                              (const half8*)Wp2f, p2b, out);
}

// Round 9
// 222.373 us; speedup vs baseline: 12.3799x; 1.1734x over previous
//
#include <hip/hip_runtime.h>
#include <math.h>

#define NSP 32768   // H*W*D = 32*32*32
#define NCH 64

typedef _Float16 half8 __attribute__((ext_vector_type(8)));
typedef _Float16 half4 __attribute__((ext_vector_type(4)));
typedef _Float16 half2v __attribute__((ext_vector_type(2)));
typedef float f32x4 __attribute__((ext_vector_type(4)));

// ---------------------------------------------------------------------------
// K1 (MFMA): U = gelu(proj1_w @ x^T + b)   (U layout: [C][N])
__global__ __launch_bounds__(256) void k_proj1m(const float* __restrict__ x,
        const half8* __restrict__ Wp1, const float* __restrict__ b,
        float* __restrict__ U) {
    __shared__ __align__(16) _Float16 Sx[64 * 72];   // 9216 B
    int t = threadIdx.x;
    int n0 = blockIdx.x * 64;
    int lane = t & 63, wv = t >> 6;
    for (int i = wv; i < 64; i += 4) {
        float v = x[(size_t)(n0 + i) * 64 + lane];
        Sx[i * 72 + lane] = (_Float16)v;
    }
    __syncthreads();
    int pl = lane & 15, g = lane >> 4;
    int ob = wv;
    const half8* wbase = Wp1 + ob * 64 + lane;       // +256 per kb
    #pragma unroll
    for (int nt = 0; nt < 4; ++nt) {
        f32x4 acc4 = {0.f, 0.f, 0.f, 0.f};
        const _Float16* sb = &Sx[(nt * 16 + pl) * 72 + g * 8];
        #pragma unroll
        for (int kb = 0; kb < 2; ++kb) {
            half8 af = wbase[kb * 256];
            half8 bf = *(const half8*)(sb + kb * 32);
            acc4 = __builtin_amdgcn_mfma_f32_16x16x32_f16(af, bf, acc4, 0, 0, 0);
        }
        int n = n0 + nt * 16 + pl;
        #pragma unroll
        for (int r = 0; r < 4; ++r) {
            int o = ob * 16 + g * 4 + r;
            float a = acc4[r] + b[o];
            float gv = 0.5f * a * (1.0f + erff(a * 0.70710678118654752f));
            U[(size_t)o * NSP + n] = gv;
        }
    }
}

// ---------------------------------------------------------------------------
// K2: depthwise 5x5x5, pad 2, register-blocked 4h x 2w.  XCD-chunked swizzle.
__global__ __launch_bounds__(256) void k_dw5(const float* __restrict__ in,
        const float* __restrict__ w, const float* __restrict__ b,
        float* __restrict__ out) {
    __shared__ __align__(16) float wl[5 * 5 * 8];
    int t = threadIdx.x;
    int bid = blockIdx.x;
    int blk = (bid & 7) * 128 + (bid >> 3);   // 1024 blocks: XCD gets 8 channels
    int c  = blk >> 4;
    int hq = (blk >> 1) & 7;
    int wq = blk & 1;
    int d  = t & 31;
    int wb = wq * 8 + (t >> 5);
    const float* wc = w + c * 125;
    for (int i = t; i < 125; i += 256) {
        int ii = i / 25, jj = (i / 5) % 5, ll = i % 5;
        wl[ii * 40 + jj * 8 + ll] = wc[i];
    }
    __syncthreads();

    float bc = b[c];
    float acc[4][2];
    #pragma unroll
    for (int a = 0; a < 4; ++a) { acc[a][0] = bc; acc[a][1] = bc; }
    const float* src = in + (size_t)c * NSP;

    #pragma unroll 1
    for (int m = 0; m < 8; ++m) {
        int hh = 4 * hq + m - 2;
        if ((unsigned)hh >= 32u) continue;
        const float* row = src + (hh << 10);
        float v[6][5];
        #pragma unroll
        for (int jc = 0; jc < 6; ++jc) {
            int wj = 2 * wb + jc - 2;
            bool okw = (unsigned)wj < 32u;
            #pragma unroll
            for (int l = 0; l < 5; ++l) {
                int dd = d + l - 2;
                bool ok = okw && ((unsigned)dd < 32u);
                int off = ok ? (wj << 5) + dd : 0;
                float vv = row[off];
                v[jc][l] = ok ? vv : 0.f;
            }
        }
        #pragma unroll
        for (int a = 0; a < 4; ++a) {
            if (a <= m && m <= a + 4) {
                const float* wr = &wl[(m - a) * 40];
                float s0 = 0.f, s1 = 0.f;
                #pragma unroll
                for (int j = 0; j < 5; ++j) {
                    float4 wA = *(const float4*)&wr[j * 8];
                    float w4 = wr[j * 8 + 4];
                    s0 += wA.x * v[j][0] + wA.y * v[j][1] + wA.z * v[j][2]
                        + wA.w * v[j][3] + w4 * v[j][4];
                    s1 += wA.x * v[j + 1][0] + wA.y * v[j + 1][1] + wA.z * v[j + 1][2]
                        + wA.w * v[j + 1][3] + w4 * v[j + 1][4];
                }
                acc[a][0] += s0;
                acc[a][1] += s1;
            }
        }
    }
    #pragma unroll
    for (int a = 0; a < 4; ++a)
        #pragma unroll
        for (int bb = 0; bb < 2; ++bb)
            out[(size_t)c * NSP + ((4 * hq + a) << 10) + ((2 * wb + bb) << 5) + d]
                = acc[a][bb];
}

// ---------------------------------------------------------------------------
// K3: depthwise 7x7x7 dilation 3, pad 9, h-residue-class blocked.  Swizzled.
__global__ __launch_bounds__(256) void k_dw7(const float* __restrict__ in,
        const float* __restrict__ w, const float* __restrict__ b,
        float* __restrict__ out) {
    __shared__ __align__(16) float wl[7 * 7 * 8];
    int t = threadIdx.x;
    int bid = blockIdx.x;
    int blk = (bid & 7) * 96 + (bid >> 3);    // 768 blocks: XCD gets 8 channels
    int c  = blk / 12;
    int h0 = (blk % 12) >> 2;
    int wq = blk & 3;
    int d  = t & 31;
    int w_ = wq * 8 + (t >> 5);
    const float* wc = w + c * 343;
    for (int i = t; i < 343; i += 256) {
        int ii = i / 49, jj = (i / 7) % 7, ll = i % 7;
        wl[ii * 56 + jj * 8 + ll] = wc[i];
    }
    __syncthreads();

    float bc = b[c];
    float acc[11];
    #pragma unroll
    for (int a = 0; a < 11; ++a) acc[a] = bc;
    const float* src = in + (size_t)c * NSP;

    #pragma unroll 1
    for (int m = 0; m < 17; ++m) {
        int hh = h0 + 3 * m - 9;
        if ((unsigned)hh >= 32u) continue;
        const float* row = src + (hh << 10);
        float v[7][7];
        #pragma unroll
        for (int jw = 0; jw < 7; ++jw) {
            int wj = w_ + 3 * jw - 9;
            bool okw = (unsigned)wj < 32u;
            #pragma unroll
            for (int l = 0; l < 7; ++l) {
                int dd = d + 3 * l - 9;
                bool ok = okw && ((unsigned)dd < 32u);
                int off = ok ? (wj << 5) + dd : 0;
                float vv = row[off];
                v[jw][l] = ok ? vv : 0.f;
            }
        }
        #pragma unroll
        for (int a = 0; a < 11; ++a) {
            if (a <= m && m <= a + 6) {
                const float4* wp = (const float4*)&wl[(m - a) * 56];
                float s = 0.f;
                #pragma unroll
                for (int jw = 0; jw < 7; ++jw) {
                    float4 wA = wp[jw * 2];
                    float4 wB = wp[jw * 2 + 1];
                    s += wA.x * v[jw][0] + wA.y * v[jw][1] + wA.z * v[jw][2]
                       + wA.w * v[jw][3] + wB.x * v[jw][4] + wB.y * v[jw][5]
                       + wB.z * v[jw][6];
                }
                acc[a] += s;
            }
        }
    }
    #pragma unroll
    for (int a = 0; a < 11; ++a) {
        int h = h0 + 3 * a;
        if (h < 32)
            out[(size_t)c * NSP + (h << 10) + (w_ << 5) + d] = acc[a];
    }
}

// ---------------------------------------------------------------------------
// K4: transpose [C][N] -> f16 [N][C] only (f32 copy eliminated)
__global__ __launch_bounds__(256) void k_tr(const float* __restrict__ in,
        _Float16* __restrict__ outh) {
    __shared__ float tile[64 * 65];
    int t = threadIdx.x;
    int n0 = blockIdx.x * 64;
    for (int i = 0; i < 16; ++i) {
        int idx = i * 256 + t;
        int c = idx >> 6, nl = idx & 63;
        tile[c * 65 + nl] = in[(size_t)c * NSP + n0 + nl];
    }
    __syncthreads();
    for (int i = 0; i < 16; ++i) {
        int idx = i * 256 + t;
        int nl = idx >> 6, c = idx & 63;
        outh[(size_t)(n0 + nl) * 64 + c] = (_Float16)tile[c * 65 + nl];
    }
}

// ---------------------------------------------------------------------------
// K5a: pre-pack deform weights into f16 MFMA A-fragment order.
__global__ __launch_bounds__(256) void k_wpack(const float* __restrict__ dw,
        _Float16* __restrict__ Wp) {
    int idx = blockIdx.x * 256 + threadIdx.x;   // 0 .. 110591
    int j = idx & 7;
    int l = (idx >> 3) & 63;
    int obk = idx >> 9;
    int ob = obk & 3, kb = obk >> 2;
    int o = ob * 16 + (l & 15);
    int Kp = kb * 32 + (l >> 4) * 8 + j;
    int k = Kp >> 6, c = Kp & 63;
    Wp[idx] = (_Float16)dw[(size_t)o * 1728 + c * 27 + k];
}

// ---------------------------------------------------------------------------
// K5b: pre-pack offset-conv weights, 6 o-blocks of 16 (rows 81..95 = 0).
__global__ __launch_bounds__(256) void k_wpack_off(const float* __restrict__ ow,
        _Float16* __restrict__ Wp2) {
    int idx = blockIdx.x * 256 + threadIdx.x;   // 0 .. 165887
    int j = idx & 7;
    int l = (idx >> 3) & 63;
    int obk = idx >> 9;                          // 0 .. 323
    int ob = obk % 6, kb = obk / 6;
    int o = ob * 16 + (l & 15);
    int Kp = kb * 32 + (l >> 4) * 8 + j;
    int k = Kp >> 6, c = Kp & 63;
    Wp2[idx] = (o < 81) ? (_Float16)ow[(size_t)o * 1728 + c * 27 + k]
                        : (_Float16)0.f;
}

// ---------------------------------------------------------------------------
// K5d: pack a 64x64 f32 weight matrix into A-frag order (4 ob x 2 kb).
__global__ __launch_bounds__(256) void k_wpack64(const float* __restrict__ w,
        _Float16* __restrict__ Wp) {
    int idx = blockIdx.x * 256 + threadIdx.x;   // 0 .. 4095
    int j = idx & 7;
    int l = (idx >> 3) & 63;
    int obk = idx >> 9;                          // 0..7
    int ob = obk & 3, kb = obk >> 2;
    int o = ob * 16 + (l & 15);
    int Kp = kb * 32 + (l >> 4) * 8 + j;
    Wp[idx] = (_Float16)w[o * 64 + Kp];
}

// ---------------------------------------------------------------------------
// K5c: offset conv, 64-position halo tile.  Block = 384 thr (6 waves), grid
// 512 (XCD-chunked).  Halo S2[12 nbr][34 d][72 ch] f16 (58.7 KB) staged from
// aTh.  Wave = obi: per kb ONE A-frag load feeds FOUR p-tile MFMAs (acc[4])
// -> 4x less weight traffic per position + 4 independent MFMA chains.
__global__ __launch_bounds__(384) void k_offg(const _Float16* __restrict__ aTh,
        const half8* __restrict__ Wp2, const float* __restrict__ obias,
        float* __restrict__ off) {
    __shared__ __align__(16) _Float16 S2[12 * 34 * 72];   // 58752 B
    int t = threadIdx.x;
    int bid = blockIdx.x;
    int blk = (bid & 7) * 64 + (bid >> 3);   // 512 blocks, h-slabs per XCD
    int h = blk >> 4, w0 = (blk & 15) * 2;
    int n0 = (h << 10) + (w0 << 5);
    int lane = t & 63, wv = t >> 6;          // wv 0..5

    for (int i = wv; i < 408; i += 6) {      // stage: 12 nbrs x 34 dd
        int nb = i / 34, dd = i - nb * 34;
        int hh = h + nb / 4 - 1;
        int wj = w0 + (nb & 3) - 1;
        int di = dd - 1;
        bool ok = ((unsigned)hh < 32u) & ((unsigned)wj < 32u) & ((unsigned)di < 32u);
        _Float16 v = ok ? aTh[(size_t)(((hh << 5) + wj) * 32 + di) * 64 + lane]
                        : (_Float16)0.f;
        S2[(nb * 34 + dd) * 72 + lane] = v;
    }
    __syncthreads();

    int pl = lane & 15, g = lane >> 4;
    int obi = wv;
    f32x4 acc[4];
    #pragma unroll
    for (int i = 0; i < 4; ++i) acc[i] = (f32x4){0.f, 0.f, 0.f, 0.f};
    const half8* wb = Wp2 + obi * 64 + lane;
    const _Float16* sb = &S2[pl * 72 + g * 8];
    #pragma unroll
    for (int kb = 0; kb < 54; ++kb) {        // full unroll: offsets fold
        int k = kb >> 1;
        int kh = k / 9, kw3 = (k / 3) % 3, kd = k % 3;
        half8 af = wb[(size_t)kb * 384];
        #pragma unroll
        for (int pt = 0; pt < 4; ++pt) {     // s = pt>>1, dhalf = pt&1
            int row = (kh * 4 + (pt >> 1) + kw3) * 34 + (pt & 1) * 16 + kd;
            half8 bf = *(const half8*)(sb + row * 72 + (kb & 1) * 32);
            acc[pt] = __builtin_amdgcn_mfma_f32_16x16x32_f16(af, bf, acc[pt], 0, 0, 0);
        }
    }
    #pragma unroll
    for (int pt = 0; pt < 4; ++pt) {
        #pragma unroll
        for (int r = 0; r < 4; ++r) {
            int o = obi * 16 + g * 4 + r;
            if (o < 81)
                off[(size_t)o * NSP + n0 + pt * 16 + pl] = acc[pt][r] + obias[o];
        }
    }
}

// ---------------------------------------------------------------------------
// K6: deformable gather + MFMA GEMM, 16-position blocks (full 16x16 tiles).
// TP compressed to 20 B/tap: packed (base+4096)<<8|mask int + 8 f16 weights;
// corner addrs reconstructed from compile-time offsets + cndmask.
__global__ __launch_bounds__(256) void k_deform(const _Float16* __restrict__ aTh,
        const float* __restrict__ off, const half8* __restrict__ Wp,
        const float* __restrict__ db, float* __restrict__ dcn) {
    __shared__ __align__(16) _Float16 S[16 * 1736];    // 55552 B
    __shared__ __align__(16) _Float16 TPwg[432 * 8];   // 6912 B
    __shared__ int TPv[432];                           // 1728 B  (total 64192)
    int t = threadIdx.x;
    int bid = blockIdx.x;
    int blk = (bid & 7) * 256 + (bid >> 3);  // 2048 blocks, n-slabs per XCD
    int n0 = blk * 16;
    int lane = t & 63, wv = t >> 6;

    for (int idx = t; idx < 432; idx += 256) {        // Phase A: 16p x 27k taps
        int p = idx & 15, k = idx >> 4;
        int n = n0 + p;
        int h = n >> 10, w = (n >> 5) & 31, d = n & 31;
        float ph = (float)(h + k / 9 - 1)       + off[(size_t)(k * 3 + 0) * NSP + n];
        float pw = (float)(w + (k / 3) % 3 - 1) + off[(size_t)(k * 3 + 1) * NSP + n];
        float pd = (float)(d + k % 3 - 1)       + off[(size_t)(k * 3 + 2) * NSP + n];
        float fh = floorf(ph), fw = floorf(pw), fd = floorf(pd);
        int ih = (int)fh, iw = (int)fw, id = (int)fd;
        float rh = ph - fh, rw = pw - fw, rd = pd - fd;
        int nb0 = ih * 1024 + iw * 32 + id;           // true base (may be <0)
        int mask = 0;
        half8 wgs;
        #pragma unroll
        for (int cb = 0; cb < 8; ++cb) {
            int hh = ih + ((cb >> 2) & 1);
            int wq = iw + ((cb >> 1) & 1);
            int dq = id + (cb & 1);
            float wg = ((cb & 4) ? rh : 1.f - rh) * ((cb & 2) ? rw : 1.f - rw)
                     * ((cb & 1) ? rd : 1.f - rd);
            bool ok = ((unsigned)hh < 32u) & ((unsigned)wq < 32u) & ((unsigned)dq < 32u);
            wgs[cb] = (_Float16)(ok ? wg : 0.f);
            mask |= (ok ? 1 : 0) << cb;
        }
        TPv[idx] = ((nb0 + 4096) << 8) | mask;
        *(half8*)&TPwg[idx * 8] = wgs;
    }
    __syncthreads();

    int p8 = lane >> 3, co = lane & 7;
    for (int idx = wv; idx < 54; idx += 4) {          // Phase B: gather
        int k = idx >> 1, phf = idx & 1;
        int tap = k * 16 + phf * 8 + p8;
        int v = TPv[tap];
        int nb = (v >> 8) - 4096, mask = v & 255;
        half8 wgv = *(const half8*)&TPwg[tap * 8];
        half2v a0 = (half2v)0, a1 = (half2v)0, a2 = (half2v)0, a3 = (half2v)0;
        #pragma unroll
        for (int i = 0; i < 8; ++i) {
            int nn = nb + ((i >> 2) & 1) * 1024 + ((i >> 1) & 1) * 32 + (i & 1);
            bool okc = (mask >> i) & 1;
            size_t ad = okc ? ((size_t)nn << 6) : 0;
            half8 vv = *(const half8*)(aTh + ad + (co << 3));
            half2v wg2 = (half2v){wgv[i], wgv[i]};
            a0 += (half2v){vv[0], vv[1]} * wg2;
            a1 += (half2v){vv[2], vv[3]} * wg2;
            a2 += (half2v){vv[4], vv[5]} * wg2;
            a3 += (half2v){vv[6], vv[7]} * wg2;
        }
        half8 r;
        r[0] = a0[0]; r[1] = a0[1]; r[2] = a1[0]; r[3] = a1[1];
        r[4] = a2[0]; r[5] = a2[1]; r[6] = a3[0]; r[7] = a3[1];
        int p = phf * 8 + p8;
        *(half8*)&S[p * 1736 + k * 64 + (co << 3)] = r;
    }
    __syncthreads();

    // Phase C: full 16x16 tiles  D[o=wv*16..+15][p=0..15], K = 1728
    f32x4 acc4 = {0.f, 0.f, 0.f, 0.f};
    const half8* wbase = Wp + wv * 64 + lane;
    const _Float16* sbase = &S[(lane & 15) * 1736 + (lane >> 4) * 8];
    #pragma unroll 9
    for (int kb = 0; kb < 54; ++kb) {
        half8 af = wbase[(size_t)kb * 256];
        half8 bf = *(const half8*)(sbase + kb * 32);
        acc4 = __builtin_amdgcn_mfma_f32_16x16x32_f16(af, bf, acc4, 0, 0, 0);
    }
    int pl = lane & 15, g = lane >> 4;
    #pragma unroll
    for (int r2 = 0; r2 < 4; ++r2) {
        int o = wv * 16 + g * 4 + r2;
        dcn[(size_t)o * NSP + n0 + pl] = acc4[r2] + db[o];
    }
}

// ---------------------------------------------------------------------------
// K7 (MFMA): a2 = conv1_w @ dcn + b ; h = U * a2 ; out = proj2_w @ h + b2 + x
__global__ __launch_bounds__(256) void k_finalm(const float* __restrict__ dcn,
        const float* __restrict__ U, const float* __restrict__ x,
        const half8* __restrict__ Wc1, const float* __restrict__ c1b,
        const half8* __restrict__ Wp2f, const float* __restrict__ p2b,
        float* __restrict__ out) {
    __shared__ __align__(16) _Float16 Sd[64 * 72];   // 9216 B
    __shared__ __align__(16) _Float16 Sh[64 * 72];   // 9216 B
    int t = threadIdx.x;
    int n0 = blockIdx.x * 64;
    int lane = t & 63, wv = t >> 6;
    for (int i = wv; i < 64; i += 4) {               // transpose-stage dcn
        float v = dcn[(size_t)i * NSP + n0 + lane];
        Sd[lane * 72 + i] = (_Float16)v;
    }
    __syncthreads();

    int pl = lane & 15, g = lane >> 4;
    int ob = wv;
    const half8* w1 = Wc1 + ob * 64 + lane;
    #pragma unroll
    for (int nt = 0; nt < 4; ++nt) {                 // GEMM1 + gate
        f32x4 acc4 = {0.f, 0.f, 0.f, 0.f};
        const _Float16* sb = &Sd[(nt * 16 + pl) * 72 + g * 8];
        #pragma unroll
        for (int kb = 0; kb < 2; ++kb) {
            half8 af = w1[kb * 256];
            half8 bf = *(const half8*)(sb + kb * 32);
            acc4 = __builtin_amdgcn_mfma_f32_16x16x32_f16(af, bf, acc4, 0, 0, 0);
        }
        int n = n0 + nt * 16 + pl;
        int o0 = ob * 16 + g * 4;
        float4 bb = *(const float4*)&c1b[o0];
        half4 hv;
        hv[0] = (_Float16)(U[(size_t)(o0 + 0) * NSP + n] * (acc4[0] + bb.x));
        hv[1] = (_Float16)(U[(size_t)(o0 + 1) * NSP + n] * (acc4[1] + bb.y));
        hv[2] = (_Float16)(U[(size_t)(o0 + 2) * NSP + n] * (acc4[2] + bb.z));
        hv[3] = (_Float16)(U[(size_t)(o0 + 3) * NSP + n] * (acc4[3] + bb.w));
        *(half4*)&Sh[(nt * 16 + pl) * 72 + o0] = hv;
    }
    __syncthreads();

    const half8* w2 = Wp2f + ob * 64 + lane;
    #pragma unroll
    for (int nt = 0; nt < 4; ++nt) {                 // GEMM2 + residual
        f32x4 acc4 = {0.f, 0.f, 0.f, 0.f};
        const _Float16* sb = &Sh[(nt * 16 + pl) * 72 + g * 8];
        #pragma unroll
        for (int kb = 0; kb < 2; ++kb) {
            half8 af = w2[kb * 256];
            half8 bf = *(const half8*)(sb + kb * 32);
            acc4 = __builtin_amdgcn_mfma_f32_16x16x32_f16(af, bf, acc4, 0, 0, 0);
        }
        int n = n0 + nt * 16 + pl;
        int o0 = ob * 16 + g * 4;
        float4 bb = *(const float4*)&p2b[o0];
        float4 xr = *(const float4*)&x[(size_t)n * 64 + o0];
        float4 ov;
        ov.x = acc4[0] + bb.x + xr.x;
        ov.y = acc4[1] + bb.y + xr.y;
        ov.z = acc4[2] + bb.z + xr.z;
        ov.w = acc4[3] + bb.w + xr.w;
        *(float4*)&out[(size_t)n * 64 + o0] = ov;
    }
}

// ---------------------------------------------------------------------------
extern "C" void kernel_launch(void* const* d_in, const int* in_sizes, int n_in,
                              void* d_out, int out_size, void* d_ws, size_t ws_size,
                              hipStream_t stream) {
    const float* x   = (const float*)d_in[0];
    const float* p1w = (const float*)d_in[1];
    const float* p1b = (const float*)d_in[2];
    const float* c0w = (const float*)d_in[3];
    const float* c0b = (const float*)d_in[4];
    const float* csw = (const float*)d_in[5];
    const float* csb = (const float*)d_in[6];
    const float* ofw = (const float*)d_in[7];
    const float* ofb = (const float*)d_in[8];
    const float* dcw = (const float*)d_in[9];
    const float* dcb = (const float*)d_in[10];
    const float* c1w = (const float*)d_in[11];
    const float* c1b = (const float*)d_in[12];
    const float* p2w = (const float*)d_in[13];
    const float* p2b = (const float*)d_in[14];
    float* out = (float*)d_out;

    char* ws = (char*)d_ws;
    const size_t CN4 = (size_t)NCH * NSP * 4;       // 8 MiB per [C][N] f32
    float* U    = (float*)(ws);
    float* T0   = (float*)(ws + CN4);
    float* T1   = (float*)(ws + 2 * CN4);
    float* OFFp = (float*)(ws + 4 * CN4);           // 81*N f32
    float* DCN  = (float*)(ws + 4 * CN4 + (size_t)81 * NSP * 4);
    _Float16* Wp   = (_Float16*)(ws + 5 * CN4 + (size_t)81 * NSP * 4);
    _Float16* Wp2  = Wp + 110592;
    _Float16* Wp1  = Wp2 + 165888;
    _Float16* Wc1  = Wp1 + 4096;
    _Float16* Wp2f = Wc1 + 4096;
    _Float16* aTh  = (_Float16*)T0;                 // reuses T0 (dead after dw7)

    k_wpack64  <<<16, 256, 0, stream>>>(p1w, Wp1);
    k_wpack64  <<<16, 256, 0, stream>>>(c1w, Wc1);
    k_wpack64  <<<16, 256, 0, stream>>>(p2w, Wp2f);
    k_wpack    <<<432, 256, 0, stream>>>(dcw, Wp);
    k_wpack_off<<<648, 256, 0, stream>>>(ofw, Wp2);
    k_proj1m   <<<NSP / 64, 256, 0, stream>>>(x, (const half8*)Wp1, p1b, U);
    k_dw5      <<<1024, 256, 0, stream>>>(U, c0w, c0b, T0);
    k_dw7      <<<768, 256, 0, stream>>>(T0, csw, csb, T1);
    k_tr       <<<NSP / 64, 256, 0, stream>>>(T1, aTh);
    k_offg     <<<512, 384, 0, stream>>>(aTh, (const half8*)Wp2, ofb, OFFp);
    k_deform   <<<2048, 256, 0, stream>>>(aTh, OFFp, (const half8*)Wp, dcb, DCN);
    k_finalm   <<<NSP / 64, 256, 0, stream>>>(DCN, U, x, (const half8*)Wc1, c1b,
                                              (const half8*)Wp2f, p2b, out);
}

// Round 10
// 197.431 us; speedup vs baseline: 13.9438x; 1.1263x over previous
//
#include <hip/hip_runtime.h>
#include <math.h>

#define NSP 32768   // H*W*D = 32*32*32
#define NCH 64

typedef _Float16 half8 __attribute__((ext_vector_type(8)));
typedef _Float16 half4 __attribute__((ext_vector_type(4)));
typedef _Float16 half2v __attribute__((ext_vector_type(2)));
typedef float f32x4 __attribute__((ext_vector_type(4)));

// ---------------------------------------------------------------------------
// K1 (MFMA): U = gelu(proj1_w @ x^T + b)   (U layout: [C][N])
__global__ __launch_bounds__(256) void k_proj1m(const float* __restrict__ x,
        const half8* __restrict__ Wp1, const float* __restrict__ b,
        float* __restrict__ U) {
    __shared__ __align__(16) _Float16 Sx[64 * 72];   // 9216 B
    int t = threadIdx.x;
    int n0 = blockIdx.x * 64;
    int lane = t & 63, wv = t >> 6;
    for (int i = wv; i < 64; i += 4) {
        float v = x[(size_t)(n0 + i) * 64 + lane];
        Sx[i * 72 + lane] = (_Float16)v;
    }
    __syncthreads();
    int pl = lane & 15, g = lane >> 4;
    int ob = wv;
    const half8* wbase = Wp1 + ob * 64 + lane;       // +256 per kb
    #pragma unroll
    for (int nt = 0; nt < 4; ++nt) {
        f32x4 acc4 = {0.f, 0.f, 0.f, 0.f};
        const _Float16* sb = &Sx[(nt * 16 + pl) * 72 + g * 8];
        #pragma unroll
        for (int kb = 0; kb < 2; ++kb) {
            half8 af = wbase[kb * 256];
            half8 bf = *(const half8*)(sb + kb * 32);
            acc4 = __builtin_amdgcn_mfma_f32_16x16x32_f16(af, bf, acc4, 0, 0, 0);
        }
        int n = n0 + nt * 16 + pl;
        #pragma unroll
        for (int r = 0; r < 4; ++r) {
            int o = ob * 16 + g * 4 + r;
            float a = acc4[r] + b[o];
            float gv = 0.5f * a * (1.0f + erff(a * 0.70710678118654752f));
            U[(size_t)o * NSP + n] = gv;
        }
    }
}

// ---------------------------------------------------------------------------
// K2: depthwise 5x5x5, pad 2.  Weights: direct global uniform reads -> SGPR.
// Values: double-buffered LDS halo row tile [2][20 w][38 D'] f32.
// Thread = (wbloc 0..7 -> 2 w outputs, d 0..31), 4 h outputs (hq row).
__global__ __launch_bounds__(256) void k_dw5(const float* __restrict__ in,
        const float* __restrict__ w, const float* __restrict__ b,
        float* __restrict__ out) {
    __shared__ float Sb5[2][20 * 38];                // 6080 B
    int t = threadIdx.x;
    int bid = blockIdx.x;
    int blk = (bid & 7) * 128 + (bid >> 3);          // XCD-chunked
    int c  = blk >> 4;
    int hq = (blk >> 1) & 7;
    int wq = blk & 1;
    int d  = t & 31;
    int wbloc = t >> 5;                              // 0..7
    int wb = wq * 8 + wbloc;
    const float* wc = w + c * 125;                   // uniform -> scalar loads
    const float* src = in + (size_t)c * NSP;

    float bc = b[c];
    float acc[4][2];
    #pragma unroll
    for (int a = 0; a < 4; ++a) { acc[a][0] = bc; acc[a][1] = bc; }

    // stage row m into Sb5[m&1]: wi in [0,20), Dp in [0,36)
    #define STAGE5(m)                                                        \
        { int hh_ = 4 * hq + (m) - 2;                                        \
          if ((unsigned)hh_ < 32u) {                                         \
            const float* row_ = src + (hh_ << 10);                           \
            for (int idx = t; idx < 20 * 36; idx += 256) {                   \
                int wi = idx / 36, Dp = idx - wi * 36;                       \
                int wj = 16 * wq - 2 + wi, di = Dp - 2;                      \
                bool ok = ((unsigned)wj < 32u) & ((unsigned)di < 32u);       \
                Sb5[(m) & 1][wi * 38 + Dp] = ok ? row_[(wj << 5) + di] : 0.f;\
            } } }

    STAGE5(0)
    __syncthreads();
    #pragma unroll 1
    for (int m = 0; m < 8; ++m) {
        if (m < 7) STAGE5(m + 1)
        int hh = 4 * hq + m - 2;
        if ((unsigned)hh < 32u) {
            float v[6][5];
            const float* sb = &Sb5[m & 1][0];
            #pragma unroll
            for (int jc = 0; jc < 6; ++jc)
                #pragma unroll
                for (int l = 0; l < 5; ++l)
                    v[jc][l] = sb[(2 * wbloc + jc) * 38 + d + l];
            #pragma unroll
            for (int a = 0; a < 4; ++a) {
                if (a <= m && m <= a + 4) {
                    const float* wr = wc + (m - a) * 25;   // uniform
                    float s0 = 0.f, s1 = 0.f;
                    #pragma unroll
                    for (int j = 0; j < 5; ++j)
                        #pragma unroll
                        for (int l = 0; l < 5; ++l) {
                            float wv2 = wr[j * 5 + l];
                            s0 += wv2 * v[j][l];
                            s1 += wv2 * v[j + 1][l];
                        }
                    acc[a][0] += s0;
                    acc[a][1] += s1;
                }
            }
        }
        __syncthreads();
    }
    #pragma unroll
    for (int a = 0; a < 4; ++a)
        #pragma unroll
        for (int bb = 0; bb < 2; ++bb)
            out[(size_t)c * NSP + ((4 * hq + a) << 10) + ((2 * wb + bb) << 5) + d]
                = acc[a][bb];
    #undef STAGE5
}

// ---------------------------------------------------------------------------
// K3: depthwise 7x7x7 dilation 3.  Weights: direct global uniform -> SGPR.
// Values: double-buffered LDS halo row tile [2][26 w][52 D'] f32.
// Thread = (wloc 0..7, d 0..31); 11 h-residue outputs.
__global__ __launch_bounds__(256) void k_dw7(const float* __restrict__ in,
        const float* __restrict__ w, const float* __restrict__ b,
        float* __restrict__ out) {
    __shared__ float Sb7[2][26 * 52];                // 10816 B
    int t = threadIdx.x;
    int bid = blockIdx.x;
    int blk = (bid & 7) * 96 + (bid >> 3);           // XCD-chunked
    int c  = blk / 12;
    int h0 = (blk % 12) >> 2;
    int wq = blk & 3;
    int d  = t & 31;
    int wloc = t >> 5;                               // 0..7
    int w_ = wq * 8 + wloc;
    const float* wc = w + c * 343;                   // uniform -> scalar loads
    const float* src = in + (size_t)c * NSP;

    float bc = b[c];
    float acc[11];
    #pragma unroll
    for (int a = 0; a < 11; ++a) acc[a] = bc;

    // stage row m into Sb7[m&1]: wi in [0,26), Dp in [0,50)
    #define STAGE7(m)                                                        \
        { int hh_ = h0 + 3 * (m) - 9;                                        \
          if ((unsigned)hh_ < 32u) {                                         \
            const float* row_ = src + (hh_ << 10);                           \
            for (int idx = t; idx < 26 * 50; idx += 256) {                   \
                int wi = idx / 50, Dp = idx - wi * 50;                       \
                int wj = 8 * wq - 9 + wi, di = Dp - 9;                       \
                bool ok = ((unsigned)wj < 32u) & ((unsigned)di < 32u);       \
                Sb7[(m) & 1][wi * 52 + Dp] = ok ? row_[(wj << 5) + di] : 0.f;\
            } } }

    STAGE7(0)
    __syncthreads();
    #pragma unroll 1
    for (int m = 0; m < 17; ++m) {
        if (m < 16) STAGE7(m + 1)
        int hh = h0 + 3 * m - 9;
        if ((unsigned)hh < 32u) {
            float v[7][7];
            const float* sb = &Sb7[m & 1][0];
            #pragma unroll
            for (int jw = 0; jw < 7; ++jw)
                #pragma unroll
                for (int l = 0; l < 7; ++l)
                    v[jw][l] = sb[(wloc + 3 * jw) * 52 + d + 3 * l];
            #pragma unroll
            for (int a = 0; a < 11; ++a) {
                if (a <= m && m <= a + 6) {
                    const float* wr = wc + (m - a) * 49;   // uniform
                    float s = 0.f;
                    #pragma unroll
                    for (int jw = 0; jw < 7; ++jw)
                        #pragma unroll
                        for (int l = 0; l < 7; ++l)
                            s += wr[jw * 7 + l] * v[jw][l];
                    acc[a] += s;
                }
            }
        }
        __syncthreads();
    }
    #pragma unroll
    for (int a = 0; a < 11; ++a) {
        int h = h0 + 3 * a;
        if (h < 32)
            out[(size_t)c * NSP + (h << 10) + (w_ << 5) + d] = acc[a];
    }
    #undef STAGE7
}

// ---------------------------------------------------------------------------
// K4: transpose [C][N] -> f16 [N][C]
__global__ __launch_bounds__(256) void k_tr(const float* __restrict__ in,
        _Float16* __restrict__ outh) {
    __shared__ float tile[64 * 65];
    int t = threadIdx.x;
    int n0 = blockIdx.x * 64;
    for (int i = 0; i < 16; ++i) {
        int idx = i * 256 + t;
        int c = idx >> 6, nl = idx & 63;
        tile[c * 65 + nl] = in[(size_t)c * NSP + n0 + nl];
    }
    __syncthreads();
    for (int i = 0; i < 16; ++i) {
        int idx = i * 256 + t;
        int nl = idx >> 6, c = idx & 63;
        outh[(size_t)(n0 + nl) * 64 + c] = (_Float16)tile[c * 65 + nl];
    }
}

// ---------------------------------------------------------------------------
// K5a: pre-pack deform weights into f16 MFMA A-fragment order.
__global__ __launch_bounds__(256) void k_wpack(const float* __restrict__ dw,
        _Float16* __restrict__ Wp) {
    int idx = blockIdx.x * 256 + threadIdx.x;   // 0 .. 110591
    int j = idx & 7;
    int l = (idx >> 3) & 63;
    int obk = idx >> 9;
    int ob = obk & 3, kb = obk >> 2;
    int o = ob * 16 + (l & 15);
    int Kp = kb * 32 + (l >> 4) * 8 + j;
    int k = Kp >> 6, c = Kp & 63;
    Wp[idx] = (_Float16)dw[(size_t)o * 1728 + c * 27 + k];
}

// ---------------------------------------------------------------------------
// K5b: pre-pack offset-conv weights, 6 o-blocks of 16 (rows 81..95 = 0).
__global__ __launch_bounds__(256) void k_wpack_off(const float* __restrict__ ow,
        _Float16* __restrict__ Wp2) {
    int idx = blockIdx.x * 256 + threadIdx.x;   // 0 .. 165887
    int j = idx & 7;
    int l = (idx >> 3) & 63;
    int obk = idx >> 9;                          // 0 .. 323
    int ob = obk % 6, kb = obk / 6;
    int o = ob * 16 + (l & 15);
    int Kp = kb * 32 + (l >> 4) * 8 + j;
    int k = Kp >> 6, c = Kp & 63;
    Wp2[idx] = (o < 81) ? (_Float16)ow[(size_t)o * 1728 + c * 27 + k]
                        : (_Float16)0.f;
}

// ---------------------------------------------------------------------------
// K5d: pack a 64x64 f32 weight matrix into A-frag order (4 ob x 2 kb).
__global__ __launch_bounds__(256) void k_wpack64(const float* __restrict__ w,
        _Float16* __restrict__ Wp) {
    int idx = blockIdx.x * 256 + threadIdx.x;   // 0 .. 4095
    int j = idx & 7;
    int l = (idx >> 3) & 63;
    int obk = idx >> 9;                          // 0..7
    int ob = obk & 3, kb = obk >> 2;
    int o = ob * 16 + (l & 15);
    int Kp = kb * 32 + (l >> 4) * 8 + j;
    Wp[idx] = (_Float16)w[o * 64 + Kp];
}

// ---------------------------------------------------------------------------
// K5c: offset conv, 64-position halo tile (6 waves; 1 A-frag -> 4 MFMAs).
__global__ __launch_bounds__(384) void k_offg(const _Float16* __restrict__ aTh,
        const half8* __restrict__ Wp2, const float* __restrict__ obias,
        float* __restrict__ off) {
    __shared__ __align__(16) _Float16 S2[12 * 34 * 72];   // 58752 B
    int t = threadIdx.x;
    int bid = blockIdx.x;
    int blk = (bid & 7) * 64 + (bid >> 3);   // 512 blocks, h-slabs per XCD
    int h = blk >> 4, w0 = (blk & 15) * 2;
    int n0 = (h << 10) + (w0 << 5);
    int lane = t & 63, wv = t >> 6;          // wv 0..5

    for (int i = wv; i < 408; i += 6) {      // stage: 12 nbrs x 34 dd
        int nb = i / 34, dd = i - nb * 34;
        int hh = h + nb / 4 - 1;
        int wj = w0 + (nb & 3) - 1;
        int di = dd - 1;
        bool ok = ((unsigned)hh < 32u) & ((unsigned)wj < 32u) & ((unsigned)di < 32u);
        _Float16 v = ok ? aTh[(size_t)(((hh << 5) + wj) * 32 + di) * 64 + lane]
                        : (_Float16)0.f;
        S2[(nb * 34 + dd) * 72 + lane] = v;
    }
    __syncthreads();

    int pl = lane & 15, g = lane >> 4;
    int obi = wv;
    f32x4 acc[4];
    #pragma unroll
    for (int i = 0; i < 4; ++i) acc[i] = (f32x4){0.f, 0.f, 0.f, 0.f};
    const half8* wb = Wp2 + obi * 64 + lane;
    const _Float16* sb = &S2[pl * 72 + g * 8];
    #pragma unroll
    for (int kb = 0; kb < 54; ++kb) {        // full unroll: offsets fold
        int k = kb >> 1;
        int kh = k / 9, kw3 = (k / 3) % 3, kd = k % 3;
        half8 af = wb[(size_t)kb * 384];
        #pragma unroll
        for (int pt = 0; pt < 4; ++pt) {
            int row = (kh * 4 + (pt >> 1) + kw3) * 34 + (pt & 1) * 16 + kd;
            half8 bf = *(const half8*)(sb + row * 72 + (kb & 1) * 32);
            acc[pt] = __builtin_amdgcn_mfma_f32_16x16x32_f16(af, bf, acc[pt], 0, 0, 0);
        }
    }
    #pragma unroll
    for (int pt = 0; pt < 4; ++pt) {
        #pragma unroll
        for (int r = 0; r < 4; ++r) {
            int o = obi * 16 + g * 4 + r;
            if (o < 81)
                off[(size_t)o * NSP + n0 + pt * 16 + pl] = acc[pt][r] + obias[o];
        }
    }
}

// ---------------------------------------------------------------------------
// K6: deformable gather + MFMA GEMM, 16-position blocks.
__global__ __launch_bounds__(256) void k_deform(const _Float16* __restrict__ aTh,
        const float* __restrict__ off, const half8* __restrict__ Wp,
        const float* __restrict__ db, float* __restrict__ dcn) {
    __shared__ __align__(16) _Float16 S[16 * 1736];    // 55552 B
    __shared__ __align__(16) _Float16 TPwg[432 * 8];   // 6912 B
    __shared__ int TPv[432];                           // 1728 B
    int t = threadIdx.x;
    int bid = blockIdx.x;
    int blk = (bid & 7) * 256 + (bid >> 3);  // 2048 blocks
    int n0 = blk * 16;
    int lane = t & 63, wv = t >> 6;

    for (int idx = t; idx < 432; idx += 256) {        // Phase A
        int p = idx & 15, k = idx >> 4;
        int n = n0 + p;
        int h = n >> 10, w = (n >> 5) & 31, d = n & 31;
        float ph = (float)(h + k / 9 - 1)       + off[(size_t)(k * 3 + 0) * NSP + n];
        float pw = (float)(w + (k / 3) % 3 - 1) + off[(size_t)(k * 3 + 1) * NSP + n];
        float pd = (float)(d + k % 3 - 1)       + off[(size_t)(k * 3 + 2) * NSP + n];
        float fh = floorf(ph), fw = floorf(pw), fd = floorf(pd);
        int ih = (int)fh, iw = (int)fw, id = (int)fd;
        float rh = ph - fh, rw = pw - fw, rd = pd - fd;
        int nb0 = ih * 1024 + iw * 32 + id;
        int mask = 0;
        half8 wgs;
        #pragma unroll
        for (int cb = 0; cb < 8; ++cb) {
            int hh = ih + ((cb >> 2) & 1);
            int wq = iw + ((cb >> 1) & 1);
            int dq = id + (cb & 1);
            float wg = ((cb & 4) ? rh : 1.f - rh) * ((cb & 2) ? rw : 1.f - rw)
                     * ((cb & 1) ? rd : 1.f - rd);
            bool ok = ((unsigned)hh < 32u) & ((unsigned)wq < 32u) & ((unsigned)dq < 32u);
            wgs[cb] = (_Float16)(ok ? wg : 0.f);
            mask |= (ok ? 1 : 0) << cb;
        }
        TPv[idx] = ((nb0 + 4096) << 8) | mask;
        *(half8*)&TPwg[idx * 8] = wgs;
    }
    __syncthreads();

    int p8 = lane >> 3, co = lane & 7;
    for (int idx = wv; idx < 54; idx += 4) {          // Phase B
        int k = idx >> 1, phf = idx & 1;
        int tap = k * 16 + phf * 8 + p8;
        int v = TPv[tap];
        int nb = (v >> 8) - 4096, mask = v & 255;
        half8 wgv = *(const half8*)&TPwg[tap * 8];
        half2v a0 = (half2v)0, a1 = (half2v)0, a2 = (half2v)0, a3 = (half2v)0;
        #pragma unroll
        for (int i = 0; i < 8; ++i) {
            int nn = nb + ((i >> 2) & 1) * 1024 + ((i >> 1) & 1) * 32 + (i & 1);
            bool okc = (mask >> i) & 1;
            size_t ad = okc ? ((size_t)nn << 6) : 0;
            half8 vv = *(const half8*)(aTh + ad + (co << 3));
            half2v wg2 = (half2v){wgv[i], wgv[i]};
            a0 += (half2v){vv[0], vv[1]} * wg2;
            a1 += (half2v){vv[2], vv[3]} * wg2;
            a2 += (half2v){vv[4], vv[5]} * wg2;
            a3 += (half2v){vv[6], vv[7]} * wg2;
        }
        half8 r;
        r[0] = a0[0]; r[1] = a0[1]; r[2] = a1[0]; r[3] = a1[1];
        r[4] = a2[0]; r[5] = a2[1]; r[6] = a3[0]; r[7] = a3[1];
        int p = phf * 8 + p8;
        *(half8*)&S[p * 1736 + k * 64 + (co << 3)] = r;
    }
    __syncthreads();

    // Phase C: full 16x16 tiles
    f32x4 acc4 = {0.f, 0.f, 0.f, 0.f};
    const half8* wbase = Wp + wv * 64 + lane;
    const _Float16* sbase = &S[(lane & 15) * 1736 + (lane >> 4) * 8];
    #pragma unroll 9
    for (int kb = 0; kb < 54; ++kb) {
        half8 af = wbase[(size_t)kb * 256];
        half8 bf = *(const half8*)(sbase + kb * 32);
        acc4 = __builtin_amdgcn_mfma_f32_16x16x32_f16(af, bf, acc4, 0, 0, 0);
    }
    int pl = lane & 15, g = lane >> 4;
    #pragma unroll
    for (int r2 = 0; r2 < 4; ++r2) {
        int o = wv * 16 + g * 4 + r2;
        dcn[(size_t)o * NSP + n0 + pl] = acc4[r2] + db[o];
    }
}

// ---------------------------------------------------------------------------
// K7 (MFMA): a2 = conv1_w @ dcn + b ; h = U * a2 ; out = proj2_w @ h + b2 + x
__global__ __launch_bounds__(256) void k_finalm(const float* __restrict__ dcn,
        const float* __restrict__ U, const float* __restrict__ x,
        const half8* __restrict__ Wc1, const float* __restrict__ c1b,
        const half8* __restrict__ Wp2f, const float* __restrict__ p2b,
        float* __restrict__ out) {
    __shared__ __align__(16) _Float16 Sd[64 * 72];   // 9216 B
    __shared__ __align__(16) _Float16 Sh[64 * 72];   // 9216 B
    int t = threadIdx.x;
    int n0 = blockIdx.x * 64;
    int lane = t & 63, wv = t >> 6;
    for (int i = wv; i < 64; i += 4) {
        float v = dcn[(size_t)i * NSP + n0 + lane];
        Sd[lane * 72 + i] = (_Float16)v;
    }
    __syncthreads();

    int pl = lane & 15, g = lane >> 4;
    int ob = wv;
    const half8* w1 = Wc1 + ob * 64 + lane;
    #pragma unroll
    for (int nt = 0; nt < 4; ++nt) {                 // GEMM1 + gate
        f32x4 acc4 = {0.f, 0.f, 0.f, 0.f};
        const _Float16* sb = &Sd[(nt * 16 + pl) * 72 + g * 8];
        #pragma unroll
        for (int kb = 0; kb < 2; ++kb) {
            half8 af = w1[kb * 256];
            half8 bf = *(const half8*)(sb + kb * 32);
            acc4 = __builtin_amdgcn_mfma_f32_16x16x32_f16(af, bf, acc4, 0, 0, 0);
        }
        int n = n0 + nt * 16 + pl;
        int o0 = ob * 16 + g * 4;
        float4 bb = *(const float4*)&c1b[o0];
        half4 hv;
        hv[0] = (_Float16)(U[(size_t)(o0 + 0) * NSP + n] * (acc4[0] + bb.x));
        hv[1] = (_Float16)(U[(size_t)(o0 + 1) * NSP + n] * (acc4[1] + bb.y));
        hv[2] = (_Float16)(U[(size_t)(o0 + 2) * NSP + n] * (acc4[2] + bb.z));
        hv[3] = (_Float16)(U[(size_t)(o0 + 3) * NSP + n] * (acc4[3] + bb.w));
        *(half4*)&Sh[(nt * 16 + pl) * 72 + o0] = hv;
    }
    __syncthreads();

    const half8* w2 = Wp2f + ob * 64 + lane;
    #pragma unroll
    for (int nt = 0; nt < 4; ++nt) {                 // GEMM2 + residual
        f32x4 acc4 = {0.f, 0.f, 0.f, 0.f};
        const _Float16* sb = &Sh[(nt * 16 + pl) * 72 + g * 8];
        #pragma unroll
        for (int kb = 0; kb < 2; ++kb) {
            half8 af = w2[kb * 256];
            half8 bf = *(const half8*)(sb + kb * 32);
            acc4 = __builtin_amdgcn_mfma_f32_16x16x32_f16(af, bf, acc4, 0, 0, 0);
        }
        int n = n0 + nt * 16 + pl;
        int o0 = ob * 16 + g * 4;
        float4 bb = *(const float4*)&p2b[o0];
        float4 xr = *(const float4*)&x[(size_t)n * 64 + o0];
        float4 ov;
        ov.x = acc4[0] + bb.x + xr.x;
        ov.y = acc4[1] + bb.y + xr.y;
        ov.z = acc4[2] + bb.z + xr.z;
        ov.w = acc4[3] + bb.w + xr.w;
        *(float4*)&out[(size_t)n * 64 + o0] = ov;
    }
}

// ---------------------------------------------------------------------------
extern "C" void kernel_launch(void* const* d_in, const int* in_sizes, int n_in,
                              void* d_out, int out_size, void* d_ws, size_t ws_size,
                              hipStream_t stream) {
    const float* x   = (const float*)d_in[0];
    const float* p1w = (const float*)d_in[1];
    const float* p1b = (const float*)d_in[2];
    const float* c0w = (const float*)d_in[3];
    const float* c0b = (const float*)d_in[4];
    const float* csw = (const float*)d_in[5];
    const float* csb = (const float*)d_in[6];
    const float* ofw = (const float*)d_in[7];
    const float* ofb = (const float*)d_in[8];
    const float* dcw = (const float*)d_in[9];
    const float* dcb = (const float*)d_in[10];
    const float* c1w = (const float*)d_in[11];
    const float* c1b = (const float*)d_in[12];
    const float* p2w = (const float*)d_in[13];
    const float* p2b = (const float*)d_in[14];
    float* out = (float*)d_out;

    char* ws = (char*)d_ws;
    const size_t CN4 = (size_t)NCH * NSP * 4;       // 8 MiB per [C][N] f32
    float* U    = (float*)(ws);
    float* T0   = (float*)(ws + CN4);
    float* T1   = (float*)(ws + 2 * CN4);
    float* OFFp = (float*)(ws + 4 * CN4);           // 81*N f32
    float* DCN  = (float*)(ws + 4 * CN4 + (size_t)81 * NSP * 4);
    _Float16* Wp   = (_Float16*)(ws + 5 * CN4 + (size_t)81 * NSP * 4);
    _Float16* Wp2  = Wp + 110592;
    _Float16* Wp1  = Wp2 + 165888;
    _Float16* Wc1  = Wp1 + 4096;
    _Float16* Wp2f = Wc1 + 4096;
    _Float16* aTh  = (_Float16*)T0;                 // reuses T0 (dead after dw7)

    k_wpack64  <<<16, 256, 0, stream>>>(p1w, Wp1);
    k_wpack64  <<<16, 256, 0, stream>>>(c1w, Wc1);
    k_wpack64  <<<16, 256, 0, stream>>>(p2w, Wp2f);
    k_wpack    <<<432, 256, 0, stream>>>(dcw, Wp);
    k_wpack_off<<<648, 256, 0, stream>>>(ofw, Wp2);
    k_proj1m   <<<NSP / 64, 256, 0, stream>>>(x, (const half8*)Wp1, p1b, U);
    k_dw5      <<<1024, 256, 0, stream>>>(U, c0w, c0b, T0);
    k_dw7      <<<768, 256, 0, stream>>>(T0, csw, csb, T1);
    k_tr       <<<NSP / 64, 256, 0, stream>>>(T1, aTh);
    k_offg     <<<512, 384, 0, stream>>>(aTh, (const half8*)Wp2, ofb, OFFp);
    k_deform   <<<2048, 256, 0, stream>>>(aTh, OFFp, (const half8*)Wp, dcb, DCN);
    k_finalm   <<<NSP / 64, 256, 0, stream>>>(DCN, U, x, (const half8*)Wc1, c1b,
                                              (const half8*)Wp2f, p2b, out);
}

// Round 11
// 169.240 us; speedup vs baseline: 16.2665x; 1.1666x over previous
//
#include <hip/hip_runtime.h>
#include <math.h>

#define NSP 32768   // H*W*D = 32*32*32
#define NCH 64

typedef _Float16 half8 __attribute__((ext_vector_type(8)));
typedef _Float16 half4 __attribute__((ext_vector_type(4)));
typedef _Float16 half2v __attribute__((ext_vector_type(2)));
typedef float f32x4 __attribute__((ext_vector_type(4)));

// ---------------------------------------------------------------------------
// K1 (MFMA): U = gelu(proj1_w @ x^T + b)   (U layout: [C][N])
__global__ __launch_bounds__(256) void k_proj1m(const float* __restrict__ x,
        const half8* __restrict__ Wp1, const float* __restrict__ b,
        float* __restrict__ U) {
    __shared__ __align__(16) _Float16 Sx[64 * 72];   // 9216 B
    int t = threadIdx.x;
    int n0 = blockIdx.x * 64;
    int lane = t & 63, wv = t >> 6;
    for (int i = wv; i < 64; i += 4) {
        float v = x[(size_t)(n0 + i) * 64 + lane];
        Sx[i * 72 + lane] = (_Float16)v;
    }
    __syncthreads();
    int pl = lane & 15, g = lane >> 4;
    int ob = wv;
    const half8* wbase = Wp1 + ob * 64 + lane;       // +256 per kb
    #pragma unroll
    for (int nt = 0; nt < 4; ++nt) {
        f32x4 acc4 = {0.f, 0.f, 0.f, 0.f};
        const _Float16* sb = &Sx[(nt * 16 + pl) * 72 + g * 8];
        #pragma unroll
        for (int kb = 0; kb < 2; ++kb) {
            half8 af = wbase[kb * 256];
            half8 bf = *(const half8*)(sb + kb * 32);
            acc4 = __builtin_amdgcn_mfma_f32_16x16x32_f16(af, bf, acc4, 0, 0, 0);
        }
        int n = n0 + nt * 16 + pl;
        #pragma unroll
        for (int r = 0; r < 4; ++r) {
            int o = ob * 16 + g * 4 + r;
            float a = acc4[r] + b[o];
            float gv = 0.5f * a * (1.0f + erff(a * 0.70710678118654752f));
            U[(size_t)o * NSP + n] = gv;
        }
    }
}

// ---------------------------------------------------------------------------
// K2: depthwise 5x5x5, pad 2.  Weights uniform->SGPR; values via dbuf LDS.
__global__ __launch_bounds__(256) void k_dw5(const float* __restrict__ in,
        const float* __restrict__ w, const float* __restrict__ b,
        float* __restrict__ out) {
    __shared__ float Sb5[2][20 * 38];                // 6080 B
    int t = threadIdx.x;
    int bid = blockIdx.x;
    int blk = (bid & 7) * 128 + (bid >> 3);          // XCD-chunked
    int c  = blk >> 4;
    int hq = (blk >> 1) & 7;
    int wq = blk & 1;
    int d  = t & 31;
    int wbloc = t >> 5;                              // 0..7
    int wb = wq * 8 + wbloc;
    const float* wc = w + c * 125;                   // uniform -> scalar loads
    const float* src = in + (size_t)c * NSP;

    float bc = b[c];
    float acc[4][2];
    #pragma unroll
    for (int a = 0; a < 4; ++a) { acc[a][0] = bc; acc[a][1] = bc; }

    #define STAGE5(m)                                                        \
        { int hh_ = 4 * hq + (m) - 2;                                        \
          if ((unsigned)hh_ < 32u) {                                         \
            const float* row_ = src + (hh_ << 10);                           \
            for (int idx = t; idx < 20 * 36; idx += 256) {                   \
                int wi = idx / 36, Dp = idx - wi * 36;                       \
                int wj = 16 * wq - 2 + wi, di = Dp - 2;                      \
                bool ok = ((unsigned)wj < 32u) & ((unsigned)di < 32u);       \
                Sb5[(m) & 1][wi * 38 + Dp] = ok ? row_[(wj << 5) + di] : 0.f;\
            } } }

    STAGE5(0)
    __syncthreads();
    #pragma unroll 1
    for (int m = 0; m < 8; ++m) {
        if (m < 7) STAGE5(m + 1)
        int hh = 4 * hq + m - 2;
        if ((unsigned)hh < 32u) {
            float v[6][5];
            const float* sb = &Sb5[m & 1][0];
            #pragma unroll
            for (int jc = 0; jc < 6; ++jc)
                #pragma unroll
                for (int l = 0; l < 5; ++l)
                    v[jc][l] = sb[(2 * wbloc + jc) * 38 + d + l];
            #pragma unroll
            for (int a = 0; a < 4; ++a) {
                if (a <= m && m <= a + 4) {
                    const float* wr = wc + (m - a) * 25;   // uniform
                    float s0 = 0.f, s1 = 0.f;
                    #pragma unroll
                    for (int j = 0; j < 5; ++j)
                        #pragma unroll
                        for (int l = 0; l < 5; ++l) {
                            float wv2 = wr[j * 5 + l];
                            s0 += wv2 * v[j][l];
                            s1 += wv2 * v[j + 1][l];
                        }
                    acc[a][0] += s0;
                    acc[a][1] += s1;
                }
            }
        }
        __syncthreads();
    }
    #pragma unroll
    for (int a = 0; a < 4; ++a)
        #pragma unroll
        for (int bb = 0; bb < 2; ++bb)
            out[(size_t)c * NSP + ((4 * hq + a) << 10) + ((2 * wb + bb) << 5) + d]
                = acc[a][bb];
    #undef STAGE5
}

// ---------------------------------------------------------------------------
// K3: depthwise 7x7x7 dilation 3.  Weights uniform->SGPR; values dbuf LDS.
__global__ __launch_bounds__(256) void k_dw7(const float* __restrict__ in,
        const float* __restrict__ w, const float* __restrict__ b,
        float* __restrict__ out) {
    __shared__ float Sb7[2][26 * 52];                // 10816 B
    int t = threadIdx.x;
    int bid = blockIdx.x;
    int blk = (bid & 7) * 96 + (bid >> 3);           // XCD-chunked
    int c  = blk / 12;
    int h0 = (blk % 12) >> 2;
    int wq = blk & 3;
    int d  = t & 31;
    int wloc = t >> 5;                               // 0..7
    int w_ = wq * 8 + wloc;
    const float* wc = w + c * 343;                   // uniform -> scalar loads
    const float* src = in + (size_t)c * NSP;

    float bc = b[c];
    float acc[11];
    #pragma unroll
    for (int a = 0; a < 11; ++a) acc[a] = bc;

    #define STAGE7(m)                                                        \
        { int hh_ = h0 + 3 * (m) - 9;                                        \
          if ((unsigned)hh_ < 32u) {                                         \
            const float* row_ = src + (hh_ << 10);                           \
            for (int idx = t; idx < 26 * 50; idx += 256) {                   \
                int wi = idx / 50, Dp = idx - wi * 50;                       \
                int wj = 8 * wq - 9 + wi, di = Dp - 9;                       \
                bool ok = ((unsigned)wj < 32u) & ((unsigned)di < 32u);       \
                Sb7[(m) & 1][wi * 52 + Dp] = ok ? row_[(wj << 5) + di] : 0.f;\
            } } }

    STAGE7(0)
    __syncthreads();
    #pragma unroll 1
    for (int m = 0; m < 17; ++m) {
        if (m < 16) STAGE7(m + 1)
        int hh = h0 + 3 * m - 9;
        if ((unsigned)hh < 32u) {
            float v[7][7];
            const float* sb = &Sb7[m & 1][0];
            #pragma unroll
            for (int jw = 0; jw < 7; ++jw)
                #pragma unroll
                for (int l = 0; l < 7; ++l)
                    v[jw][l] = sb[(wloc + 3 * jw) * 52 + d + 3 * l];
            #pragma unroll
            for (int a = 0; a < 11; ++a) {
                if (a <= m && m <= a + 6) {
                    const float* wr = wc + (m - a) * 49;   // uniform
                    float s = 0.f;
                    #pragma unroll
                    for (int jw = 0; jw < 7; ++jw)
                        #pragma unroll
                        for (int l = 0; l < 7; ++l)
                            s += wr[jw * 7 + l] * v[jw][l];
                    acc[a] += s;
                }
            }
        }
        __syncthreads();
    }
    #pragma unroll
    for (int a = 0; a < 11; ++a) {
        int h = h0 + 3 * a;
        if (h < 32)
            out[(size_t)c * NSP + (h << 10) + (w_ << 5) + d] = acc[a];
    }
    #undef STAGE7
}

// ---------------------------------------------------------------------------
// K4: transpose [C][N] -> f16 [N][C]
__global__ __launch_bounds__(256) void k_tr(const float* __restrict__ in,
        _Float16* __restrict__ outh) {
    __shared__ float tile[64 * 65];
    int t = threadIdx.x;
    int n0 = blockIdx.x * 64;
    for (int i = 0; i < 16; ++i) {
        int idx = i * 256 + t;
        int c = idx >> 6, nl = idx & 63;
        tile[c * 65 + nl] = in[(size_t)c * NSP + n0 + nl];
    }
    __syncthreads();
    for (int i = 0; i < 16; ++i) {
        int idx = i * 256 + t;
        int nl = idx >> 6, c = idx & 63;
        outh[(size_t)(n0 + nl) * 64 + c] = (_Float16)tile[c * 65 + nl];
    }
}

// ---------------------------------------------------------------------------
// K5a: pre-pack deform weights into f16 MFMA A-fragment order.
__global__ __launch_bounds__(256) void k_wpack(const float* __restrict__ dw,
        _Float16* __restrict__ Wp) {
    int idx = blockIdx.x * 256 + threadIdx.x;   // 0 .. 110591
    int j = idx & 7;
    int l = (idx >> 3) & 63;
    int obk = idx >> 9;
    int ob = obk & 3, kb = obk >> 2;
    int o = ob * 16 + (l & 15);
    int Kp = kb * 32 + (l >> 4) * 8 + j;
    int k = Kp >> 6, c = Kp & 63;
    Wp[idx] = (_Float16)dw[(size_t)o * 1728 + c * 27 + k];
}

// ---------------------------------------------------------------------------
// K5b: pre-pack offset-conv weights, 6 o-blocks of 16 (rows 81..95 = 0).
__global__ __launch_bounds__(256) void k_wpack_off(const float* __restrict__ ow,
        _Float16* __restrict__ Wp2) {
    int idx = blockIdx.x * 256 + threadIdx.x;   // 0 .. 165887
    int j = idx & 7;
    int l = (idx >> 3) & 63;
    int obk = idx >> 9;                          // 0 .. 323
    int ob = obk % 6, kb = obk / 6;
    int o = ob * 16 + (l & 15);
    int Kp = kb * 32 + (l >> 4) * 8 + j;
    int k = Kp >> 6, c = Kp & 63;
    Wp2[idx] = (o < 81) ? (_Float16)ow[(size_t)o * 1728 + c * 27 + k]
                        : (_Float16)0.f;
}

// ---------------------------------------------------------------------------
// K5d: pack a 64x64 f32 weight matrix into A-frag order (4 ob x 2 kb).
__global__ __launch_bounds__(256) void k_wpack64(const float* __restrict__ w,
        _Float16* __restrict__ Wp) {
    int idx = blockIdx.x * 256 + threadIdx.x;   // 0 .. 4095
    int j = idx & 7;
    int l = (idx >> 3) & 63;
    int obk = idx >> 9;                          // 0..7
    int ob = obk & 3, kb = obk >> 2;
    int o = ob * 16 + (l & 15);
    int Kp = kb * 32 + (l >> 4) * 8 + j;
    Wp[idx] = (_Float16)w[o * 64 + Kp];
}

// ---------------------------------------------------------------------------
// K5c: offset conv, 64-position tile, kh-chunked DOUBLE-BUFFERED halo.
// Taps with h-offset kh only touch nbr rows kh*4+0..3 -> stage 4 w-rows per
// chunk (19.6 KB), 2 buffers = 39.2 KB -> 4 blocks/CU (was 2).  Pipeline:
// stage(kh+1) overlaps MFMA(kh).  Per kb one A-frag feeds 4 p-tile MFMAs.
__global__ __launch_bounds__(384) void k_offg(const _Float16* __restrict__ aTh,
        const half8* __restrict__ Wp2, const float* __restrict__ obias,
        float* __restrict__ off) {
    __shared__ __align__(16) _Float16 S2[2][4 * 34 * 72];   // 39168 B
    int t = threadIdx.x;
    int bid = blockIdx.x;
    int blk = (bid & 7) * 64 + (bid >> 3);   // 512 blocks, h-slabs per XCD
    int h = blk >> 4, w0 = (blk & 15) * 2;
    int n0 = (h << 10) + (w0 << 5);
    int lane = t & 63, wv = t >> 6;          // wv 0..5

    int pl = lane & 15, g = lane >> 4;
    int obi = wv;
    f32x4 acc[4];
    #pragma unroll
    for (int i = 0; i < 4; ++i) acc[i] = (f32x4){0.f, 0.f, 0.f, 0.f};
    const half8* wb = Wp2 + obi * 64 + lane;

    // stage chunk kh into buffer kh&1: 4 w-nbrs x 34 dd, h-row = h+kh-1
    #define OSTAGE(kh)                                                        \
        { int hh_ = h + (kh) - 1;                                            \
          bool okh_ = (unsigned)hh_ < 32u;                                   \
          for (int i = wv; i < 136; i += 6) {                                \
              int nbw = i / 34, dd = i - nbw * 34;                           \
              int wj = w0 + nbw - 1, di = dd - 1;                            \
              bool ok = okh_ & ((unsigned)wj < 32u) & ((unsigned)di < 32u);  \
              _Float16 v = ok ?                                              \
                  aTh[(size_t)(((hh_ << 5) + wj) * 32 + di) * 64 + lane]     \
                  : (_Float16)0.f;                                           \
              S2[(kh) & 1][(nbw * 34 + dd) * 72 + lane] = v;                 \
          } }

    // MFMA chunk kh: 18 kbs (taps kh*9 .. kh*9+8), rows local to buffer
    #define OCOMP(kh)                                                        \
        { const _Float16* sb = &S2[(kh) & 1][pl * 72 + g * 8];               \
          _Pragma("unroll")                                                  \
          for (int kk = 0; kk < 18; ++kk) {                                  \
              int kglob = (kh) * 9 + (kk >> 1);                              \
              int kw3 = (kglob / 3) % 3, kd = kglob % 3;                     \
              half8 af = wb[(size_t)((kh) * 18 + kk) * 384];                 \
              _Pragma("unroll")                                              \
              for (int pt = 0; pt < 4; ++pt) {                               \
                  int row = ((pt >> 1) + kw3) * 34 + (pt & 1) * 16 + kd;     \
                  half8 bf = *(const half8*)(sb + row * 72 + (kk & 1) * 32); \
                  acc[pt] = __builtin_amdgcn_mfma_f32_16x16x32_f16(          \
                                af, bf, acc[pt], 0, 0, 0);                   \
              }                                                              \
          } }

    OSTAGE(0)
    __syncthreads();
    OSTAGE(1)
    OCOMP(0)
    __syncthreads();
    OSTAGE(2)
    OCOMP(1)
    __syncthreads();
    OCOMP(2)
    #undef OSTAGE
    #undef OCOMP

    #pragma unroll
    for (int pt = 0; pt < 4; ++pt) {
        #pragma unroll
        for (int r = 0; r < 4; ++r) {
            int o = obi * 16 + g * 4 + r;
            if (o < 81)
                off[(size_t)o * NSP + n0 + pt * 16 + pl] = acc[pt][r] + obias[o];
        }
    }
}

// ---------------------------------------------------------------------------
// K6: deformable gather + MFMA GEMM, 16-position blocks, K-CHUNKED S.
// S holds 14 taps at a time (taps {0..13}, {14..26}); phase B/C alternate,
// accumulating into one acc4.  LDS 37.6 KB -> 4 blocks/CU (was 2).
__global__ __launch_bounds__(256) void k_deform(const _Float16* __restrict__ aTh,
        const float* __restrict__ off, const half8* __restrict__ Wp,
        const float* __restrict__ db, float* __restrict__ dcn) {
    __shared__ __align__(16) _Float16 S[16 * 904];     // 28928 B
    __shared__ __align__(16) _Float16 TPwg[432 * 8];   // 6912 B
    __shared__ int TPv[432];                           // 1728 B (total 37568)
    int t = threadIdx.x;
    int bid = blockIdx.x;
    int blk = (bid & 7) * 256 + (bid >> 3);  // 2048 blocks, n-slabs per XCD
    int n0 = blk * 16;
    int lane = t & 63, wv = t >> 6;

    for (int idx = t; idx < 432; idx += 256) {        // Phase A: all 432 taps
        int p = idx & 15, k = idx >> 4;
        int n = n0 + p;
        int h = n >> 10, w = (n >> 5) & 31, d = n & 31;
        float ph = (float)(h + k / 9 - 1)       + off[(size_t)(k * 3 + 0) * NSP + n];
        float pw = (float)(w + (k / 3) % 3 - 1) + off[(size_t)(k * 3 + 1) * NSP + n];
        float pd = (float)(d + k % 3 - 1)       + off[(size_t)(k * 3 + 2) * NSP + n];
        float fh = floorf(ph), fw = floorf(pw), fd = floorf(pd);
        int ih = (int)fh, iw = (int)fw, id = (int)fd;
        float rh = ph - fh, rw = pw - fw, rd = pd - fd;
        int nb0 = ih * 1024 + iw * 32 + id;
        int mask = 0;
        half8 wgs;
        #pragma unroll
        for (int cb = 0; cb < 8; ++cb) {
            int hh = ih + ((cb >> 2) & 1);
            int wq = iw + ((cb >> 1) & 1);
            int dq = id + (cb & 1);
            float wg = ((cb & 4) ? rh : 1.f - rh) * ((cb & 2) ? rw : 1.f - rw)
                     * ((cb & 1) ? rd : 1.f - rd);
            bool ok = ((unsigned)hh < 32u) & ((unsigned)wq < 32u) & ((unsigned)dq < 32u);
            wgs[cb] = (_Float16)(ok ? wg : 0.f);
            mask |= (ok ? 1 : 0) << cb;
        }
        TPv[idx] = ((nb0 + 4096) << 8) | mask;
        *(half8*)&TPwg[idx * 8] = wgs;
    }
    __syncthreads();

    int p8 = lane >> 3, co = lane & 7;
    f32x4 acc4 = {0.f, 0.f, 0.f, 0.f};
    const half8* wbase = Wp + wv * 64 + lane;
    const _Float16* sbase = &S[(lane & 15) * 904 + (lane >> 4) * 8];

    // gather taps [T0, T0+NT) into S rows kk = k-T0
    #define GATHER(T0, NT)                                                   \
        for (int idx = wv; idx < (NT) * 2; idx += 4) {                       \
            int kk = idx >> 1, phf = idx & 1;                                \
            int tap = ((T0) + kk) * 16 + phf * 8 + p8;                       \
            int v = TPv[tap];                                                \
            int nb = (v >> 8) - 4096, mask = v & 255;                        \
            half8 wgv = *(const half8*)&TPwg[tap * 8];                       \
            half2v a0 = (half2v)0, a1 = (half2v)0, a2 = (half2v)0,           \
                   a3 = (half2v)0;                                           \
            _Pragma("unroll")                                                \
            for (int i = 0; i < 8; ++i) {                                    \
                int nn = nb + ((i >> 2) & 1) * 1024 + ((i >> 1) & 1) * 32    \
                       + (i & 1);                                            \
                bool okc = (mask >> i) & 1;                                  \
                size_t ad = okc ? ((size_t)nn << 6) : 0;                     \
                half8 vv = *(const half8*)(aTh + ad + (co << 3));            \
                half2v wg2 = (half2v){wgv[i], wgv[i]};                       \
                a0 += (half2v){vv[0], vv[1]} * wg2;                          \
                a1 += (half2v){vv[2], vv[3]} * wg2;                          \
                a2 += (half2v){vv[4], vv[5]} * wg2;                          \
                a3 += (half2v){vv[6], vv[7]} * wg2;                          \
            }                                                                \
            half8 r;                                                         \
            r[0] = a0[0]; r[1] = a0[1]; r[2] = a1[0]; r[3] = a1[1];          \
            r[4] = a2[0]; r[5] = a2[1]; r[6] = a3[0]; r[7] = a3[1];          \
            int p = phf * 8 + p8;                                            \
            *(half8*)&S[p * 904 + kk * 64 + (co << 3)] = r;                  \
        }

    GATHER(0, 14)                       // chunk 0: taps 0..13
    __syncthreads();
    #pragma unroll
    for (int kb = 0; kb < 28; ++kb) {
        half8 af = wbase[(size_t)kb * 256];
        half8 bf = *(const half8*)(sbase + kb * 32);
        acc4 = __builtin_amdgcn_mfma_f32_16x16x32_f16(af, bf, acc4, 0, 0, 0);
    }
    __syncthreads();                    // WAR: chunk-0 reads done
    GATHER(14, 13)                      // chunk 1: taps 14..26
    __syncthreads();
    #pragma unroll
    for (int kb = 0; kb < 26; ++kb) {
        half8 af = wbase[(size_t)(28 + kb) * 256];
        half8 bf = *(const half8*)(sbase + kb * 32);
        acc4 = __builtin_amdgcn_mfma_f32_16x16x32_f16(af, bf, acc4, 0, 0, 0);
    }
    #undef GATHER

    int pl = lane & 15, g = lane >> 4;
    #pragma unroll
    for (int r2 = 0; r2 < 4; ++r2) {
        int o = wv * 16 + g * 4 + r2;
        dcn[(size_t)o * NSP + n0 + pl] = acc4[r2] + db[o];
    }
}

// ---------------------------------------------------------------------------
// K7 (MFMA): a2 = conv1_w @ dcn + b ; h = U * a2 ; out = proj2_w @ h + b2 + x
__global__ __launch_bounds__(256) void k_finalm(const float* __restrict__ dcn,
        const float* __restrict__ U, const float* __restrict__ x,
        const half8* __restrict__ Wc1, const float* __restrict__ c1b,
        const half8* __restrict__ Wp2f, const float* __restrict__ p2b,
        float* __restrict__ out) {
    __shared__ __align__(16) _Float16 Sd[64 * 72];   // 9216 B
    __shared__ __align__(16) _Float16 Sh[64 * 72];   // 9216 B
    int t = threadIdx.x;
    int n0 = blockIdx.x * 64;
    int lane = t & 63, wv = t >> 6;
    for (int i = wv; i < 64; i += 4) {
        float v = dcn[(size_t)i * NSP + n0 + lane];
        Sd[lane * 72 + i] = (_Float16)v;
    }
    __syncthreads();

    int pl = lane & 15, g = lane >> 4;
    int ob = wv;
    const half8* w1 = Wc1 + ob * 64 + lane;
    #pragma unroll
    for (int nt = 0; nt < 4; ++nt) {                 // GEMM1 + gate
        f32x4 acc4 = {0.f, 0.f, 0.f, 0.f};
        const _Float16* sb = &Sd[(nt * 16 + pl) * 72 + g * 8];
        #pragma unroll
        for (int kb = 0; kb < 2; ++kb) {
            half8 af = w1[kb * 256];
            half8 bf = *(const half8*)(sb + kb * 32);
            acc4 = __builtin_amdgcn_mfma_f32_16x16x32_f16(af, bf, acc4, 0, 0, 0);
        }
        int n = n0 + nt * 16 + pl;
        int o0 = ob * 16 + g * 4;
        float4 bb = *(const float4*)&c1b[o0];
        half4 hv;
        hv[0] = (_Float16)(U[(size_t)(o0 + 0) * NSP + n] * (acc4[0] + bb.x));
        hv[1] = (_Float16)(U[(size_t)(o0 + 1) * NSP + n] * (acc4[1] + bb.y));
        hv[2] = (_Float16)(U[(size_t)(o0 + 2) * NSP + n] * (acc4[2] + bb.z));
        hv[3] = (_Float16)(U[(size_t)(o0 + 3) * NSP + n] * (acc4[3] + bb.w));
        *(half4*)&Sh[(nt * 16 + pl) * 72 + o0] = hv;
    }
    __syncthreads();

    const half8* w2 = Wp2f + ob * 64 + lane;
    #pragma unroll
    for (int nt = 0; nt < 4; ++nt) {                 // GEMM2 + residual
        f32x4 acc4 = {0.f, 0.f, 0.f, 0.f};
        const _Float16* sb = &Sh[(nt * 16 + pl) * 72 + g * 8];
        #pragma unroll
        for (int kb = 0; kb < 2; ++kb) {
            half8 af = w2[kb * 256];
            half8 bf = *(const half8*)(sb + kb * 32);
            acc4 = __builtin_amdgcn_mfma_f32_16x16x32_f16(af, bf, acc4, 0, 0, 0);
        }
        int n = n0 + nt * 16 + pl;
        int o0 = ob * 16 + g * 4;
        float4 bb = *(const float4*)&p2b[o0];
        float4 xr = *(const float4*)&x[(size_t)n * 64 + o0];
        float4 ov;
        ov.x = acc4[0] + bb.x + xr.x;
        ov.y = acc4[1] + bb.y + xr.y;
        ov.z = acc4[2] + bb.z + xr.z;
        ov.w = acc4[3] + bb.w + xr.w;
        *(float4*)&out[(size_t)n * 64 + o0] = ov;
    }
}

// ---------------------------------------------------------------------------
extern "C" void kernel_launch(void* const* d_in, const int* in_sizes, int n_in,
                              void* d_out, int out_size, void* d_ws, size_t ws_size,
                              hipStream_t stream) {
    const float* x   = (const float*)d_in[0];
    const float* p1w = (const float*)d_in[1];
    const float* p1b = (const float*)d_in[2];
    const float* c0w = (const float*)d_in[3];
    const float* c0b = (const float*)d_in[4];
    const float* csw = (const float*)d_in[5];
    const float* csb = (const float*)d_in[6];
    const float* ofw = (const float*)d_in[7];
    const float* ofb = (const float*)d_in[8];
    const float* dcw = (const float*)d_in[9];
    const float* dcb = (const float*)d_in[10];
    const float* c1w = (const float*)d_in[11];
    const float* c1b = (const float*)d_in[12];
    const float* p2w = (const float*)d_in[13];
    const float* p2b = (const float*)d_in[14];
    float* out = (float*)d_out;

    char* ws = (char*)d_ws;
    const size_t CN4 = (size_t)NCH * NSP * 4;       // 8 MiB per [C][N] f32
    float* U    = (float*)(ws);
    float* T0   = (float*)(ws + CN4);
    float* T1   = (float*)(ws + 2 * CN4);
    float* OFFp = (float*)(ws + 4 * CN4);           // 81*N f32
    float* DCN  = (float*)(ws + 4 * CN4 + (size_t)81 * NSP * 4);
    _Float16* Wp   = (_Float16*)(ws + 5 * CN4 + (size_t)81 * NSP * 4);
    _Float16* Wp2  = Wp + 110592;
    _Float16* Wp1  = Wp2 + 165888;
    _Float16* Wc1  = Wp1 + 4096;
    _Float16* Wp2f = Wc1 + 4096;
    _Float16* aTh  = (_Float16*)T0;                 // reuses T0 (dead after dw7)

    k_wpack64  <<<16, 256, 0, stream>>>(p1w, Wp1);
    k_wpack64  <<<16, 256, 0, stream>>>(c1w, Wc1);
    k_wpack64  <<<16, 256, 0, stream>>>(p2w, Wp2f);
    k_wpack    <<<432, 256, 0, stream>>>(dcw, Wp);
    k_wpack_off<<<648, 256, 0, stream>>>(ofw, Wp2);
    k_proj1m   <<<NSP / 64, 256, 0, stream>>>(x, (const half8*)Wp1, p1b, U);
    k_dw5      <<<1024, 256, 0, stream>>>(U, c0w, c0b, T0);
    k_dw7      <<<768, 256, 0, stream>>>(T0, csw, csb, T1);
    k_tr       <<<NSP / 64, 256, 0, stream>>>(T1, aTh);
    k_offg     <<<512, 384, 0, stream>>>(aTh, (const half8*)Wp2, ofb, OFFp);
    k_deform   <<<2048, 256, 0, stream>>>(aTh, OFFp, (const half8*)Wp, dcb, DCN);
    k_finalm   <<<NSP / 64, 256, 0, stream>>>(DCN, U, x, (const half8*)Wc1, c1b,
                                              (const half8*)Wp2f, p2b, out);
}

// Round 12
// 131.327 us; speedup vs baseline: 20.9625x; 1.2887x over previous
//
#include <hip/hip_runtime.h>
#include <math.h>

#define NSP 32768   // H*W*D = 32*32*32
#define NCH 64

typedef _Float16 half8 __attribute__((ext_vector_type(8)));
typedef _Float16 half4 __attribute__((ext_vector_type(4)));
typedef _Float16 half2v __attribute__((ext_vector_type(2)));
typedef float f32x4 __attribute__((ext_vector_type(4)));

// ---------------------------------------------------------------------------
// K1 (MFMA): U = gelu(proj1_w @ x^T + b)   (U layout: [C][N])
__global__ __launch_bounds__(256) void k_proj1m(const float* __restrict__ x,
        const half8* __restrict__ Wp1, const float* __restrict__ b,
        float* __restrict__ U) {
    __shared__ __align__(16) _Float16 Sx[64 * 72];   // 9216 B
    int t = threadIdx.x;
    int n0 = blockIdx.x * 64;
    int lane = t & 63, wv = t >> 6;
    for (int i = wv; i < 64; i += 4) {
        float v = x[(size_t)(n0 + i) * 64 + lane];
        Sx[i * 72 + lane] = (_Float16)v;
    }
    __syncthreads();
    int pl = lane & 15, g = lane >> 4;
    int ob = wv;
    const half8* wbase = Wp1 + ob * 64 + lane;       // +256 per kb
    #pragma unroll
    for (int nt = 0; nt < 4; ++nt) {
        f32x4 acc4 = {0.f, 0.f, 0.f, 0.f};
        const _Float16* sb = &Sx[(nt * 16 + pl) * 72 + g * 8];
        #pragma unroll
        for (int kb = 0; kb < 2; ++kb) {
            half8 af = wbase[kb * 256];
            half8 bf = *(const half8*)(sb + kb * 32);
            acc4 = __builtin_amdgcn_mfma_f32_16x16x32_f16(af, bf, acc4, 0, 0, 0);
        }
        int n = n0 + nt * 16 + pl;
        #pragma unroll
        for (int r = 0; r < 4; ++r) {
            int o = ob * 16 + g * 4 + r;
            float a = acc4[r] + b[o];
            float gv = 0.5f * a * (1.0f + erff(a * 0.70710678118654752f));
            U[(size_t)o * NSP + n] = gv;
        }
    }
}

// ---------------------------------------------------------------------------
// K2: depthwise 5x5x5, pad 2.  Weights uniform->SGPR; values dbuf LDS;
// staging via float4 loads (4x fewer VMEM instrs); edge cols zeroed once.
__global__ __launch_bounds__(256) void k_dw5(const float* __restrict__ in,
        const float* __restrict__ w, const float* __restrict__ b,
        float* __restrict__ out) {
    __shared__ float Sb5[2][20 * 38];                // 6080 B
    int t = threadIdx.x;
    int bid = blockIdx.x;
    int blk = (bid & 7) * 128 + (bid >> 3);          // XCD-chunked
    int c  = blk >> 4;
    int hq = (blk >> 1) & 7;
    int wq = blk & 1;
    int d  = t & 31;
    int wbloc = t >> 5;                              // 0..7
    int wb = wq * 8 + wbloc;
    const float* wc = w + c * 125;                   // uniform -> scalar loads
    const float* src = in + (size_t)c * NSP;

    // constant-zero edge cols (di<0 or di>=32): zero once, both buffers
    for (int idx = t; idx < 160; idx += 256) {
        int bi = idx / 80, r = idx % 80;
        int wi = r >> 2, e = r & 3;
        int Dp = (e < 2) ? e : 32 + e;               // {0,1,34,35}
        Sb5[bi][wi * 38 + Dp] = 0.f;
    }

    float bc = b[c];
    float acc[4][2];
    #pragma unroll
    for (int a = 0; a < 4; ++a) { acc[a][0] = bc; acc[a][1] = bc; }

    // stage row m (interior di 0..31 as float4; invalid wj -> zeros)
    #define STAGE5(m)                                                        \
        { int hh_ = 4 * hq + (m) - 2;                                        \
          if ((unsigned)hh_ < 32u) {                                         \
            const float* row_ = src + (hh_ << 10);                           \
            for (int idx = t; idx < 160; idx += 256) {                       \
                int wi = idx >> 3, q = idx & 7;                              \
                int wj = 16 * wq - 2 + wi;                                   \
                float4 vv = make_float4(0.f, 0.f, 0.f, 0.f);                 \
                if ((unsigned)wj < 32u)                                      \
                    vv = *(const float4*)&row_[(wj << 5) + q * 4];           \
                float* dst = &Sb5[(m) & 1][wi * 38 + 2 + q * 4];             \
                dst[0] = vv.x; dst[1] = vv.y; dst[2] = vv.z; dst[3] = vv.w;  \
            } } }

    STAGE5(0)
    __syncthreads();
    #pragma unroll 1
    for (int m = 0; m < 8; ++m) {
        if (m < 7) STAGE5(m + 1)
        int hh = 4 * hq + m - 2;
        if ((unsigned)hh < 32u) {
            float v[6][5];
            const float* sb = &Sb5[m & 1][0];
            #pragma unroll
            for (int jc = 0; jc < 6; ++jc)
                #pragma unroll
                for (int l = 0; l < 5; ++l)
                    v[jc][l] = sb[(2 * wbloc + jc) * 38 + d + l];
            #pragma unroll
            for (int a = 0; a < 4; ++a) {
                if (a <= m && m <= a + 4) {
                    const float* wr = wc + (m - a) * 25;   // uniform
                    float s0 = 0.f, s1 = 0.f;
                    #pragma unroll
                    for (int j = 0; j < 5; ++j)
                        #pragma unroll
                        for (int l = 0; l < 5; ++l) {
                            float wv2 = wr[j * 5 + l];
                            s0 += wv2 * v[j][l];
                            s1 += wv2 * v[j + 1][l];
                        }
                    acc[a][0] += s0;
                    acc[a][1] += s1;
                }
            }
        }
        __syncthreads();
    }
    #pragma unroll
    for (int a = 0; a < 4; ++a)
        #pragma unroll
        for (int bb = 0; bb < 2; ++bb)
            out[(size_t)c * NSP + ((4 * hq + a) << 10) + ((2 * wb + bb) << 5) + d]
                = acc[a][bb];
    #undef STAGE5
}

// ---------------------------------------------------------------------------
// K3: depthwise 7x7x7 dilation 3.  float4 staging; paired-FMA (pk) inner.
__global__ __launch_bounds__(256) void k_dw7(const float* __restrict__ in,
        const float* __restrict__ w, const float* __restrict__ b,
        float* __restrict__ out) {
    __shared__ float Sb7[2][26 * 52];                // 10816 B
    int t = threadIdx.x;
    int bid = blockIdx.x;
    int blk = (bid & 7) * 96 + (bid >> 3);           // XCD-chunked
    int c  = blk / 12;
    int h0 = (blk % 12) >> 2;
    int wq = blk & 3;
    int d  = t & 31;
    int wloc = t >> 5;                               // 0..7
    int w_ = wq * 8 + wloc;
    const float* wc = w + c * 343;                   // uniform -> scalar loads
    const float* src = in + (size_t)c * NSP;

    // constant-zero edge cols (di<0 or di>=32): zero once, both buffers
    for (int idx = t; idx < 936; idx += 256) {
        int bi = idx / 468, r = idx % 468;
        int wi = r / 18, e = r % 18;
        int Dp = (e < 9) ? e : 32 + e;               // {0..8, 41..49}
        Sb7[bi][wi * 52 + Dp] = 0.f;
    }

    float bc = b[c];
    float acc[11];
    #pragma unroll
    for (int a = 0; a < 11; ++a) acc[a] = bc;

    // stage row m (interior di 0..31 as float4)
    #define STAGE7(m)                                                        \
        { int hh_ = h0 + 3 * (m) - 9;                                        \
          if ((unsigned)hh_ < 32u) {                                         \
            const float* row_ = src + (hh_ << 10);                           \
            for (int idx = t; idx < 208; idx += 256) {                       \
                int wi = idx >> 3, q = idx & 7;                              \
                int wj = 8 * wq - 9 + wi;                                    \
                float4 vv = make_float4(0.f, 0.f, 0.f, 0.f);                 \
                if ((unsigned)wj < 32u)                                      \
                    vv = *(const float4*)&row_[(wj << 5) + q * 4];           \
                float* dst = &Sb7[(m) & 1][wi * 52 + 9 + q * 4];             \
                dst[0] = vv.x; dst[1] = vv.y; dst[2] = vv.z; dst[3] = vv.w;  \
            } } }

    STAGE7(0)
    __syncthreads();
    #pragma unroll 1
    for (int m = 0; m < 17; ++m) {
        if (m < 16) STAGE7(m + 1)
        int hh = h0 + 3 * m - 9;
        if ((unsigned)hh < 32u) {
            float vf[49];
            const float* sb = &Sb7[m & 1][0];
            #pragma unroll
            for (int jw = 0; jw < 7; ++jw)
                #pragma unroll
                for (int l = 0; l < 7; ++l)
                    vf[jw * 7 + l] = sb[(wloc + 3 * jw) * 52 + d + 3 * l];
            #pragma unroll
            for (int a = 0; a < 11; ++a) {
                if (a <= m && m <= a + 6) {
                    const float* wr = wc + (m - a) * 49;   // uniform
                    float sA = 0.f, sB = 0.f;              // 2 indep chains -> pk
                    #pragma unroll
                    for (int q = 0; q < 24; ++q) {
                        sA = fmaf(wr[2 * q],     vf[2 * q],     sA);
                        sB = fmaf(wr[2 * q + 1], vf[2 * q + 1], sB);
                    }
                    acc[a] += sA + sB + wr[48] * vf[48];
                }
            }
        }
        __syncthreads();
    }
    #pragma unroll
    for (int a = 0; a < 11; ++a) {
        int h = h0 + 3 * a;
        if (h < 32)
            out[(size_t)c * NSP + (h << 10) + (w_ << 5) + d] = acc[a];
    }
    #undef STAGE7
}

// ---------------------------------------------------------------------------
// K4: transpose [C][N] -> f16 [N][C]
__global__ __launch_bounds__(256) void k_tr(const float* __restrict__ in,
        _Float16* __restrict__ outh) {
    __shared__ float tile[64 * 65];
    int t = threadIdx.x;
    int n0 = blockIdx.x * 64;
    for (int i = 0; i < 16; ++i) {
        int idx = i * 256 + t;
        int c = idx >> 6, nl = idx & 63;
        tile[c * 65 + nl] = in[(size_t)c * NSP + n0 + nl];
    }
    __syncthreads();
    for (int i = 0; i < 16; ++i) {
        int idx = i * 256 + t;
        int nl = idx >> 6, c = idx & 63;
        outh[(size_t)(n0 + nl) * 64 + c] = (_Float16)tile[c * 65 + nl];
    }
}

// ---------------------------------------------------------------------------
// K5a: pre-pack deform weights into f16 MFMA A-fragment order.
__global__ __launch_bounds__(256) void k_wpack(const float* __restrict__ dw,
        _Float16* __restrict__ Wp) {
    int idx = blockIdx.x * 256 + threadIdx.x;   // 0 .. 110591
    int j = idx & 7;
    int l = (idx >> 3) & 63;
    int obk = idx >> 9;
    int ob = obk & 3, kb = obk >> 2;
    int o = ob * 16 + (l & 15);
    int Kp = kb * 32 + (l >> 4) * 8 + j;
    int k = Kp >> 6, c = Kp & 63;
    Wp[idx] = (_Float16)dw[(size_t)o * 1728 + c * 27 + k];
}

// ---------------------------------------------------------------------------
// K5b: pre-pack offset-conv weights, 6 o-blocks of 16 (rows 81..95 = 0).
__global__ __launch_bounds__(256) void k_wpack_off(const float* __restrict__ ow,
        _Float16* __restrict__ Wp2) {
    int idx = blockIdx.x * 256 + threadIdx.x;   // 0 .. 165887
    int j = idx & 7;
    int l = (idx >> 3) & 63;
    int obk = idx >> 9;                          // 0 .. 323
    int ob = obk % 6, kb = obk / 6;
    int o = ob * 16 + (l & 15);
    int Kp = kb * 32 + (l >> 4) * 8 + j;
    int k = Kp >> 6, c = Kp & 63;
    Wp2[idx] = (o < 81) ? (_Float16)ow[(size_t)o * 1728 + c * 27 + k]
                        : (_Float16)0.f;
}

// ---------------------------------------------------------------------------
// K5d: pack a 64x64 f32 weight matrix into A-frag order (4 ob x 2 kb).
__global__ __launch_bounds__(256) void k_wpack64(const float* __restrict__ w,
        _Float16* __restrict__ Wp) {
    int idx = blockIdx.x * 256 + threadIdx.x;   // 0 .. 4095
    int j = idx & 7;
    int l = (idx >> 3) & 63;
    int obk = idx >> 9;                          // 0..7
    int ob = obk & 3, kb = obk >> 2;
    int o = ob * 16 + (l & 15);
    int Kp = kb * 32 + (l >> 4) * 8 + j;
    Wp[idx] = (_Float16)w[o * 64 + Kp];
}

// ---------------------------------------------------------------------------
// K5c: offset conv, 64-position tile, kh-chunked dbuf halo; half8 staging
// (one dwordx4 wave-load = 8 dd x 64 ch; 8x fewer staging instructions).
__global__ __launch_bounds__(384) void k_offg(const _Float16* __restrict__ aTh,
        const half8* __restrict__ Wp2, const float* __restrict__ obias,
        float* __restrict__ off) {
    __shared__ __align__(16) _Float16 S2[2][4 * 34 * 72];   // 39168 B
    int t = threadIdx.x;
    int bid = blockIdx.x;
    int blk = (bid & 7) * 64 + (bid >> 3);   // 512 blocks, h-slabs per XCD
    int h = blk >> 4, w0 = (blk & 15) * 2;
    int n0 = (h << 10) + (w0 << 5);
    int lane = t & 63, wv = t >> 6;          // wv 0..5
    int co8 = (lane & 7) << 3;

    // constant-zero edge dd rows (dd 0 and 33): once, both buffers
    for (int u = t; u < 1152; u += 384) {
        int bi = u / 576, r2 = u % 576;
        int nbw = r2 / 144, r3 = r2 % 144;
        int dd = (r3 >= 72) ? 33 : 0, cc = r3 % 72;
        S2[bi][(nbw * 34 + dd) * 72 + cc] = (_Float16)0.f;
    }

    int pl = lane & 15, g = lane >> 4;
    int obi = wv;
    f32x4 acc[4];
    #pragma unroll
    for (int i = 0; i < 4; ++i) acc[i] = (f32x4){0.f, 0.f, 0.f, 0.f};
    const half8* wb = Wp2 + obi * 64 + lane;

    // stage chunk kh (h-row = h+kh-1): 4 w-nbrs x 4 d-octets, half8/lane
    #define OSTAGE(kh)                                                        \
        { int hh_ = h + (kh) - 1;                                            \
          bool okh_ = (unsigned)hh_ < 32u;                                   \
          for (int u = wv; u < 16; u += 6) {                                 \
              int nbw = u >> 2, oct = u & 3;                                 \
              int wj = w0 + nbw - 1;                                         \
              int di = oct * 8 + (lane >> 3);                                \
              bool ok = okh_ & ((unsigned)wj < 32u);                         \
              half8 vv = (half8)(_Float16)0.f;                               \
              if (ok) vv = *(const half8*)(aTh +                             \
                  ((size_t)((((hh_ << 5) + wj) << 5) + di)) * 64 + co8);     \
              *(half8*)&S2[(kh) & 1][(nbw * 34 + 1 + di) * 72 + co8] = vv;   \
          } }

    // MFMA chunk kh: 18 kbs (taps kh*9 .. kh*9+8)
    #define OCOMP(kh)                                                        \
        { const _Float16* sb = &S2[(kh) & 1][pl * 72 + g * 8];               \
          _Pragma("unroll")                                                  \
          for (int kk = 0; kk < 18; ++kk) {                                  \
              int kglob = (kh) * 9 + (kk >> 1);                              \
              int kw3 = (kglob / 3) % 3, kd = kglob % 3;                     \
              half8 af = wb[(size_t)((kh) * 18 + kk) * 384];                 \
              _Pragma("unroll")                                              \
              for (int pt = 0; pt < 4; ++pt) {                               \
                  int row = ((pt >> 1) + kw3) * 34 + (pt & 1) * 16 + kd;     \
                  half8 bf = *(const half8*)(sb + row * 72 + (kk & 1) * 32); \
                  acc[pt] = __builtin_amdgcn_mfma_f32_16x16x32_f16(          \
                                af, bf, acc[pt], 0, 0, 0);                   \
              }                                                              \
          } }

    OSTAGE(0)
    __syncthreads();
    OSTAGE(1)
    OCOMP(0)
    __syncthreads();
    OSTAGE(2)
    OCOMP(1)
    __syncthreads();
    OCOMP(2)
    #undef OSTAGE
    #undef OCOMP

    #pragma unroll
    for (int pt = 0; pt < 4; ++pt) {
        #pragma unroll
        for (int r = 0; r < 4; ++r) {
            int o = obi * 16 + g * 4 + r;
            if (o < 81)
                off[(size_t)o * NSP + n0 + pt * 16 + pl] = acc[pt][r] + obias[o];
        }
    }
}

// ---------------------------------------------------------------------------
// K6: deformable gather + MFMA GEMM, 32-position blocks, 4 K-chunks.
// One af load feeds BOTH p-tiles (af traffic per position halved).  TP holds
// packed base+mask (4B) + 3 f16 fracs (8B); trilinear wg recomputed in f16.
__global__ __launch_bounds__(256) void k_deform(const _Float16* __restrict__ aTh,
        const float* __restrict__ off, const half8* __restrict__ Wp,
        const float* __restrict__ db, float* __restrict__ dcn) {
    __shared__ __align__(16) _Float16 S[32 * 456];     // 29184 B (7 taps max)
    __shared__ __align__(16) _Float16 TPF[864 * 4];    // 6912 B {rh,rw,rd,_}
    __shared__ int TPv[864];                           // 3456 B (total 39552)
    int t = threadIdx.x;
    int bid = blockIdx.x;
    int blk = (bid & 7) * 128 + (bid >> 3);  // 1024 blocks, n-slabs per XCD
    int n0 = blk * 32;
    int lane = t & 63, wv = t >> 6;

    for (int idx = t; idx < 864; idx += 256) {        // Phase A: 27k x 32p
        int p = idx & 31, k = idx >> 5;
        int n = n0 + p;
        int h = n >> 10, w = (n >> 5) & 31, d = n & 31;
        float ph = (float)(h + k / 9 - 1)       + off[(size_t)(k * 3 + 0) * NSP + n];
        float pw = (float)(w + (k / 3) % 3 - 1) + off[(size_t)(k * 3 + 1) * NSP + n];
        float pd = (float)(d + k % 3 - 1)       + off[(size_t)(k * 3 + 2) * NSP + n];
        float fh = floorf(ph), fw = floorf(pw), fd = floorf(pd);
        int ih = (int)fh, iw = (int)fw, id = (int)fd;
        int nb0 = ih * 1024 + iw * 32 + id;
        int mask = 0;
        #pragma unroll
        for (int cb = 0; cb < 8; ++cb) {
            int hh = ih + ((cb >> 2) & 1);
            int wq = iw + ((cb >> 1) & 1);
            int dq = id + (cb & 1);
            bool ok = ((unsigned)hh < 32u) & ((unsigned)wq < 32u) & ((unsigned)dq < 32u);
            mask |= (ok ? 1 : 0) << cb;
        }
        TPv[idx] = ((nb0 + 4096) << 8) | mask;
        half4 f;
        f[0] = (_Float16)(ph - fh);
        f[1] = (_Float16)(pw - fw);
        f[2] = (_Float16)(pd - fd);
        f[3] = (_Float16)0.f;
        *(half4*)&TPF[idx * 4] = f;
    }
    __syncthreads();

    int p8 = lane >> 3, co = lane & 7;
    int pl = lane & 15, g = lane >> 4;
    f32x4 acc[2];
    acc[0] = (f32x4){0.f, 0.f, 0.f, 0.f};
    acc[1] = (f32x4){0.f, 0.f, 0.f, 0.f};
    const half8* wbase = Wp + wv * 64 + lane;
    const _Float16* sbase0 = &S[pl * 456 + g * 8];
    const _Float16* sbase1 = &S[(16 + pl) * 456 + g * 8];

    // chunk: gather taps [T0, T0+NT) -> S, then NT*2 kbs x 2 p-tile MFMAs
    #define DCHUNK(T0, NT)                                                   \
        for (int u = wv; u < (NT) * 4; u += 4) {                             \
            int kk = u >> 2, pg = u & 3;                                     \
            int p = pg * 8 + p8;                                             \
            int tap = ((T0) + kk) * 32 + p;                                  \
            int v = TPv[tap];                                                \
            int nb = (v >> 8) - 4096, mask = v & 255;                        \
            half4 f = *(const half4*)&TPF[tap * 4];                          \
            _Float16 one = (_Float16)1.f;                                    \
            _Float16 rh = f[0], rw = f[1], rd = f[2];                        \
            _Float16 h0 = one - rh, w0 = one - rw, d0 = one - rd;            \
            _Float16 t00 = h0 * w0, t01 = h0 * rw;                           \
            _Float16 t10 = rh * w0, t11 = rh * rw;                           \
            half2v a0 = (half2v)0, a1 = (half2v)0, a2 = (half2v)0,           \
                   a3 = (half2v)0;                                           \
            _Pragma("unroll")                                                \
            for (int i = 0; i < 8; ++i) {                                    \
                int nn = nb + ((i >> 2) & 1) * 1024 + ((i >> 1) & 1) * 32    \
                       + (i & 1);                                            \
                bool okc = (mask >> i) & 1;                                  \
                size_t ad = okc ? ((size_t)nn << 6) : 0;                     \
                half8 vv = *(const half8*)(aTh + ad + (co << 3));            \
                _Float16 txy = (i & 4) ? ((i & 2) ? t11 : t10)               \
                                       : ((i & 2) ? t01 : t00);              \
                _Float16 wg = txy * ((i & 1) ? rd : d0);                     \
                wg = okc ? wg : (_Float16)0.f;                               \
                half2v wg2 = {wg, wg};                                       \
                a0 += (half2v){vv[0], vv[1]} * wg2;                          \
                a1 += (half2v){vv[2], vv[3]} * wg2;                          \
                a2 += (half2v){vv[4], vv[5]} * wg2;                          \
                a3 += (half2v){vv[6], vv[7]} * wg2;                          \
            }                                                                \
            half8 r;                                                         \
            r[0] = a0[0]; r[1] = a0[1]; r[2] = a1[0]; r[3] = a1[1];          \
            r[4] = a2[0]; r[5] = a2[1]; r[6] = a3[0]; r[7] = a3[1];          \
            *(half8*)&S[p * 456 + kk * 64 + (co << 3)] = r;                  \
        }                                                                    \
        __syncthreads();                                                     \
        _Pragma("unroll")                                                    \
        for (int kb = 0; kb < (NT) * 2; ++kb) {                              \
            half8 af = wbase[(size_t)(2 * (T0) + kb) * 256];                 \
            half8 bf0 = *(const half8*)(sbase0 + kb * 32);                   \
            half8 bf1 = *(const half8*)(sbase1 + kb * 32);                   \
            acc[0] = __builtin_amdgcn_mfma_f32_16x16x32_f16(af, bf0,         \
                         acc[0], 0, 0, 0);                                   \
            acc[1] = __builtin_amdgcn_mfma_f32_16x16x32_f16(af, bf1,         \
                         acc[1], 0, 0, 0);                                   \
        }                                                                    \
        __syncthreads();

    DCHUNK(0, 7)
    DCHUNK(7, 7)
    DCHUNK(14, 7)
    DCHUNK(21, 6)
    #undef DCHUNK

    #pragma unroll
    for (int pt = 0; pt < 2; ++pt) {
        #pragma unroll
        for (int r2 = 0; r2 < 4; ++r2) {
            int o = wv * 16 + g * 4 + r2;
            dcn[(size_t)o * NSP + n0 + pt * 16 + pl] = acc[pt][r2] + db[o];
        }
    }
}

// ---------------------------------------------------------------------------
// K7 (MFMA): a2 = conv1_w @ dcn + b ; h = U * a2 ; out = proj2_w @ h + b2 + x
__global__ __launch_bounds__(256) void k_finalm(const float* __restrict__ dcn,
        const float* __restrict__ U, const float* __restrict__ x,
        const half8* __restrict__ Wc1, const float* __restrict__ c1b,
        const half8* __restrict__ Wp2f, const float* __restrict__ p2b,
        float* __restrict__ out) {
    __shared__ __align__(16) _Float16 Sd[64 * 72];   // 9216 B
    __shared__ __align__(16) _Float16 Sh[64 * 72];   // 9216 B
    int t = threadIdx.x;
    int n0 = blockIdx.x * 64;
    int lane = t & 63, wv = t >> 6;
    for (int i = wv; i < 64; i += 4) {
        float v = dcn[(size_t)i * NSP + n0 + lane];
        Sd[lane * 72 + i] = (_Float16)v;
    }
    __syncthreads();

    int pl = lane & 15, g = lane >> 4;
    int ob = wv;
    const half8* w1 = Wc1 + ob * 64 + lane;
    #pragma unroll
    for (int nt = 0; nt < 4; ++nt) {                 // GEMM1 + gate
        f32x4 acc4 = {0.f, 0.f, 0.f, 0.f};
        const _Float16* sb = &Sd[(nt * 16 + pl) * 72 + g * 8];
        #pragma unroll
        for (int kb = 0; kb < 2; ++kb) {
            half8 af = w1[kb * 256];
            half8 bf = *(const half8*)(sb + kb * 32);
            acc4 = __builtin_amdgcn_mfma_f32_16x16x32_f16(af, bf, acc4, 0, 0, 0);
        }
        int n = n0 + nt * 16 + pl;
        int o0 = ob * 16 + g * 4;
        float4 bb = *(const float4*)&c1b[o0];
        half4 hv;
        hv[0] = (_Float16)(U[(size_t)(o0 + 0) * NSP + n] * (acc4[0] + bb.x));
        hv[1] = (_Float16)(U[(size_t)(o0 + 1) * NSP + n] * (acc4[1] + bb.y));
        hv[2] = (_Float16)(U[(size_t)(o0 + 2) * NSP + n] * (acc4[2] + bb.z));
        hv[3] = (_Float16)(U[(size_t)(o0 + 3) * NSP + n] * (acc4[3] + bb.w));
        *(half4*)&Sh[(nt * 16 + pl) * 72 + o0] = hv;
    }
    __syncthreads();

    const half8* w2 = Wp2f + ob * 64 + lane;
    #pragma unroll
    for (int nt = 0; nt < 4; ++nt) {                 // GEMM2 + residual
        f32x4 acc4 = {0.f, 0.f, 0.f, 0.f};
        const _Float16* sb = &Sh[(nt * 16 + pl) * 72 + g * 8];
        #pragma unroll
        for (int kb = 0; kb < 2; ++kb) {
            half8 af = w2[kb * 256];
            half8 bf = *(const half8*)(sb + kb * 32);
            acc4 = __builtin_amdgcn_mfma_f32_16x16x32_f16(af, bf, acc4, 0, 0, 0);
        }
        int n = n0 + nt * 16 + pl;
        int o0 = ob * 16 + g * 4;
        float4 bb = *(const float4*)&p2b[o0];
        float4 xr = *(const float4*)&x[(size_t)n * 64 + o0];
        float4 ov;
        ov.x = acc4[0] + bb.x + xr.x;
        ov.y = acc4[1] + bb.y + xr.y;
        ov.z = acc4[2] + bb.z + xr.z;
        ov.w = acc4[3] + bb.w + xr.w;
        *(float4*)&out[(size_t)n * 64 + o0] = ov;
    }
}

// ---------------------------------------------------------------------------
extern "C" void kernel_launch(void* const* d_in, const int* in_sizes, int n_in,
                              void* d_out, int out_size, void* d_ws, size_t ws_size,
                              hipStream_t stream) {
    const float* x   = (const float*)d_in[0];
    const float* p1w = (const float*)d_in[1];
    const float* p1b = (const float*)d_in[2];
    const float* c0w = (const float*)d_in[3];
    const float* c0b = (const float*)d_in[4];
    const float* csw = (const float*)d_in[5];
    const float* csb = (const float*)d_in[6];
    const float* ofw = (const float*)d_in[7];
    const float* ofb = (const float*)d_in[8];
    const float* dcw = (const float*)d_in[9];
    const float* dcb = (const float*)d_in[10];
    const float* c1w = (const float*)d_in[11];
    const float* c1b = (const float*)d_in[12];
    const float* p2w = (const float*)d_in[13];
    const float* p2b = (const float*)d_in[14];
    float* out = (float*)d_out;

    char* ws = (char*)d_ws;
    const size_t CN4 = (size_t)NCH * NSP * 4;       // 8 MiB per [C][N] f32
    float* U    = (float*)(ws);
    float* T0   = (float*)(ws + CN4);
    float* T1   = (float*)(ws + 2 * CN4);
    float* OFFp = (float*)(ws + 4 * CN4);           // 81*N f32
    float* DCN  = (float*)(ws + 4 * CN4 + (size_t)81 * NSP * 4);
    _Float16* Wp   = (_Float16*)(ws + 5 * CN4 + (size_t)81 * NSP * 4);
    _Float16* Wp2  = Wp + 110592;
    _Float16* Wp1  = Wp2 + 165888;
    _Float16* Wc1  = Wp1 + 4096;
    _Float16* Wp2f = Wc1 + 4096;
    _Float16* aTh  = (_Float16*)T0;                 // reuses T0 (dead after dw7)

    k_wpack64  <<<16, 256, 0, stream>>>(p1w, Wp1);
    k_wpack64  <<<16, 256, 0, stream>>>(c1w, Wc1);
    k_wpack64  <<<16, 256, 0, stream>>>(p2w, Wp2f);
    k_wpack    <<<432, 256, 0, stream>>>(dcw, Wp);
    k_wpack_off<<<648, 256, 0, stream>>>(ofw, Wp2);
    k_proj1m   <<<NSP / 64, 256, 0, stream>>>(x, (const half8*)Wp1, p1b, U);
    k_dw5      <<<1024, 256, 0, stream>>>(U, c0w, c0b, T0);
    k_dw7      <<<768, 256, 0, stream>>>(T0, csw, csb, T1);
    k_tr       <<<NSP / 64, 256, 0, stream>>>(T1, aTh);
    k_offg     <<<512, 384, 0, stream>>>(aTh, (const half8*)Wp2, ofb, OFFp);
    k_deform   <<<1024, 256, 0, stream>>>(aTh, OFFp, (const half8*)Wp, dcb, DCN);
    k_finalm   <<<NSP / 64, 256, 0, stream>>>(DCN, U, x, (const half8*)Wc1, c1b,
                                              (const half8*)Wp2f, p2b, out);
}

// Round 13
// 125.454 us; speedup vs baseline: 21.9438x; 1.0468x over previous
//
#include <hip/hip_runtime.h>
#include <math.h>

#define NSP 32768   // H*W*D = 32*32*32
#define NCH 64

typedef _Float16 half8 __attribute__((ext_vector_type(8)));
typedef _Float16 half4 __attribute__((ext_vector_type(4)));
typedef _Float16 half2v __attribute__((ext_vector_type(2)));
typedef float f32x4 __attribute__((ext_vector_type(4)));

// ---------------------------------------------------------------------------
// K1 (MFMA): U = gelu(proj1_w @ x^T + b)   (U layout: f16 [C][N])
__global__ __launch_bounds__(256) void k_proj1m(const float* __restrict__ x,
        const half8* __restrict__ Wp1, const float* __restrict__ b,
        _Float16* __restrict__ Uh) {
    __shared__ __align__(16) _Float16 Sx[64 * 72];   // 9216 B
    int t = threadIdx.x;
    int n0 = blockIdx.x * 64;
    int lane = t & 63, wv = t >> 6;
    for (int i = wv; i < 64; i += 4) {
        float v = x[(size_t)(n0 + i) * 64 + lane];
        Sx[i * 72 + lane] = (_Float16)v;
    }
    __syncthreads();
    int pl = lane & 15, g = lane >> 4;
    int ob = wv;
    const half8* wbase = Wp1 + ob * 64 + lane;       // +256 per kb
    #pragma unroll
    for (int nt = 0; nt < 4; ++nt) {
        f32x4 acc4 = {0.f, 0.f, 0.f, 0.f};
        const _Float16* sb = &Sx[(nt * 16 + pl) * 72 + g * 8];
        #pragma unroll
        for (int kb = 0; kb < 2; ++kb) {
            half8 af = wbase[kb * 256];
            half8 bf = *(const half8*)(sb + kb * 32);
            acc4 = __builtin_amdgcn_mfma_f32_16x16x32_f16(af, bf, acc4, 0, 0, 0);
        }
        int n = n0 + nt * 16 + pl;
        #pragma unroll
        for (int r = 0; r < 4; ++r) {
            int o = ob * 16 + g * 4 + r;
            float a = acc4[r] + b[o];
            float gv = 0.5f * a * (1.0f + erff(a * 0.70710678118654752f));
            Uh[(size_t)o * NSP + n] = (_Float16)gv;
        }
    }
}

// ---------------------------------------------------------------------------
// K2: depthwise 5x5x5, pad 2.  f16 in/out; weights uniform->SGPR; values
// staged to f32 LDS via half8 loads (8 elems / 16B instr).
__global__ __launch_bounds__(256) void k_dw5(const _Float16* __restrict__ in,
        const float* __restrict__ w, const float* __restrict__ b,
        _Float16* __restrict__ out) {
    __shared__ float Sb5[2][20 * 38];                // 6080 B
    int t = threadIdx.x;
    int bid = blockIdx.x;
    int blk = (bid & 7) * 128 + (bid >> 3);          // XCD-chunked
    int c  = blk >> 4;
    int hq = (blk >> 1) & 7;
    int wq = blk & 1;
    int d  = t & 31;
    int wbloc = t >> 5;                              // 0..7
    int wb = wq * 8 + wbloc;
    const float* wc = w + c * 125;                   // uniform -> scalar loads
    const _Float16* src = in + ((size_t)c << 15);

    // constant-zero edge cols (di<0 or di>=32): zero once, both buffers
    for (int idx = t; idx < 160; idx += 256) {
        int bi = idx / 80, r = idx % 80;
        int wi = r >> 2, e = r & 3;
        int Dp = (e < 2) ? e : 32 + e;               // {0,1,34,35}
        Sb5[bi][wi * 38 + Dp] = 0.f;
    }

    float bc = b[c];
    float acc[4][2];
    #pragma unroll
    for (int a = 0; a < 4; ++a) { acc[a][0] = bc; acc[a][1] = bc; }

    // stage row m: 20 wi x 4 octets, half8 per unit
    #define STAGE5(m)                                                        \
        { int hh_ = 4 * hq + (m) - 2;                                        \
          if ((unsigned)hh_ < 32u) {                                         \
            const _Float16* row_ = src + (hh_ << 10);                        \
            for (int idx = t; idx < 80; idx += 256) {                        \
                int wi = idx >> 2, oct = idx & 3;                            \
                int wj = 16 * wq - 2 + wi;                                   \
                half8 vv = (half8)(_Float16)0.f;                             \
                if ((unsigned)wj < 32u)                                      \
                    vv = *(const half8*)&row_[(wj << 5) + oct * 8];          \
                float* dst = &Sb5[(m) & 1][wi * 38 + 2 + oct * 8];           \
                dst[0] = (float)vv[0]; dst[1] = (float)vv[1];                \
                dst[2] = (float)vv[2]; dst[3] = (float)vv[3];                \
                dst[4] = (float)vv[4]; dst[5] = (float)vv[5];                \
                dst[6] = (float)vv[6]; dst[7] = (float)vv[7];                \
            } } }

    STAGE5(0)
    __syncthreads();
    #pragma unroll 1
    for (int m = 0; m < 8; ++m) {
        if (m < 7) STAGE5(m + 1)
        int hh = 4 * hq + m - 2;
        if ((unsigned)hh < 32u) {
            float v[6][5];
            const float* sb = &Sb5[m & 1][0];
            #pragma unroll
            for (int jc = 0; jc < 6; ++jc)
                #pragma unroll
                for (int l = 0; l < 5; ++l)
                    v[jc][l] = sb[(2 * wbloc + jc) * 38 + d + l];
            #pragma unroll
            for (int a = 0; a < 4; ++a) {
                if (a <= m && m <= a + 4) {
                    const float* wr = wc + (m - a) * 25;   // uniform
                    float s0 = 0.f, s1 = 0.f;
                    #pragma unroll
                    for (int j = 0; j < 5; ++j)
                        #pragma unroll
                        for (int l = 0; l < 5; ++l) {
                            float wv2 = wr[j * 5 + l];
                            s0 += wv2 * v[j][l];
                            s1 += wv2 * v[j + 1][l];
                        }
                    acc[a][0] += s0;
                    acc[a][1] += s1;
                }
            }
        }
        __syncthreads();
    }
    #pragma unroll
    for (int a = 0; a < 4; ++a)
        #pragma unroll
        for (int bb = 0; bb < 2; ++bb)
            out[(size_t)c * NSP + ((4 * hq + a) << 10) + ((2 * wb + bb) << 5) + d]
                = (_Float16)acc[a][bb];
    #undef STAGE5
}

// ---------------------------------------------------------------------------
// K3: depthwise 7x7x7 dilation 3.  f16 in/out; half8 staging; pk inner.
__global__ __launch_bounds__(256) void k_dw7(const _Float16* __restrict__ in,
        const float* __restrict__ w, const float* __restrict__ b,
        _Float16* __restrict__ out) {
    __shared__ float Sb7[2][26 * 52];                // 10816 B
    int t = threadIdx.x;
    int bid = blockIdx.x;
    int blk = (bid & 7) * 96 + (bid >> 3);           // XCD-chunked
    int c  = blk / 12;
    int h0 = (blk % 12) >> 2;
    int wq = blk & 3;
    int d  = t & 31;
    int wloc = t >> 5;                               // 0..7
    int w_ = wq * 8 + wloc;
    const float* wc = w + c * 343;                   // uniform -> scalar loads
    const _Float16* src = in + ((size_t)c << 15);

    // constant-zero edge cols: once, both buffers
    for (int idx = t; idx < 936; idx += 256) {
        int bi = idx / 468, r = idx % 468;
        int wi = r / 18, e = r % 18;
        int Dp = (e < 9) ? e : 32 + e;               // {0..8, 41..49}
        Sb7[bi][wi * 52 + Dp] = 0.f;
    }

    float bc = b[c];
    float acc[11];
    #pragma unroll
    for (int a = 0; a < 11; ++a) acc[a] = bc;

    // stage row m: 26 wi x 4 octets, half8 per unit
    #define STAGE7(m)                                                        \
        { int hh_ = h0 + 3 * (m) - 9;                                        \
          if ((unsigned)hh_ < 32u) {                                         \
            const _Float16* row_ = src + (hh_ << 10);                        \
            for (int idx = t; idx < 104; idx += 256) {                       \
                int wi = idx >> 2, oct = idx & 3;                            \
                int wj = 8 * wq - 9 + wi;                                    \
                half8 vv = (half8)(_Float16)0.f;                             \
                if ((unsigned)wj < 32u)                                      \
                    vv = *(const half8*)&row_[(wj << 5) + oct * 8];          \
                float* dst = &Sb7[(m) & 1][wi * 52 + 9 + oct * 8];           \
                dst[0] = (float)vv[0]; dst[1] = (float)vv[1];                \
                dst[2] = (float)vv[2]; dst[3] = (float)vv[3];                \
                dst[4] = (float)vv[4]; dst[5] = (float)vv[5];                \
                dst[6] = (float)vv[6]; dst[7] = (float)vv[7];                \
            } } }

    STAGE7(0)
    __syncthreads();
    #pragma unroll 1
    for (int m = 0; m < 17; ++m) {
        if (m < 16) STAGE7(m + 1)
        int hh = h0 + 3 * m - 9;
        if ((unsigned)hh < 32u) {
            float vf[49];
            const float* sb = &Sb7[m & 1][0];
            #pragma unroll
            for (int jw = 0; jw < 7; ++jw)
                #pragma unroll
                for (int l = 0; l < 7; ++l)
                    vf[jw * 7 + l] = sb[(wloc + 3 * jw) * 52 + d + 3 * l];
            #pragma unroll
            for (int a = 0; a < 11; ++a) {
                if (a <= m && m <= a + 6) {
                    const float* wr = wc + (m - a) * 49;   // uniform
                    float sA = 0.f, sB = 0.f;              // 2 chains -> pk
                    #pragma unroll
                    for (int q = 0; q < 24; ++q) {
                        sA = fmaf(wr[2 * q],     vf[2 * q],     sA);
                        sB = fmaf(wr[2 * q + 1], vf[2 * q + 1], sB);
                    }
                    acc[a] += sA + sB + wr[48] * vf[48];
                }
            }
        }
        __syncthreads();
    }
    #pragma unroll
    for (int a = 0; a < 11; ++a) {
        int h = h0 + 3 * a;
        if (h < 32)
            out[(size_t)c * NSP + (h << 10) + (w_ << 5) + d] = (_Float16)acc[a];
    }
    #undef STAGE7
}

// ---------------------------------------------------------------------------
// K4: transpose f16 [C][N] -> f16 [N][C], half8 both sides (stride-74 tile)
__global__ __launch_bounds__(256) void k_tr(const _Float16* __restrict__ in,
        _Float16* __restrict__ outh) {
    __shared__ __align__(16) _Float16 tile[64 * 74];  // 9472 B
    int t = threadIdx.x;
    int n0 = blockIdx.x * 64;
    #pragma unroll
    for (int i = 0; i < 2; ++i) {
        int u = i * 256 + t;         // 0..511
        int c = u >> 3, oct = u & 7;
        half8 v = *(const half8*)&in[(size_t)c * NSP + n0 + oct * 8];
        *(half8*)&tile[c * 74 + oct * 8] = v;
    }
    __syncthreads();
    #pragma unroll
    for (int i = 0; i < 2; ++i) {
        int u = i * 256 + t;
        int nl = u >> 3, co = u & 7;
        half8 r;
        #pragma unroll
        for (int j = 0; j < 8; ++j) r[j] = tile[(co * 8 + j) * 74 + nl];
        *(half8*)&outh[(size_t)(n0 + nl) * 64 + co * 8] = r;
    }
}

// ---------------------------------------------------------------------------
// K5a: pre-pack deform weights into f16 MFMA A-fragment order.
__global__ __launch_bounds__(256) void k_wpack(const float* __restrict__ dw,
        _Float16* __restrict__ Wp) {
    int idx = blockIdx.x * 256 + threadIdx.x;   // 0 .. 110591
    int j = idx & 7;
    int l = (idx >> 3) & 63;
    int obk = idx >> 9;
    int ob = obk & 3, kb = obk >> 2;
    int o = ob * 16 + (l & 15);
    int Kp = kb * 32 + (l >> 4) * 8 + j;
    int k = Kp >> 6, c = Kp & 63;
    Wp[idx] = (_Float16)dw[(size_t)o * 1728 + c * 27 + k];
}

// ---------------------------------------------------------------------------
// K5b: pre-pack offset-conv weights, 6 o-blocks of 16 (rows 81..95 = 0).
__global__ __launch_bounds__(256) void k_wpack_off(const float* __restrict__ ow,
        _Float16* __restrict__ Wp2) {
    int idx = blockIdx.x * 256 + threadIdx.x;   // 0 .. 165887
    int j = idx & 7;
    int l = (idx >> 3) & 63;
    int obk = idx >> 9;                          // 0 .. 323
    int ob = obk % 6, kb = obk / 6;
    int o = ob * 16 + (l & 15);
    int Kp = kb * 32 + (l >> 4) * 8 + j;
    int k = Kp >> 6, c = Kp & 63;
    Wp2[idx] = (o < 81) ? (_Float16)ow[(size_t)o * 1728 + c * 27 + k]
                        : (_Float16)0.f;
}

// ---------------------------------------------------------------------------
// K5d: pack a 64x64 f32 weight matrix into A-frag order (4 ob x 2 kb).
__global__ __launch_bounds__(256) void k_wpack64(const float* __restrict__ w,
        _Float16* __restrict__ Wp) {
    int idx = blockIdx.x * 256 + threadIdx.x;   // 0 .. 4095
    int j = idx & 7;
    int l = (idx >> 3) & 63;
    int obk = idx >> 9;                          // 0..7
    int ob = obk & 3, kb = obk >> 2;
    int o = ob * 16 + (l & 15);
    int Kp = kb * 32 + (l >> 4) * 8 + j;
    Wp[idx] = (_Float16)w[o * 64 + Kp];
}

// ---------------------------------------------------------------------------
// K5c: offset conv, 64-position tile, kh-chunked dbuf halo; half8 staging.
__global__ __launch_bounds__(384) void k_offg(const _Float16* __restrict__ aTh,
        const half8* __restrict__ Wp2, const float* __restrict__ obias,
        float* __restrict__ off) {
    __shared__ __align__(16) _Float16 S2[2][4 * 34 * 72];   // 39168 B
    int t = threadIdx.x;
    int bid = blockIdx.x;
    int blk = (bid & 7) * 64 + (bid >> 3);   // 512 blocks, h-slabs per XCD
    int h = blk >> 4, w0 = (blk & 15) * 2;
    int n0 = (h << 10) + (w0 << 5);
    int lane = t & 63, wv = t >> 6;          // wv 0..5
    int co8 = (lane & 7) << 3;

    // constant-zero edge dd rows (dd 0 and 33): once, both buffers
    for (int u = t; u < 1152; u += 384) {
        int bi = u / 576, r2 = u % 576;
        int nbw = r2 / 144, r3 = r2 % 144;
        int dd = (r3 >= 72) ? 33 : 0, cc = r3 % 72;
        S2[bi][(nbw * 34 + dd) * 72 + cc] = (_Float16)0.f;
    }

    int pl = lane & 15, g = lane >> 4;
    int obi = wv;
    f32x4 acc[4];
    #pragma unroll
    for (int i = 0; i < 4; ++i) acc[i] = (f32x4){0.f, 0.f, 0.f, 0.f};
    const half8* wb = Wp2 + obi * 64 + lane;

    #define OSTAGE(kh)                                                        \
        { int hh_ = h + (kh) - 1;                                            \
          bool okh_ = (unsigned)hh_ < 32u;                                   \
          for (int u = wv; u < 16; u += 6) {                                 \
              int nbw = u >> 2, oct = u & 3;                                 \
              int wj = w0 + nbw - 1;                                         \
              int di = oct * 8 + (lane >> 3);                                \
              bool ok = okh_ & ((unsigned)wj < 32u);                         \
              half8 vv = (half8)(_Float16)0.f;                               \
              if (ok) vv = *(const half8*)(aTh +                             \
                  ((size_t)((((hh_ << 5) + wj) << 5) + di)) * 64 + co8);     \
              *(half8*)&S2[(kh) & 1][(nbw * 34 + 1 + di) * 72 + co8] = vv;   \
          } }

    #define OCOMP(kh)                                                        \
        { const _Float16* sb = &S2[(kh) & 1][pl * 72 + g * 8];               \
          _Pragma("unroll")                                                  \
          for (int kk = 0; kk < 18; ++kk) {                                  \
              int kglob = (kh) * 9 + (kk >> 1);                              \
              int kw3 = (kglob / 3) % 3, kd = kglob % 3;                     \
              half8 af = wb[(size_t)((kh) * 18 + kk) * 384];                 \
              _Pragma("unroll")                                              \
              for (int pt = 0; pt < 4; ++pt) {                               \
                  int row = ((pt >> 1) + kw3) * 34 + (pt & 1) * 16 + kd;     \
                  half8 bf = *(const half8*)(sb + row * 72 + (kk & 1) * 32); \
                  acc[pt] = __builtin_amdgcn_mfma_f32_16x16x32_f16(          \
                                af, bf, acc[pt], 0, 0, 0);                   \
              }                                                              \
          } }

    OSTAGE(0)
    __syncthreads();
    OSTAGE(1)
    OCOMP(0)
    __syncthreads();
    OSTAGE(2)
    OCOMP(1)
    __syncthreads();
    OCOMP(2)
    #undef OSTAGE
    #undef OCOMP

    #pragma unroll
    for (int pt = 0; pt < 4; ++pt) {
        #pragma unroll
        for (int r = 0; r < 4; ++r) {
            int o = obi * 16 + g * 4 + r;
            if (o < 81)
                off[(size_t)o * NSP + n0 + pt * 16 + pl] = acc[pt][r] + obias[o];
        }
    }
}

// ---------------------------------------------------------------------------
// K6: deformable gather + MFMA GEMM, 32-position blocks, 4 K-chunks.
// Output dcnT f16 [N][C] (half4 stores; feeds k_finalm transpose-free).
__global__ __launch_bounds__(256) void k_deform(const _Float16* __restrict__ aTh,
        const float* __restrict__ off, const half8* __restrict__ Wp,
        const float* __restrict__ db, _Float16* __restrict__ dcnT) {
    __shared__ __align__(16) _Float16 S[32 * 456];     // 29184 B (7 taps max)
    __shared__ __align__(16) _Float16 TPF[864 * 4];    // 6912 B {rh,rw,rd,_}
    __shared__ int TPv[864];                           // 3456 B (total 39552)
    int t = threadIdx.x;
    int bid = blockIdx.x;
    int blk = (bid & 7) * 128 + (bid >> 3);  // 1024 blocks, n-slabs per XCD
    int n0 = blk * 32;
    int lane = t & 63, wv = t >> 6;

    for (int idx = t; idx < 864; idx += 256) {        // Phase A: 27k x 32p
        int p = idx & 31, k = idx >> 5;
        int n = n0 + p;
        int h = n >> 10, w = (n >> 5) & 31, d = n & 31;
        float ph = (float)(h + k / 9 - 1)       + off[(size_t)(k * 3 + 0) * NSP + n];
        float pw = (float)(w + (k / 3) % 3 - 1) + off[(size_t)(k * 3 + 1) * NSP + n];
        float pd = (float)(d + k % 3 - 1)       + off[(size_t)(k * 3 + 2) * NSP + n];
        float fh = floorf(ph), fw = floorf(pw), fd = floorf(pd);
        int ih = (int)fh, iw = (int)fw, id = (int)fd;
        int nb0 = ih * 1024 + iw * 32 + id;
        int mask = 0;
        #pragma unroll
        for (int cb = 0; cb < 8; ++cb) {
            int hh = ih + ((cb >> 2) & 1);
            int wq = iw + ((cb >> 1) & 1);
            int dq = id + (cb & 1);
            bool ok = ((unsigned)hh < 32u) & ((unsigned)wq < 32u) & ((unsigned)dq < 32u);
            mask |= (ok ? 1 : 0) << cb;
        }
        TPv[idx] = ((nb0 + 4096) << 8) | mask;
        half4 f;
        f[0] = (_Float16)(ph - fh);
        f[1] = (_Float16)(pw - fw);
        f[2] = (_Float16)(pd - fd);
        f[3] = (_Float16)0.f;
        *(half4*)&TPF[idx * 4] = f;
    }
    __syncthreads();

    int p8 = lane >> 3, co = lane & 7;
    int pl = lane & 15, g = lane >> 4;
    f32x4 acc[2];
    acc[0] = (f32x4){0.f, 0.f, 0.f, 0.f};
    acc[1] = (f32x4){0.f, 0.f, 0.f, 0.f};
    const half8* wbase = Wp + wv * 64 + lane;
    const _Float16* sbase0 = &S[pl * 456 + g * 8];
    const _Float16* sbase1 = &S[(16 + pl) * 456 + g * 8];

    #define DCHUNK(T0, NT)                                                   \
        for (int u = wv; u < (NT) * 4; u += 4) {                             \
            int kk = u >> 2, pg = u & 3;                                     \
            int p = pg * 8 + p8;                                             \
            int tap = ((T0) + kk) * 32 + p;                                  \
            int v = TPv[tap];                                                \
            int nb = (v >> 8) - 4096, mask = v & 255;                        \
            half4 f = *(const half4*)&TPF[tap * 4];                          \
            _Float16 one = (_Float16)1.f;                                    \
            _Float16 rh = f[0], rw = f[1], rd = f[2];                        \
            _Float16 h0 = one - rh, w0 = one - rw, d0 = one - rd;            \
            _Float16 t00 = h0 * w0, t01 = h0 * rw;                           \
            _Float16 t10 = rh * w0, t11 = rh * rw;                           \
            half2v a0 = (half2v)0, a1 = (half2v)0, a2 = (half2v)0,           \
                   a3 = (half2v)0;                                           \
            _Pragma("unroll")                                                \
            for (int i = 0; i < 8; ++i) {                                    \
                int nn = nb + ((i >> 2) & 1) * 1024 + ((i >> 1) & 1) * 32    \
                       + (i & 1);                                            \
                bool okc = (mask >> i) & 1;                                  \
                size_t ad = okc ? ((size_t)nn << 6) : 0;                     \
                half8 vv = *(const half8*)(aTh + ad + (co << 3));            \
                _Float16 txy = (i & 4) ? ((i & 2) ? t11 : t10)               \
                                       : ((i & 2) ? t01 : t00);              \
                _Float16 wg = txy * ((i & 1) ? rd : d0);                     \
                wg = okc ? wg : (_Float16)0.f;                               \
                half2v wg2 = {wg, wg};                                       \
                a0 += (half2v){vv[0], vv[1]} * wg2;                          \
                a1 += (half2v){vv[2], vv[3]} * wg2;                          \
                a2 += (half2v){vv[4], vv[5]} * wg2;                          \
                a3 += (half2v){vv[6], vv[7]} * wg2;                          \
            }                                                                \
            half8 r;                                                         \
            r[0] = a0[0]; r[1] = a0[1]; r[2] = a1[0]; r[3] = a1[1];          \
            r[4] = a2[0]; r[5] = a2[1]; r[6] = a3[0]; r[7] = a3[1];          \
            *(half8*)&S[p * 456 + kk * 64 + (co << 3)] = r;                  \
        }                                                                    \
        __syncthreads();                                                     \
        _Pragma("unroll")                                                    \
        for (int kb = 0; kb < (NT) * 2; ++kb) {                              \
            half8 af = wbase[(size_t)(2 * (T0) + kb) * 256];                 \
            half8 bf0 = *(const half8*)(sbase0 + kb * 32);                   \
            half8 bf1 = *(const half8*)(sbase1 + kb * 32);                   \
            acc[0] = __builtin_amdgcn_mfma_f32_16x16x32_f16(af, bf0,         \
                         acc[0], 0, 0, 0);                                   \
            acc[1] = __builtin_amdgcn_mfma_f32_16x16x32_f16(af, bf1,         \
                         acc[1], 0, 0, 0);                                   \
        }                                                                    \
        __syncthreads();

    DCHUNK(0, 7)
    DCHUNK(7, 7)
    DCHUNK(14, 7)
    DCHUNK(21, 6)
    #undef DCHUNK

    #pragma unroll
    for (int pt = 0; pt < 2; ++pt) {
        half4 hv;
        #pragma unroll
        for (int r2 = 0; r2 < 4; ++r2) {
            int o = wv * 16 + g * 4 + r2;
            hv[r2] = (_Float16)(acc[pt][r2] + db[o]);
        }
        *(half4*)&dcnT[(size_t)(n0 + pt * 16 + pl) * 64 + wv * 16 + g * 4] = hv;
    }
}

// ---------------------------------------------------------------------------
// K7 (MFMA): a2 = conv1_w @ dcn + b ; h = U * a2 ; out = proj2_w @ h + b2 + x
// dcnT f16 [N][C]: staging is 2 coalesced half8 copies (no transpose).
__global__ __launch_bounds__(256) void k_finalm(const _Float16* __restrict__ dcnT,
        const _Float16* __restrict__ Uh, const float* __restrict__ x,
        const half8* __restrict__ Wc1, const float* __restrict__ c1b,
        const half8* __restrict__ Wp2f, const float* __restrict__ p2b,
        float* __restrict__ out) {
    __shared__ __align__(16) _Float16 Sd[64 * 72];   // 9216 B
    __shared__ __align__(16) _Float16 Sh[64 * 72];   // 9216 B
    int t = threadIdx.x;
    int n0 = blockIdx.x * 64;
    int lane = t & 63, wv = t >> 6;
    #pragma unroll
    for (int i = 0; i < 2; ++i) {
        int u = i * 256 + t;
        int nl = u >> 3, oct = u & 7;
        *(half8*)&Sd[nl * 72 + oct * 8] =
            *(const half8*)&dcnT[(size_t)(n0 + nl) * 64 + oct * 8];
    }
    __syncthreads();

    int pl = lane & 15, g = lane >> 4;
    int ob = wv;
    const half8* w1 = Wc1 + ob * 64 + lane;
    #pragma unroll
    for (int nt = 0; nt < 4; ++nt) {                 // GEMM1 + gate
        f32x4 acc4 = {0.f, 0.f, 0.f, 0.f};
        const _Float16* sb = &Sd[(nt * 16 + pl) * 72 + g * 8];
        #pragma unroll
        for (int kb = 0; kb < 2; ++kb) {
            half8 af = w1[kb * 256];
            half8 bf = *(const half8*)(sb + kb * 32);
            acc4 = __builtin_amdgcn_mfma_f32_16x16x32_f16(af, bf, acc4, 0, 0, 0);
        }
        int n = n0 + nt * 16 + pl;
        int o0 = ob * 16 + g * 4;
        float4 bb = *(const float4*)&c1b[o0];
        half4 hv;
        hv[0] = (_Float16)((float)Uh[(size_t)(o0 + 0) * NSP + n] * (acc4[0] + bb.x));
        hv[1] = (_Float16)((float)Uh[(size_t)(o0 + 1) * NSP + n] * (acc4[1] + bb.y));
        hv[2] = (_Float16)((float)Uh[(size_t)(o0 + 2) * NSP + n] * (acc4[2] + bb.z));
        hv[3] = (_Float16)((float)Uh[(size_t)(o0 + 3) * NSP + n] * (acc4[3] + bb.w));
        *(half4*)&Sh[(nt * 16 + pl) * 72 + o0] = hv;
    }
    __syncthreads();

    const half8* w2 = Wp2f + ob * 64 + lane;
    #pragma unroll
    for (int nt = 0; nt < 4; ++nt) {                 // GEMM2 + residual
        f32x4 acc4 = {0.f, 0.f, 0.f, 0.f};
        const _Float16* sb = &Sh[(nt * 16 + pl) * 72 + g * 8];
        #pragma unroll
        for (int kb = 0; kb < 2; ++kb) {
            half8 af = w2[kb * 256];
            half8 bf = *(const half8*)(sb + kb * 32);
            acc4 = __builtin_amdgcn_mfma_f32_16x16x32_f16(af, bf, acc4, 0, 0, 0);
        }
        int n = n0 + nt * 16 + pl;
        int o0 = ob * 16 + g * 4;
        float4 bb = *(const float4*)&p2b[o0];
        float4 xr = *(const float4*)&x[(size_t)n * 64 + o0];
        float4 ov;
        ov.x = acc4[0] + bb.x + xr.x;
        ov.y = acc4[1] + bb.y + xr.y;
        ov.z = acc4[2] + bb.z + xr.z;
        ov.w = acc4[3] + bb.w + xr.w;
        *(float4*)&out[(size_t)n * 64 + o0] = ov;
    }
}

// ---------------------------------------------------------------------------
extern "C" void kernel_launch(void* const* d_in, const int* in_sizes, int n_in,
                              void* d_out, int out_size, void* d_ws, size_t ws_size,
                              hipStream_t stream) {
    const float* x   = (const float*)d_in[0];
    const float* p1w = (const float*)d_in[1];
    const float* p1b = (const float*)d_in[2];
    const float* c0w = (const float*)d_in[3];
    const float* c0b = (const float*)d_in[4];
    const float* csw = (const float*)d_in[5];
    const float* csb = (const float*)d_in[6];
    const float* ofw = (const float*)d_in[7];
    const float* ofb = (const float*)d_in[8];
    const float* dcw = (const float*)d_in[9];
    const float* dcb = (const float*)d_in[10];
    const float* c1w = (const float*)d_in[11];
    const float* c1b = (const float*)d_in[12];
    const float* p2w = (const float*)d_in[13];
    const float* p2b = (const float*)d_in[14];
    float* out = (float*)d_out;

    char* ws = (char*)d_ws;
    const size_t CN2 = (size_t)NCH * NSP * 2;       // 4 MiB per [C][N] f16
    _Float16* Uh   = (_Float16*)(ws);
    _Float16* T0h  = (_Float16*)(ws + CN2);
    _Float16* T1h  = (_Float16*)(ws + 2 * CN2);
    _Float16* aTh  = (_Float16*)(ws + 3 * CN2);
    float*    OFFp = (float*)(ws + 4 * CN2);        // 81*N f32
    _Float16* dcnT = (_Float16*)(ws + 4 * CN2 + (size_t)81 * NSP * 4);
    _Float16* Wp   = dcnT + (size_t)NSP * 64;
    _Float16* Wp2  = Wp + 110592;
    _Float16* Wp1  = Wp2 + 165888;
    _Float16* Wc1  = Wp1 + 4096;
    _Float16* Wp2f = Wc1 + 4096;

    k_wpack64  <<<16, 256, 0, stream>>>(p1w, Wp1);
    k_wpack64  <<<16, 256, 0, stream>>>(c1w, Wc1);
    k_wpack64  <<<16, 256, 0, stream>>>(p2w, Wp2f);
    k_wpack    <<<432, 256, 0, stream>>>(dcw, Wp);
    k_wpack_off<<<648, 256, 0, stream>>>(ofw, Wp2);
    k_proj1m   <<<NSP / 64, 256, 0, stream>>>(x, (const half8*)Wp1, p1b, Uh);
    k_dw5      <<<1024, 256, 0, stream>>>(Uh, c0w, c0b, T0h);
    k_dw7      <<<768, 256, 0, stream>>>(T0h, csw, csb, T1h);
    k_tr       <<<NSP / 64, 256, 0, stream>>>(T1h, aTh);
    k_offg     <<<512, 384, 0, stream>>>(aTh, (const half8*)Wp2, ofb, OFFp);
    k_deform   <<<1024, 256, 0, stream>>>(aTh, OFFp, (const half8*)Wp, dcb, dcnT);
    k_finalm   <<<NSP / 64, 256, 0, stream>>>(dcnT, Uh, x, (const half8*)Wc1, c1b,
                                              (const half8*)Wp2f, p2b, out);
}

// Round 14
// 120.803 us; speedup vs baseline: 22.7887x; 1.0385x over previous
//
#include <hip/hip_runtime.h>
#include <math.h>

#define NSP 32768   // H*W*D = 32*32*32
#define NCH 64

typedef _Float16 half8 __attribute__((ext_vector_type(8)));
typedef _Float16 half4 __attribute__((ext_vector_type(4)));
typedef _Float16 half2v __attribute__((ext_vector_type(2)));
typedef float f32x4 __attribute__((ext_vector_type(4)));

// ---------------------------------------------------------------------------
// K1 (MFMA): U = gelu(proj1_w @ x^T + b)   (U layout: f16 [C][N])
__global__ __launch_bounds__(256) void k_proj1m(const float* __restrict__ x,
        const half8* __restrict__ Wp1, const float* __restrict__ b,
        _Float16* __restrict__ Uh) {
    __shared__ __align__(16) _Float16 Sx[64 * 72];   // 9216 B
    int t = threadIdx.x;
    int n0 = blockIdx.x * 64;
    int lane = t & 63, wv = t >> 6;
    for (int i = wv; i < 64; i += 4) {
        float v = x[(size_t)(n0 + i) * 64 + lane];
        Sx[i * 72 + lane] = (_Float16)v;
    }
    __syncthreads();
    int pl = lane & 15, g = lane >> 4;
    int ob = wv;
    const half8* wbase = Wp1 + ob * 64 + lane;       // +256 per kb
    #pragma unroll
    for (int nt = 0; nt < 4; ++nt) {
        f32x4 acc4 = {0.f, 0.f, 0.f, 0.f};
        const _Float16* sb = &Sx[(nt * 16 + pl) * 72 + g * 8];
        #pragma unroll
        for (int kb = 0; kb < 2; ++kb) {
            half8 af = wbase[kb * 256];
            half8 bf = *(const half8*)(sb + kb * 32);
            acc4 = __builtin_amdgcn_mfma_f32_16x16x32_f16(af, bf, acc4, 0, 0, 0);
        }
        int n = n0 + nt * 16 + pl;
        #pragma unroll
        for (int r = 0; r < 4; ++r) {
            int o = ob * 16 + g * 4 + r;
            float a = acc4[r] + b[o];
            float gv = 0.5f * a * (1.0f + erff(a * 0.70710678118654752f));
            Uh[(size_t)o * NSP + n] = (_Float16)gv;
        }
    }
}

// ---------------------------------------------------------------------------
// K2: depthwise 5x5x5, pad 2.  f16 in/out; weights uniform->SGPR.
__global__ __launch_bounds__(256) void k_dw5(const _Float16* __restrict__ in,
        const float* __restrict__ w, const float* __restrict__ b,
        _Float16* __restrict__ out) {
    __shared__ float Sb5[2][20 * 38];                // 6080 B
    int t = threadIdx.x;
    int bid = blockIdx.x;
    int blk = (bid & 7) * 128 + (bid >> 3);          // XCD-chunked
    int c  = blk >> 4;
    int hq = (blk >> 1) & 7;
    int wq = blk & 1;
    int d  = t & 31;
    int wbloc = t >> 5;                              // 0..7
    int wb = wq * 8 + wbloc;
    const float* wc = w + c * 125;                   // uniform -> scalar loads
    const _Float16* src = in + ((size_t)c << 15);

    for (int idx = t; idx < 160; idx += 256) {
        int bi = idx / 80, r = idx % 80;
        int wi = r >> 2, e = r & 3;
        int Dp = (e < 2) ? e : 32 + e;               // {0,1,34,35}
        Sb5[bi][wi * 38 + Dp] = 0.f;
    }

    float bc = b[c];
    float acc[4][2];
    #pragma unroll
    for (int a = 0; a < 4; ++a) { acc[a][0] = bc; acc[a][1] = bc; }

    #define STAGE5(m)                                                        \
        { int hh_ = 4 * hq + (m) - 2;                                        \
          if ((unsigned)hh_ < 32u) {                                         \
            const _Float16* row_ = src + (hh_ << 10);                        \
            for (int idx = t; idx < 80; idx += 256) {                        \
                int wi = idx >> 2, oct = idx & 3;                            \
                int wj = 16 * wq - 2 + wi;                                   \
                half8 vv = (half8)(_Float16)0.f;                             \
                if ((unsigned)wj < 32u)                                      \
                    vv = *(const half8*)&row_[(wj << 5) + oct * 8];          \
                float* dst = &Sb5[(m) & 1][wi * 38 + 2 + oct * 8];           \
                dst[0] = (float)vv[0]; dst[1] = (float)vv[1];                \
                dst[2] = (float)vv[2]; dst[3] = (float)vv[3];                \
                dst[4] = (float)vv[4]; dst[5] = (float)vv[5];                \
                dst[6] = (float)vv[6]; dst[7] = (float)vv[7];                \
            } } }

    STAGE5(0)
    __syncthreads();
    #pragma unroll 1
    for (int m = 0; m < 8; ++m) {
        if (m < 7) STAGE5(m + 1)
        int hh = 4 * hq + m - 2;
        if ((unsigned)hh < 32u) {
            float v[6][5];
            const float* sb = &Sb5[m & 1][0];
            #pragma unroll
            for (int jc = 0; jc < 6; ++jc)
                #pragma unroll
                for (int l = 0; l < 5; ++l)
                    v[jc][l] = sb[(2 * wbloc + jc) * 38 + d + l];
            #pragma unroll
            for (int a = 0; a < 4; ++a) {
                if (a <= m && m <= a + 4) {
                    const float* wr = wc + (m - a) * 25;   // uniform
                    float s0 = 0.f, s1 = 0.f;
                    #pragma unroll
                    for (int j = 0; j < 5; ++j)
                        #pragma unroll
                        for (int l = 0; l < 5; ++l) {
                            float wv2 = wr[j * 5 + l];
                            s0 += wv2 * v[j][l];
                            s1 += wv2 * v[j + 1][l];
                        }
                    acc[a][0] += s0;
                    acc[a][1] += s1;
                }
            }
        }
        __syncthreads();
    }
    #pragma unroll
    for (int a = 0; a < 4; ++a)
        #pragma unroll
        for (int bb = 0; bb < 2; ++bb)
            out[(size_t)c * NSP + ((4 * hq + a) << 10) + ((2 * wb + bb) << 5) + d]
                = (_Float16)acc[a][bb];
    #undef STAGE5
}

// ---------------------------------------------------------------------------
// K3: depthwise 7x7x7 dilation 3.  f16 in/out; half8 staging; pk inner.
__global__ __launch_bounds__(256) void k_dw7(const _Float16* __restrict__ in,
        const float* __restrict__ w, const float* __restrict__ b,
        _Float16* __restrict__ out) {
    __shared__ float Sb7[2][26 * 52];                // 10816 B
    int t = threadIdx.x;
    int bid = blockIdx.x;
    int blk = (bid & 7) * 96 + (bid >> 3);           // XCD-chunked
    int c  = blk / 12;
    int h0 = (blk % 12) >> 2;
    int wq = blk & 3;
    int d  = t & 31;
    int wloc = t >> 5;                               // 0..7
    int w_ = wq * 8 + wloc;
    const float* wc = w + c * 343;                   // uniform -> scalar loads
    const _Float16* src = in + ((size_t)c << 15);

    for (int idx = t; idx < 936; idx += 256) {
        int bi = idx / 468, r = idx % 468;
        int wi = r / 18, e = r % 18;
        int Dp = (e < 9) ? e : 32 + e;               // {0..8, 41..49}
        Sb7[bi][wi * 52 + Dp] = 0.f;
    }

    float bc = b[c];
    float acc[11];
    #pragma unroll
    for (int a = 0; a < 11; ++a) acc[a] = bc;

    #define STAGE7(m)                                                        \
        { int hh_ = h0 + 3 * (m) - 9;                                        \
          if ((unsigned)hh_ < 32u) {                                         \
            const _Float16* row_ = src + (hh_ << 10);                        \
            for (int idx = t; idx < 104; idx += 256) {                       \
                int wi = idx >> 2, oct = idx & 3;                            \
                int wj = 8 * wq - 9 + wi;                                    \
                half8 vv = (half8)(_Float16)0.f;                             \
                if ((unsigned)wj < 32u)                                      \
                    vv = *(const half8*)&row_[(wj << 5) + oct * 8];          \
                float* dst = &Sb7[(m) & 1][wi * 52 + 9 + oct * 8];           \
                dst[0] = (float)vv[0]; dst[1] = (float)vv[1];                \
                dst[2] = (float)vv[2]; dst[3] = (float)vv[3];                \
                dst[4] = (float)vv[4]; dst[5] = (float)vv[5];                \
                dst[6] = (float)vv[6]; dst[7] = (float)vv[7];                \
            } } }

    STAGE7(0)
    __syncthreads();
    #pragma unroll 1
    for (int m = 0; m < 17; ++m) {
        if (m < 16) STAGE7(m + 1)
        int hh = h0 + 3 * m - 9;
        if ((unsigned)hh < 32u) {
            float vf[49];
            const float* sb = &Sb7[m & 1][0];
            #pragma unroll
            for (int jw = 0; jw < 7; ++jw)
                #pragma unroll
                for (int l = 0; l < 7; ++l)
                    vf[jw * 7 + l] = sb[(wloc + 3 * jw) * 52 + d + 3 * l];
            #pragma unroll
            for (int a = 0; a < 11; ++a) {
                if (a <= m && m <= a + 6) {
                    const float* wr = wc + (m - a) * 49;   // uniform
                    float sA = 0.f, sB = 0.f;              // 2 chains -> pk
                    #pragma unroll
                    for (int q = 0; q < 24; ++q) {
                        sA = fmaf(wr[2 * q],     vf[2 * q],     sA);
                        sB = fmaf(wr[2 * q + 1], vf[2 * q + 1], sB);
                    }
                    acc[a] += sA + sB + wr[48] * vf[48];
                }
            }
        }
        __syncthreads();
    }
    #pragma unroll
    for (int a = 0; a < 11; ++a) {
        int h = h0 + 3 * a;
        if (h < 32)
            out[(size_t)c * NSP + (h << 10) + (w_ << 5) + d] = (_Float16)acc[a];
    }
    #undef STAGE7
}

// ---------------------------------------------------------------------------
// K4: transpose f16 [C][N] -> f16 [N][C], half8 both sides
__global__ __launch_bounds__(256) void k_tr(const _Float16* __restrict__ in,
        _Float16* __restrict__ outh) {
    __shared__ __align__(16) _Float16 tile[64 * 74];  // 9472 B
    int t = threadIdx.x;
    int n0 = blockIdx.x * 64;
    #pragma unroll
    for (int i = 0; i < 2; ++i) {
        int u = i * 256 + t;         // 0..511
        int c = u >> 3, oct = u & 7;
        half8 v = *(const half8*)&in[(size_t)c * NSP + n0 + oct * 8];
        *(half8*)&tile[c * 74 + oct * 8] = v;
    }
    __syncthreads();
    #pragma unroll
    for (int i = 0; i < 2; ++i) {
        int u = i * 256 + t;
        int nl = u >> 3, co = u & 7;
        half8 r;
        #pragma unroll
        for (int j = 0; j < 8; ++j) r[j] = tile[(co * 8 + j) * 74 + nl];
        *(half8*)&outh[(size_t)(n0 + nl) * 64 + co * 8] = r;
    }
}

// ---------------------------------------------------------------------------
// K5 (fused): ALL weight packs in one kernel.
//  blocks [0,16): p1w->Wp1   [16,32): c1w->Wc1   [32,48): p2w->Wp2f
//  blocks [48,480): dcw->Wp (4 o-blocks)
//  blocks [480,1128): ofw->Wp2 (6 o-blocks, rows 81..95 = 0)
__global__ __launch_bounds__(256) void k_wpack_all(
        const float* __restrict__ p1w, const float* __restrict__ c1w,
        const float* __restrict__ p2w, const float* __restrict__ dcw,
        const float* __restrict__ ofw,
        _Float16* __restrict__ Wp1, _Float16* __restrict__ Wc1,
        _Float16* __restrict__ Wp2f, _Float16* __restrict__ Wp,
        _Float16* __restrict__ Wp2) {
    int bidx = blockIdx.x;
    int t = threadIdx.x;
    if (bidx < 48) {
        const float* w = (bidx < 16) ? p1w : (bidx < 32) ? c1w : p2w;
        _Float16* Wd   = (bidx < 16) ? Wp1 : (bidx < 32) ? Wc1 : Wp2f;
        int idx = (bidx & 15) * 256 + t;             // 0..4095
        int j = idx & 7;
        int l = (idx >> 3) & 63;
        int obk = idx >> 9;
        int ob = obk & 3, kb = obk >> 2;
        int o = ob * 16 + (l & 15);
        int Kp = kb * 32 + (l >> 4) * 8 + j;
        Wd[idx] = (_Float16)w[o * 64 + Kp];
    } else if (bidx < 480) {
        int idx = (bidx - 48) * 256 + t;             // 0..110591
        int j = idx & 7;
        int l = (idx >> 3) & 63;
        int obk = idx >> 9;
        int ob = obk & 3, kb = obk >> 2;
        int o = ob * 16 + (l & 15);
        int Kp = kb * 32 + (l >> 4) * 8 + j;
        int k = Kp >> 6, c = Kp & 63;
        Wp[idx] = (_Float16)dcw[(size_t)o * 1728 + c * 27 + k];
    } else {
        int idx = (bidx - 480) * 256 + t;            // 0..165887
        int j = idx & 7;
        int l = (idx >> 3) & 63;
        int obk = idx >> 9;                          // 0..323
        int ob = obk % 6, kb = obk / 6;
        int o = ob * 16 + (l & 15);
        int Kp = kb * 32 + (l >> 4) * 8 + j;
        int k = Kp >> 6, c = Kp & 63;
        Wp2[idx] = (o < 81) ? (_Float16)ofw[(size_t)o * 1728 + c * 27 + k]
                            : (_Float16)0.f;
    }
}

// ---------------------------------------------------------------------------
// K5c: offset conv, 32-position tile (one (h,w) d-row), kh-chunked dbuf halo
// [2][3 nbr][34 d][72 ch] f16 = 28.7 KB -> 4 blocks/CU (grid 1024).
// Epilogue: LDS-transpose (aliased) -> OFFn f32 [N][108], slot = k*4+c,
// coalesced float4 stores (k_deform reads 1 float4 per tap).
__global__ __launch_bounds__(384) void k_offg(const _Float16* __restrict__ aTh,
        const half8* __restrict__ Wp2, const float* __restrict__ obias,
        float* __restrict__ OFFn) {
    __shared__ __align__(16) char SMEM[29376];       // S2 | TF alias
    _Float16* S2 = (_Float16*)SMEM;                  // [2][3*34*72]
    float*    TF = (float*)SMEM;                     // [32][108]
    const int SB = 3 * 34 * 72;                      // 7344 halfs per buffer
    int t = threadIdx.x;
    int bid = blockIdx.x;
    int blk = (bid & 7) * 128 + (bid >> 3);          // 1024 blocks, XCD-chunked
    int h = blk >> 5, w = blk & 31;
    int n0 = blk << 5;
    int lane = t & 63, wv = t >> 6;                  // wv 0..5
    int co8 = (lane & 7) << 3;

    // constant-zero d-edge rows (dd 0 and 33), both buffers
    for (int u = t; u < 864; u += 384) {
        int bi = u / 432, r2 = u % 432;
        int nbw = r2 / 144, r3 = r2 % 144;
        int dd = (r3 >= 72) ? 33 : 0, cc = r3 % 72;
        S2[bi * SB + (nbw * 34 + dd) * 72 + cc] = (_Float16)0.f;
    }

    int pl = lane & 15, g = lane >> 4;
    int obi = wv;
    f32x4 acc[2];
    acc[0] = (f32x4){0.f, 0.f, 0.f, 0.f};
    acc[1] = (f32x4){0.f, 0.f, 0.f, 0.f};
    const half8* wb = Wp2 + obi * 64 + lane;

    // stage chunk kh (h-row = h+kh-1): 3 w-nbrs x 4 d-octets, half8/lane
    #define OSTAGE(kh)                                                        \
        { int hh_ = h + (kh) - 1;                                            \
          bool okh_ = (unsigned)hh_ < 32u;                                   \
          for (int u = wv; u < 12; u += 6) {                                 \
              int nbw = u >> 2, oct = u & 3;                                 \
              int wj = w + nbw - 1;                                          \
              int di = oct * 8 + (lane >> 3);                                \
              bool ok = okh_ & ((unsigned)wj < 32u);                         \
              half8 vv = (half8)(_Float16)0.f;                               \
              if (ok) vv = *(const half8*)(aTh +                             \
                  ((size_t)((((hh_ << 5) + wj) << 5) + di)) * 64 + co8);     \
              *(half8*)&S2[((kh) & 1) * SB + (nbw * 34 + 1 + di) * 72 + co8] \
                  = vv;                                                      \
          } }

    // MFMA chunk kh: 18 kbs (taps kh*9..kh*9+8), af feeds 2 p-tiles
    #define OCOMP(kh)                                                        \
        { const _Float16* sb = &S2[((kh) & 1) * SB + pl * 72 + g * 8];       \
          _Pragma("unroll")                                                  \
          for (int kk = 0; kk < 18; ++kk) {                                  \
              int kglob = (kh) * 9 + (kk >> 1);                              \
              int kw3 = (kglob / 3) % 3, kd = kglob % 3;                     \
              half8 af = wb[(size_t)((kh) * 18 + kk) * 384];                 \
              _Pragma("unroll")                                              \
              for (int pt = 0; pt < 2; ++pt) {                               \
                  int row = kw3 * 34 + pt * 16 + kd;                         \
                  half8 bf = *(const half8*)(sb + row * 72 + (kk & 1) * 32); \
                  acc[pt] = __builtin_amdgcn_mfma_f32_16x16x32_f16(          \
                                af, bf, acc[pt], 0, 0, 0);                   \
              }                                                              \
          } }

    OSTAGE(0)
    __syncthreads();
    OSTAGE(1)
    OCOMP(0)
    __syncthreads();
    OSTAGE(2)
    OCOMP(1)
    __syncthreads();
    OCOMP(2)
    #undef OSTAGE
    #undef OCOMP

    __syncthreads();                                 // S2 -> TF alias switch
    #pragma unroll
    for (int pt = 0; pt < 2; ++pt) {
        int pos = pt * 16 + pl;
        #pragma unroll
        for (int r = 0; r < 4; ++r) {
            int o = obi * 16 + g * 4 + r;
            if (o < 81) {
                int slot = (o / 3) * 4 + o % 3;
                TF[pos * 108 + slot] = acc[pt][r] + obias[o];
            }
        }
    }
    __syncthreads();
    for (int u = t; u < 864; u += 384) {             // 32 rows x 27 float4
        int row = u / 27, q = u - row * 27;
        float4 v = *(const float4*)&TF[row * 108 + q * 4];
        *(float4*)&OFFn[(size_t)(n0 + row) * 108 + q * 4] = v;
    }
}

// ---------------------------------------------------------------------------
// K6: deformable gather + MFMA GEMM, 32-position blocks, 4 K-chunks.
// Phase A reads OFFn [N][108]: ONE float4 per tap.
__global__ __launch_bounds__(256) void k_deform(const _Float16* __restrict__ aTh,
        const float* __restrict__ OFFn, const half8* __restrict__ Wp,
        const float* __restrict__ db, _Float16* __restrict__ dcnT) {
    __shared__ __align__(16) _Float16 S[32 * 456];     // 29184 B (7 taps max)
    __shared__ __align__(16) _Float16 TPF[864 * 4];    // 6912 B {rh,rw,rd,_}
    __shared__ int TPv[864];                           // 3456 B (total 39552)
    int t = threadIdx.x;
    int bid = blockIdx.x;
    int blk = (bid & 7) * 128 + (bid >> 3);  // 1024 blocks, n-slabs per XCD
    int n0 = blk * 32;
    int lane = t & 63, wv = t >> 6;

    for (int idx = t; idx < 864; idx += 256) {        // Phase A: 27k x 32p
        int p = idx & 31, k = idx >> 5;
        int n = n0 + p;
        int h = n >> 10, w = (n >> 5) & 31, d = n & 31;
        float4 ov = *(const float4*)&OFFn[(size_t)n * 108 + k * 4];
        float ph = (float)(h + k / 9 - 1)       + ov.x;
        float pw = (float)(w + (k / 3) % 3 - 1) + ov.y;
        float pd = (float)(d + k % 3 - 1)       + ov.z;
        float fh = floorf(ph), fw = floorf(pw), fd = floorf(pd);
        int ih = (int)fh, iw = (int)fw, id = (int)fd;
        int nb0 = ih * 1024 + iw * 32 + id;
        int mask = 0;
        #pragma unroll
        for (int cb = 0; cb < 8; ++cb) {
            int hh = ih + ((cb >> 2) & 1);
            int wq = iw + ((cb >> 1) & 1);
            int dq = id + (cb & 1);
            bool ok = ((unsigned)hh < 32u) & ((unsigned)wq < 32u) & ((unsigned)dq < 32u);
            mask |= (ok ? 1 : 0) << cb;
        }
        TPv[idx] = ((nb0 + 4096) << 8) | mask;
        half4 f;
        f[0] = (_Float16)(ph - fh);
        f[1] = (_Float16)(pw - fw);
        f[2] = (_Float16)(pd - fd);
        f[3] = (_Float16)0.f;
        *(half4*)&TPF[idx * 4] = f;
    }
    __syncthreads();

    int p8 = lane >> 3, co = lane & 7;
    int pl = lane & 15, g = lane >> 4;
    f32x4 acc[2];
    acc[0] = (f32x4){0.f, 0.f, 0.f, 0.f};
    acc[1] = (f32x4){0.f, 0.f, 0.f, 0.f};
    const half8* wbase = Wp + wv * 64 + lane;
    const _Float16* sbase0 = &S[pl * 456 + g * 8];
    const _Float16* sbase1 = &S[(16 + pl) * 456 + g * 8];

    #define DCHUNK(T0, NT)                                                   \
        for (int u = wv; u < (NT) * 4; u += 4) {                             \
            int kk = u >> 2, pg = u & 3;                                     \
            int p = pg * 8 + p8;                                             \
            int tap = ((T0) + kk) * 32 + p;                                  \
            int v = TPv[tap];                                                \
            int nb = (v >> 8) - 4096, mask = v & 255;                        \
            half4 f = *(const half4*)&TPF[tap * 4];                          \
            _Float16 one = (_Float16)1.f;                                    \
            _Float16 rh = f[0], rw = f[1], rd = f[2];                        \
            _Float16 h0 = one - rh, w0 = one - rw, d0 = one - rd;            \
            _Float16 t00 = h0 * w0, t01 = h0 * rw;                           \
            _Float16 t10 = rh * w0, t11 = rh * rw;                           \
            half2v a0 = (half2v)0, a1 = (half2v)0, a2 = (half2v)0,           \
                   a3 = (half2v)0;                                           \
            _Pragma("unroll")                                                \
            for (int i = 0; i < 8; ++i) {                                    \
                int nn = nb + ((i >> 2) & 1) * 1024 + ((i >> 1) & 1) * 32    \
                       + (i & 1);                                            \
                bool okc = (mask >> i) & 1;                                  \
                size_t ad = okc ? ((size_t)nn << 6) : 0;                     \
                half8 vv = *(const half8*)(aTh + ad + (co << 3));            \
                _Float16 txy = (i & 4) ? ((i & 2) ? t11 : t10)               \
                                       : ((i & 2) ? t01 : t00);              \
                _Float16 wg = txy * ((i & 1) ? rd : d0);                     \
                wg = okc ? wg : (_Float16)0.f;                               \
                half2v wg2 = {wg, wg};                                       \
                a0 += (half2v){vv[0], vv[1]} * wg2;                          \
                a1 += (half2v){vv[2], vv[3]} * wg2;                          \
                a2 += (half2v){vv[4], vv[5]} * wg2;                          \
                a3 += (half2v){vv[6], vv[7]} * wg2;                          \
            }                                                                \
            half8 r;                                                         \
            r[0] = a0[0]; r[1] = a0[1]; r[2] = a1[0]; r[3] = a1[1];          \
            r[4] = a2[0]; r[5] = a2[1]; r[6] = a3[0]; r[7] = a3[1];          \
            *(half8*)&S[p * 456 + kk * 64 + (co << 3)] = r;                  \
        }                                                                    \
        __syncthreads();                                                     \
        _Pragma("unroll")                                                    \
        for (int kb = 0; kb < (NT) * 2; ++kb) {                              \
            half8 af = wbase[(size_t)(2 * (T0) + kb) * 256];                 \
            half8 bf0 = *(const half8*)(sbase0 + kb * 32);                   \
            half8 bf1 = *(const half8*)(sbase1 + kb * 32);                   \
            acc[0] = __builtin_amdgcn_mfma_f32_16x16x32_f16(af, bf0,         \
                         acc[0], 0, 0, 0);                                   \
            acc[1] = __builtin_amdgcn_mfma_f32_16x16x32_f16(af, bf1,         \
                         acc[1], 0, 0, 0);                                   \
        }                                                                    \
        __syncthreads();

    DCHUNK(0, 7)
    DCHUNK(7, 7)
    DCHUNK(14, 7)
    DCHUNK(21, 6)
    #undef DCHUNK

    #pragma unroll
    for (int pt = 0; pt < 2; ++pt) {
        half4 hv;
        #pragma unroll
        for (int r2 = 0; r2 < 4; ++r2) {
            int o = wv * 16 + g * 4 + r2;
            hv[r2] = (_Float16)(acc[pt][r2] + db[o]);
        }
        *(half4*)&dcnT[(size_t)(n0 + pt * 16 + pl) * 64 + wv * 16 + g * 4] = hv;
    }
}

// ---------------------------------------------------------------------------
// K7 (MFMA): a2 = conv1_w @ dcn + b ; h = U * a2 ; out = proj2_w @ h + b2 + x
__global__ __launch_bounds__(256) void k_finalm(const _Float16* __restrict__ dcnT,
        const _Float16* __restrict__ Uh, const float* __restrict__ x,
        const half8* __restrict__ Wc1, const float* __restrict__ c1b,
        const half8* __restrict__ Wp2f, const float* __restrict__ p2b,
        float* __restrict__ out) {
    __shared__ __align__(16) _Float16 Sd[64 * 72];   // 9216 B
    __shared__ __align__(16) _Float16 Sh[64 * 72];   // 9216 B
    int t = threadIdx.x;
    int n0 = blockIdx.x * 64;
    int lane = t & 63, wv = t >> 6;
    #pragma unroll
    for (int i = 0; i < 2; ++i) {
        int u = i * 256 + t;
        int nl = u >> 3, oct = u & 7;
        *(half8*)&Sd[nl * 72 + oct * 8] =
            *(const half8*)&dcnT[(size_t)(n0 + nl) * 64 + oct * 8];
    }
    __syncthreads();

    int pl = lane & 15, g = lane >> 4;
    int ob = wv;
    const half8* w1 = Wc1 + ob * 64 + lane;
    #pragma unroll
    for (int nt = 0; nt < 4; ++nt) {                 // GEMM1 + gate
        f32x4 acc4 = {0.f, 0.f, 0.f, 0.f};
        const _Float16* sb = &Sd[(nt * 16 + pl) * 72 + g * 8];
        #pragma unroll
        for (int kb = 0; kb < 2; ++kb) {
            half8 af = w1[kb * 256];
            half8 bf = *(const half8*)(sb + kb * 32);
            acc4 = __builtin_amdgcn_mfma_f32_16x16x32_f16(af, bf, acc4, 0, 0, 0);
        }
        int n = n0 + nt * 16 + pl;
        int o0 = ob * 16 + g * 4;
        float4 bb = *(const float4*)&c1b[o0];
        half4 hv;
        hv[0] = (_Float16)((float)Uh[(size_t)(o0 + 0) * NSP + n] * (acc4[0] + bb.x));
        hv[1] = (_Float16)((float)Uh[(size_t)(o0 + 1) * NSP + n] * (acc4[1] + bb.y));
        hv[2] = (_Float16)((float)Uh[(size_t)(o0 + 2) * NSP + n] * (acc4[2] + bb.z));
        hv[3] = (_Float16)((float)Uh[(size_t)(o0 + 3) * NSP + n] * (acc4[3] + bb.w));
        *(half4*)&Sh[(nt * 16 + pl) * 72 + o0] = hv;
    }
    __syncthreads();

    const half8* w2 = Wp2f + ob * 64 + lane;
    #pragma unroll
    for (int nt = 0; nt < 4; ++nt) {                 // GEMM2 + residual
        f32x4 acc4 = {0.f, 0.f, 0.f, 0.f};
        const _Float16* sb = &Sh[(nt * 16 + pl) * 72 + g * 8];
        #pragma unroll
        for (int kb = 0; kb < 2; ++kb) {
            half8 af = w2[kb * 256];
            half8 bf = *(const half8*)(sb + kb * 32);
            acc4 = __builtin_amdgcn_mfma_f32_16x16x32_f16(af, bf, acc4, 0, 0, 0);
        }
        int n = n0 + nt * 16 + pl;
        int o0 = ob * 16 + g * 4;
        float4 bb = *(const float4*)&p2b[o0];
        float4 xr = *(const float4*)&x[(size_t)n * 64 + o0];
        float4 ov;
        ov.x = acc4[0] + bb.x + xr.x;
        ov.y = acc4[1] + bb.y + xr.y;
        ov.z = acc4[2] + bb.z + xr.z;
        ov.w = acc4[3] + bb.w + xr.w;
        *(float4*)&out[(size_t)n * 64 + o0] = ov;
    }
}

// ---------------------------------------------------------------------------
extern "C" void kernel_launch(void* const* d_in, const int* in_sizes, int n_in,
                              void* d_out, int out_size, void* d_ws, size_t ws_size,
                              hipStream_t stream) {
    const float* x   = (const float*)d_in[0];
    const float* p1w = (const float*)d_in[1];
    const float* p1b = (const float*)d_in[2];
    const float* c0w = (const float*)d_in[3];
    const float* c0b = (const float*)d_in[4];
    const float* csw = (const float*)d_in[5];
    const float* csb = (const float*)d_in[6];
    const float* ofw = (const float*)d_in[7];
    const float* ofb = (const float*)d_in[8];
    const float* dcw = (const float*)d_in[9];
    const float* dcb = (const float*)d_in[10];
    const float* c1w = (const float*)d_in[11];
    const float* c1b = (const float*)d_in[12];
    const float* p2w = (const float*)d_in[13];
    const float* p2b = (const float*)d_in[14];
    float* out = (float*)d_out;

    char* ws = (char*)d_ws;
    const size_t CN2 = (size_t)NCH * NSP * 2;       // 4 MiB per [C][N] f16
    _Float16* Uh   = (_Float16*)(ws);
    _Float16* T0h  = (_Float16*)(ws + CN2);
    _Float16* T1h  = (_Float16*)(ws + 2 * CN2);
    _Float16* aTh  = (_Float16*)(ws + 3 * CN2);
    float*    OFFn = (float*)(ws + 4 * CN2);        // [N][108] f32 = 14.2 MB
    _Float16* dcnT = (_Float16*)(ws + 4 * CN2 + (size_t)NSP * 108 * 4);
    _Float16* Wp   = dcnT + (size_t)NSP * 64;
    _Float16* Wp2  = Wp + 110592;
    _Float16* Wp1  = Wp2 + 165888;
    _Float16* Wc1  = Wp1 + 4096;
    _Float16* Wp2f = Wc1 + 4096;

    k_wpack_all<<<1128, 256, 0, stream>>>(p1w, c1w, p2w, dcw, ofw,
                                          Wp1, Wc1, Wp2f, Wp, Wp2);
    k_proj1m   <<<NSP / 64, 256, 0, stream>>>(x, (const half8*)Wp1, p1b, Uh);
    k_dw5      <<<1024, 256, 0, stream>>>(Uh, c0w, c0b, T0h);
    k_dw7      <<<768, 256, 0, stream>>>(T0h, csw, csb, T1h);
    k_tr       <<<NSP / 64, 256, 0, stream>>>(T1h, aTh);
    k_offg     <<<1024, 384, 0, stream>>>(aTh, (const half8*)Wp2, ofb, OFFn);
    k_deform   <<<1024, 256, 0, stream>>>(aTh, OFFn, (const half8*)Wp, dcb, dcnT);
    k_finalm   <<<NSP / 64, 256, 0, stream>>>(dcnT, Uh, x, (const half8*)Wc1, c1b,
                                              (const half8*)Wp2f, p2b, out);
}

// Round 15
// 120.153 us; speedup vs baseline: 22.9120x; 1.0054x over previous
//
#include <hip/hip_runtime.h>
#include <math.h>

#define NSP 32768   // H*W*D = 32*32*32
#define NCH 64

typedef _Float16 half8 __attribute__((ext_vector_type(8)));
typedef _Float16 half4 __attribute__((ext_vector_type(4)));
typedef _Float16 half2v __attribute__((ext_vector_type(2)));
typedef float f32x4 __attribute__((ext_vector_type(4)));

// ---------------------------------------------------------------------------
// K1 (MFMA): U = gelu(proj1_w @ x^T + b)   (U layout: f16 [C][N])
__global__ __launch_bounds__(256) void k_proj1m(const float* __restrict__ x,
        const half8* __restrict__ Wp1, const float* __restrict__ b,
        _Float16* __restrict__ Uh) {
    __shared__ __align__(16) _Float16 Sx[64 * 72];   // 9216 B
    int t = threadIdx.x;
    int n0 = blockIdx.x * 64;
    int lane = t & 63, wv = t >> 6;
    for (int i = wv; i < 64; i += 4) {
        float v = x[(size_t)(n0 + i) * 64 + lane];
        Sx[i * 72 + lane] = (_Float16)v;
    }
    __syncthreads();
    int pl = lane & 15, g = lane >> 4;
    int ob = wv;
    const half8* wbase = Wp1 + ob * 64 + lane;       // +256 per kb
    #pragma unroll
    for (int nt = 0; nt < 4; ++nt) {
        f32x4 acc4 = {0.f, 0.f, 0.f, 0.f};
        const _Float16* sb = &Sx[(nt * 16 + pl) * 72 + g * 8];
        #pragma unroll
        for (int kb = 0; kb < 2; ++kb) {
            half8 af = wbase[kb * 256];
            half8 bf = *(const half8*)(sb + kb * 32);
            acc4 = __builtin_amdgcn_mfma_f32_16x16x32_f16(af, bf, acc4, 0, 0, 0);
        }
        int n = n0 + nt * 16 + pl;
        #pragma unroll
        for (int r = 0; r < 4; ++r) {
            int o = ob * 16 + g * 4 + r;
            float a = acc4[r] + b[o];
            float gv = 0.5f * a * (1.0f + erff(a * 0.70710678118654752f));
            Uh[(size_t)o * NSP + n] = (_Float16)gv;
        }
    }
}

// ---------------------------------------------------------------------------
// K2: depthwise 5x5x5, pad 2.  f16 in/out; weights uniform->SGPR.
__global__ __launch_bounds__(256) void k_dw5(const _Float16* __restrict__ in,
        const float* __restrict__ w, const float* __restrict__ b,
        _Float16* __restrict__ out) {
    __shared__ float Sb5[2][20 * 38];                // 6080 B
    int t = threadIdx.x;
    int bid = blockIdx.x;
    int blk = (bid & 7) * 128 + (bid >> 3);          // XCD-chunked
    int c  = blk >> 4;
    int hq = (blk >> 1) & 7;
    int wq = blk & 1;
    int d  = t & 31;
    int wbloc = t >> 5;                              // 0..7
    int wb = wq * 8 + wbloc;
    const float* wc = w + c * 125;                   // uniform -> scalar loads
    const _Float16* src = in + ((size_t)c << 15);

    for (int idx = t; idx < 160; idx += 256) {
        int bi = idx / 80, r = idx % 80;
        int wi = r >> 2, e = r & 3;
        int Dp = (e < 2) ? e : 32 + e;               // {0,1,34,35}
        Sb5[bi][wi * 38 + Dp] = 0.f;
    }

    float bc = b[c];
    float acc[4][2];
    #pragma unroll
    for (int a = 0; a < 4; ++a) { acc[a][0] = bc; acc[a][1] = bc; }

    #define STAGE5(m)                                                        \
        { int hh_ = 4 * hq + (m) - 2;                                        \
          if ((unsigned)hh_ < 32u) {                                         \
            const _Float16* row_ = src + (hh_ << 10);                        \
            for (int idx = t; idx < 80; idx += 256) {                        \
                int wi = idx >> 2, oct = idx & 3;                            \
                int wj = 16 * wq - 2 + wi;                                   \
                half8 vv = (half8)(_Float16)0.f;                             \
                if ((unsigned)wj < 32u)                                      \
                    vv = *(const half8*)&row_[(wj << 5) + oct * 8];          \
                float* dst = &Sb5[(m) & 1][wi * 38 + 2 + oct * 8];           \
                dst[0] = (float)vv[0]; dst[1] = (float)vv[1];                \
                dst[2] = (float)vv[2]; dst[3] = (float)vv[3];                \
                dst[4] = (float)vv[4]; dst[5] = (float)vv[5];                \
                dst[6] = (float)vv[6]; dst[7] = (float)vv[7];                \
            } } }

    STAGE5(0)
    __syncthreads();
    #pragma unroll 1
    for (int m = 0; m < 8; ++m) {
        if (m < 7) STAGE5(m + 1)
        int hh = 4 * hq + m - 2;
        if ((unsigned)hh < 32u) {
            float v[6][5];
            const float* sb = &Sb5[m & 1][0];
            #pragma unroll
            for (int jc = 0; jc < 6; ++jc)
                #pragma unroll
                for (int l = 0; l < 5; ++l)
                    v[jc][l] = sb[(2 * wbloc + jc) * 38 + d + l];
            #pragma unroll
            for (int a = 0; a < 4; ++a) {
                if (a <= m && m <= a + 4) {
                    const float* wr = wc + (m - a) * 25;   // uniform
                    float s0 = 0.f, s1 = 0.f;
                    #pragma unroll
                    for (int j = 0; j < 5; ++j)
                        #pragma unroll
                        for (int l = 0; l < 5; ++l) {
                            float wv2 = wr[j * 5 + l];
                            s0 += wv2 * v[j][l];
                            s1 += wv2 * v[j + 1][l];
                        }
                    acc[a][0] += s0;
                    acc[a][1] += s1;
                }
            }
        }
        __syncthreads();
    }
    #pragma unroll
    for (int a = 0; a < 4; ++a)
        #pragma unroll
        for (int bb = 0; bb < 2; ++bb)
            out[(size_t)c * NSP + ((4 * hq + a) << 10) + ((2 * wb + bb) << 5) + d]
                = (_Float16)acc[a][bb];
    #undef STAGE5
}

// ---------------------------------------------------------------------------
// K3: depthwise 7x7x7 dilation 3.  f16 in/out; half8 staging; pk inner.
__global__ __launch_bounds__(256) void k_dw7(const _Float16* __restrict__ in,
        const float* __restrict__ w, const float* __restrict__ b,
        _Float16* __restrict__ out) {
    __shared__ float Sb7[2][26 * 52];                // 10816 B
    int t = threadIdx.x;
    int bid = blockIdx.x;
    int blk = (bid & 7) * 96 + (bid >> 3);           // XCD-chunked
    int c  = blk / 12;
    int h0 = (blk % 12) >> 2;
    int wq = blk & 3;
    int d  = t & 31;
    int wloc = t >> 5;                               // 0..7
    int w_ = wq * 8 + wloc;
    const float* wc = w + c * 343;                   // uniform -> scalar loads
    const _Float16* src = in + ((size_t)c << 15);

    for (int idx = t; idx < 936; idx += 256) {
        int bi = idx / 468, r = idx % 468;
        int wi = r / 18, e = r % 18;
        int Dp = (e < 9) ? e : 32 + e;               // {0..8, 41..49}
        Sb7[bi][wi * 52 + Dp] = 0.f;
    }

    float bc = b[c];
    float acc[11];
    #pragma unroll
    for (int a = 0; a < 11; ++a) acc[a] = bc;

    #define STAGE7(m)                                                        \
        { int hh_ = h0 + 3 * (m) - 9;                                        \
          if ((unsigned)hh_ < 32u) {                                         \
            const _Float16* row_ = src + (hh_ << 10);                        \
            for (int idx = t; idx < 104; idx += 256) {                       \
                int wi = idx >> 2, oct = idx & 3;                            \
                int wj = 8 * wq - 9 + wi;                                    \
                half8 vv = (half8)(_Float16)0.f;                             \
                if ((unsigned)wj < 32u)                                      \
                    vv = *(const half8*)&row_[(wj << 5) + oct * 8];          \
                float* dst = &Sb7[(m) & 1][wi * 52 + 9 + oct * 8];           \
                dst[0] = (float)vv[0]; dst[1] = (float)vv[1];                \
                dst[2] = (float)vv[2]; dst[3] = (float)vv[3];                \
                dst[4] = (float)vv[4]; dst[5] = (float)vv[5];                \
                dst[6] = (float)vv[6]; dst[7] = (float)vv[7];                \
            } } }

    STAGE7(0)
    __syncthreads();
    #pragma unroll 1
    for (int m = 0; m < 17; ++m) {
        if (m < 16) STAGE7(m + 1)
        int hh = h0 + 3 * m - 9;
        if ((unsigned)hh < 32u) {
            float vf[49];
            const float* sb = &Sb7[m & 1][0];
            #pragma unroll
            for (int jw = 0; jw < 7; ++jw)
                #pragma unroll
                for (int l = 0; l < 7; ++l)
                    vf[jw * 7 + l] = sb[(wloc + 3 * jw) * 52 + d + 3 * l];
            #pragma unroll
            for (int a = 0; a < 11; ++a) {
                if (a <= m && m <= a + 6) {
                    const float* wr = wc + (m - a) * 49;   // uniform
                    float sA = 0.f, sB = 0.f;              // 2 chains -> pk
                    #pragma unroll
                    for (int q = 0; q < 24; ++q) {
                        sA = fmaf(wr[2 * q],     vf[2 * q],     sA);
                        sB = fmaf(wr[2 * q + 1], vf[2 * q + 1], sB);
                    }
                    acc[a] += sA + sB + wr[48] * vf[48];
                }
            }
        }
        __syncthreads();
    }
    #pragma unroll
    for (int a = 0; a < 11; ++a) {
        int h = h0 + 3 * a;
        if (h < 32)
            out[(size_t)c * NSP + (h << 10) + (w_ << 5) + d] = (_Float16)acc[a];
    }
    #undef STAGE7
}

// ---------------------------------------------------------------------------
// K4: transpose f16 [C][N] -> f16 [N][C], half8 both sides
__global__ __launch_bounds__(256) void k_tr(const _Float16* __restrict__ in,
        _Float16* __restrict__ outh) {
    __shared__ __align__(16) _Float16 tile[64 * 74];  // 9472 B
    int t = threadIdx.x;
    int n0 = blockIdx.x * 64;
    #pragma unroll
    for (int i = 0; i < 2; ++i) {
        int u = i * 256 + t;         // 0..511
        int c = u >> 3, oct = u & 7;
        half8 v = *(const half8*)&in[(size_t)c * NSP + n0 + oct * 8];
        *(half8*)&tile[c * 74 + oct * 8] = v;
    }
    __syncthreads();
    #pragma unroll
    for (int i = 0; i < 2; ++i) {
        int u = i * 256 + t;
        int nl = u >> 3, co = u & 7;
        half8 r;
        #pragma unroll
        for (int j = 0; j < 8; ++j) r[j] = tile[(co * 8 + j) * 74 + nl];
        *(half8*)&outh[(size_t)(n0 + nl) * 64 + co * 8] = r;
    }
}

// ---------------------------------------------------------------------------
// K5 (fused): ALL weight packs in one kernel.
__global__ __launch_bounds__(256) void k_wpack_all(
        const float* __restrict__ p1w, const float* __restrict__ c1w,
        const float* __restrict__ p2w, const float* __restrict__ dcw,
        const float* __restrict__ ofw,
        _Float16* __restrict__ Wp1, _Float16* __restrict__ Wc1,
        _Float16* __restrict__ Wp2f, _Float16* __restrict__ Wp,
        _Float16* __restrict__ Wp2) {
    int bidx = blockIdx.x;
    int t = threadIdx.x;
    if (bidx < 48) {
        const float* w = (bidx < 16) ? p1w : (bidx < 32) ? c1w : p2w;
        _Float16* Wd   = (bidx < 16) ? Wp1 : (bidx < 32) ? Wc1 : Wp2f;
        int idx = (bidx & 15) * 256 + t;             // 0..4095
        int j = idx & 7;
        int l = (idx >> 3) & 63;
        int obk = idx >> 9;
        int ob = obk & 3, kb = obk >> 2;
        int o = ob * 16 + (l & 15);
        int Kp = kb * 32 + (l >> 4) * 8 + j;
        Wd[idx] = (_Float16)w[o * 64 + Kp];
    } else if (bidx < 480) {
        int idx = (bidx - 48) * 256 + t;             // 0..110591
        int j = idx & 7;
        int l = (idx >> 3) & 63;
        int obk = idx >> 9;
        int ob = obk & 3, kb = obk >> 2;
        int o = ob * 16 + (l & 15);
        int Kp = kb * 32 + (l >> 4) * 8 + j;
        int k = Kp >> 6, c = Kp & 63;
        Wp[idx] = (_Float16)dcw[(size_t)o * 1728 + c * 27 + k];
    } else {
        int idx = (bidx - 480) * 256 + t;            // 0..165887
        int j = idx & 7;
        int l = (idx >> 3) & 63;
        int obk = idx >> 9;                          // 0..323
        int ob = obk % 6, kb = obk / 6;
        int o = ob * 16 + (l & 15);
        int Kp = kb * 32 + (l >> 4) * 8 + j;
        int k = Kp >> 6, c = Kp & 63;
        Wp2[idx] = (o < 81) ? (_Float16)ofw[(size_t)o * 1728 + c * 27 + k]
                            : (_Float16)0.f;
    }
}

// ---------------------------------------------------------------------------
// K5c: offset conv, 32-position tile, kh-chunked dbuf halo.  Output OFFn f16
// [N][108] (slot = k*4 + comp) via LDS-transpose epilogue (aliased).
__global__ __launch_bounds__(384) void k_offg(const _Float16* __restrict__ aTh,
        const half8* __restrict__ Wp2, const float* __restrict__ obias,
        _Float16* __restrict__ OFFn) {
    __shared__ __align__(16) char SMEM[29376];       // S2 | TFh alias
    _Float16* S2  = (_Float16*)SMEM;                 // [2][3*34*72]
    _Float16* TFh = (_Float16*)SMEM;                 // [32][108]
    const int SB = 3 * 34 * 72;                      // 7344 halfs per buffer
    int t = threadIdx.x;
    int bid = blockIdx.x;
    int blk = (bid & 7) * 128 + (bid >> 3);          // 1024 blocks, XCD-chunked
    int h = blk >> 5, w = blk & 31;
    int n0 = blk << 5;
    int lane = t & 63, wv = t >> 6;                  // wv 0..5
    int co8 = (lane & 7) << 3;

    for (int u = t; u < 864; u += 384) {             // zero d-edge rows
        int bi = u / 432, r2 = u % 432;
        int nbw = r2 / 144, r3 = r2 % 144;
        int dd = (r3 >= 72) ? 33 : 0, cc = r3 % 72;
        S2[bi * SB + (nbw * 34 + dd) * 72 + cc] = (_Float16)0.f;
    }

    int pl = lane & 15, g = lane >> 4;
    int obi = wv;
    f32x4 acc[2];
    acc[0] = (f32x4){0.f, 0.f, 0.f, 0.f};
    acc[1] = (f32x4){0.f, 0.f, 0.f, 0.f};
    const half8* wb = Wp2 + obi * 64 + lane;

    #define OSTAGE(kh)                                                        \
        { int hh_ = h + (kh) - 1;                                            \
          bool okh_ = (unsigned)hh_ < 32u;                                   \
          for (int u = wv; u < 12; u += 6) {                                 \
              int nbw = u >> 2, oct = u & 3;                                 \
              int wj = w + nbw - 1;                                          \
              int di = oct * 8 + (lane >> 3);                                \
              bool ok = okh_ & ((unsigned)wj < 32u);                         \
              half8 vv = (half8)(_Float16)0.f;                               \
              if (ok) vv = *(const half8*)(aTh +                             \
                  ((size_t)((((hh_ << 5) + wj) << 5) + di)) * 64 + co8);     \
              *(half8*)&S2[((kh) & 1) * SB + (nbw * 34 + 1 + di) * 72 + co8] \
                  = vv;                                                      \
          } }

    #define OCOMP(kh)                                                        \
        { const _Float16* sb = &S2[((kh) & 1) * SB + pl * 72 + g * 8];       \
          _Pragma("unroll")                                                  \
          for (int kk = 0; kk < 18; ++kk) {                                  \
              int kglob = (kh) * 9 + (kk >> 1);                              \
              int kw3 = (kglob / 3) % 3, kd = kglob % 3;                     \
              half8 af = wb[(size_t)((kh) * 18 + kk) * 384];                 \
              _Pragma("unroll")                                              \
              for (int pt = 0; pt < 2; ++pt) {                               \
                  int row = kw3 * 34 + pt * 16 + kd;                         \
                  half8 bf = *(const half8*)(sb + row * 72 + (kk & 1) * 32); \
                  acc[pt] = __builtin_amdgcn_mfma_f32_16x16x32_f16(          \
                                af, bf, acc[pt], 0, 0, 0);                   \
              }                                                              \
          } }

    OSTAGE(0)
    __syncthreads();
    OSTAGE(1)
    OCOMP(0)
    __syncthreads();
    OSTAGE(2)
    OCOMP(1)
    __syncthreads();
    OCOMP(2)
    #undef OSTAGE
    #undef OCOMP

    __syncthreads();                                 // S2 -> TFh alias switch
    #pragma unroll
    for (int pt = 0; pt < 2; ++pt) {
        int pos = pt * 16 + pl;
        #pragma unroll
        for (int r = 0; r < 4; ++r) {
            int o = obi * 16 + g * 4 + r;
            if (o < 81) {
                int slot = (o / 3) * 4 + o % 3;
                TFh[pos * 108 + slot] = (_Float16)(acc[pt][r] + obias[o]);
            }
        }
    }
    __syncthreads();
    for (int u = t; u < 864; u += 384) {             // 32 rows x 27 half4
        int row = u / 27, q = u - row * 27;
        half4 v = *(const half4*)&TFh[row * 108 + q * 4];
        *(half4*)&OFFn[(size_t)(n0 + row) * 108 + q * 4] = v;
    }
}

// ---------------------------------------------------------------------------
// K6: deformable gather + MFMA GEMM, 32-position blocks, 6 K-chunks of <=5
// taps (S 21 KB; total LDS 31.4 KB -> 5 blocks/CU).  OFFn f16 reads.
// Invalid corners aim at the clamped tap base row (keeps TA window tight).
__global__ __launch_bounds__(256) void k_deform(const _Float16* __restrict__ aTh,
        const _Float16* __restrict__ OFFn, const half8* __restrict__ Wp,
        const float* __restrict__ db, _Float16* __restrict__ dcnT) {
    __shared__ __align__(16) _Float16 S[32 * 328];     // 20992 B (5 taps max)
    __shared__ __align__(16) _Float16 TPF[864 * 4];    // 6912 B {rh,rw,rd,_}
    __shared__ int TPv[864];                           // 3456 B (total 31360)
    int t = threadIdx.x;
    int bid = blockIdx.x;
    int blk = (bid & 7) * 128 + (bid >> 3);  // 1024 blocks, n-slabs per XCD
    int n0 = blk * 32;
    int lane = t & 63, wv = t >> 6;

    for (int idx = t; idx < 864; idx += 256) {        // Phase A: 27k x 32p
        int p = idx & 31, k = idx >> 5;
        int n = n0 + p;
        int h = n >> 10, w = (n >> 5) & 31, d = n & 31;
        half4 ov4 = *(const half4*)&OFFn[(size_t)n * 108 + k * 4];
        float ph = (float)(h + k / 9 - 1)       + (float)ov4[0];
        float pw = (float)(w + (k / 3) % 3 - 1) + (float)ov4[1];
        float pd = (float)(d + k % 3 - 1)       + (float)ov4[2];
        float fh = floorf(ph), fw = floorf(pw), fd = floorf(pd);
        int ih = (int)fh, iw = (int)fw, id = (int)fd;
        int nb0 = ih * 1024 + iw * 32 + id;
        int mask = 0;
        #pragma unroll
        for (int cb = 0; cb < 8; ++cb) {
            int hh = ih + ((cb >> 2) & 1);
            int wq = iw + ((cb >> 1) & 1);
            int dq = id + (cb & 1);
            bool ok = ((unsigned)hh < 32u) & ((unsigned)wq < 32u) & ((unsigned)dq < 32u);
            mask |= (ok ? 1 : 0) << cb;
        }
        TPv[idx] = ((nb0 + 4096) << 8) | mask;
        half4 f;
        f[0] = (_Float16)(ph - fh);
        f[1] = (_Float16)(pw - fw);
        f[2] = (_Float16)(pd - fd);
        f[3] = (_Float16)0.f;
        *(half4*)&TPF[idx * 4] = f;
    }
    __syncthreads();

    int p8 = lane >> 3, co = lane & 7;
    int pl = lane & 15, g = lane >> 4;
    f32x4 acc[2];
    acc[0] = (f32x4){0.f, 0.f, 0.f, 0.f};
    acc[1] = (f32x4){0.f, 0.f, 0.f, 0.f};
    const half8* wbase = Wp + wv * 64 + lane;
    const _Float16* sbase0 = &S[pl * 328 + g * 8];
    const _Float16* sbase1 = &S[(16 + pl) * 328 + g * 8];

    #define DCHUNK(T0, NT)                                                   \
        for (int u = wv; u < (NT) * 4; u += 4) {                             \
            int kk = u >> 2, pg = u & 3;                                     \
            int p = pg * 8 + p8;                                             \
            int tap = ((T0) + kk) * 32 + p;                                  \
            int v = TPv[tap];                                                \
            int nb = (v >> 8) - 4096, mask = v & 255;                        \
            int snb = nb < 0 ? 0 : (nb > 32767 ? 32767 : nb);                \
            half4 f = *(const half4*)&TPF[tap * 4];                          \
            _Float16 one = (_Float16)1.f;                                    \
            _Float16 rh = f[0], rw = f[1], rd = f[2];                        \
            _Float16 h0 = one - rh, w0 = one - rw, d0 = one - rd;            \
            _Float16 t00 = h0 * w0, t01 = h0 * rw;                           \
            _Float16 t10 = rh * w0, t11 = rh * rw;                           \
            half2v a0 = (half2v)0, a1 = (half2v)0, a2 = (half2v)0,           \
                   a3 = (half2v)0;                                           \
            _Pragma("unroll")                                                \
            for (int i = 0; i < 8; ++i) {                                    \
                int nn = nb + ((i >> 2) & 1) * 1024 + ((i >> 1) & 1) * 32    \
                       + (i & 1);                                            \
                bool okc = (mask >> i) & 1;                                  \
                size_t ad = (size_t)(okc ? nn : snb) << 6;                   \
                half8 vv = *(const half8*)(aTh + ad + (co << 3));            \
                _Float16 txy = (i & 4) ? ((i & 2) ? t11 : t10)               \
                                       : ((i & 2) ? t01 : t00);              \
                _Float16 wg = txy * ((i & 1) ? rd : d0);                     \
                wg = okc ? wg : (_Float16)0.f;                               \
                half2v wg2 = {wg, wg};                                       \
                a0 += (half2v){vv[0], vv[1]} * wg2;                          \
                a1 += (half2v){vv[2], vv[3]} * wg2;                          \
                a2 += (half2v){vv[4], vv[5]} * wg2;                          \
                a3 += (half2v){vv[6], vv[7]} * wg2;                          \
            }                                                                \
            half8 r;                                                         \
            r[0] = a0[0]; r[1] = a0[1]; r[2] = a1[0]; r[3] = a1[1];          \
            r[4] = a2[0]; r[5] = a2[1]; r[6] = a3[0]; r[7] = a3[1];          \
            *(half8*)&S[p * 328 + kk * 64 + (co << 3)] = r;                  \
        }                                                                    \
        __syncthreads();                                                     \
        _Pragma("unroll")                                                    \
        for (int kb = 0; kb < (NT) * 2; ++kb) {                              \
            half8 af = wbase[(size_t)(2 * (T0) + kb) * 256];                 \
            half8 bf0 = *(const half8*)(sbase0 + kb * 32);                   \
            half8 bf1 = *(const half8*)(sbase1 + kb * 32);                   \
            acc[0] = __builtin_amdgcn_mfma_f32_16x16x32_f16(af, bf0,         \
                         acc[0], 0, 0, 0);                                   \
            acc[1] = __builtin_amdgcn_mfma_f32_16x16x32_f16(af, bf1,         \
                         acc[1], 0, 0, 0);                                   \
        }                                                                    \
        __syncthreads();

    DCHUNK(0, 5)
    DCHUNK(5, 5)
    DCHUNK(10, 5)
    DCHUNK(15, 5)
    DCHUNK(20, 5)
    DCHUNK(25, 2)
    #undef DCHUNK

    #pragma unroll
    for (int pt = 0; pt < 2; ++pt) {
        half4 hv;
        #pragma unroll
        for (int r2 = 0; r2 < 4; ++r2) {
            int o = wv * 16 + g * 4 + r2;
            hv[r2] = (_Float16)(acc[pt][r2] + db[o]);
        }
        *(half4*)&dcnT[(size_t)(n0 + pt * 16 + pl) * 64 + wv * 16 + g * 4] = hv;
    }
}

// ---------------------------------------------------------------------------
// K7 (MFMA): a2 = conv1_w @ dcn + b ; h = U * a2 ; out = proj2_w @ h + b2 + x
__global__ __launch_bounds__(256) void k_finalm(const _Float16* __restrict__ dcnT,
        const _Float16* __restrict__ Uh, const float* __restrict__ x,
        const half8* __restrict__ Wc1, const float* __restrict__ c1b,
        const half8* __restrict__ Wp2f, const float* __restrict__ p2b,
        float* __restrict__ out) {
    __shared__ __align__(16) _Float16 Sd[64 * 72];   // 9216 B
    __shared__ __align__(16) _Float16 Sh[64 * 72];   // 9216 B
    int t = threadIdx.x;
    int n0 = blockIdx.x * 64;
    int lane = t & 63, wv = t >> 6;
    #pragma unroll
    for (int i = 0; i < 2; ++i) {
        int u = i * 256 + t;
        int nl = u >> 3, oct = u & 7;
        *(half8*)&Sd[nl * 72 + oct * 8] =
            *(const half8*)&dcnT[(size_t)(n0 + nl) * 64 + oct * 8];
    }
    __syncthreads();

    int pl = lane & 15, g = lane >> 4;
    int ob = wv;
    const half8* w1 = Wc1 + ob * 64 + lane;
    #pragma unroll
    for (int nt = 0; nt < 4; ++nt) {                 // GEMM1 + gate
        f32x4 acc4 = {0.f, 0.f, 0.f, 0.f};
        const _Float16* sb = &Sd[(nt * 16 + pl) * 72 + g * 8];
        #pragma unroll
        for (int kb = 0; kb < 2; ++kb) {
            half8 af = w1[kb * 256];
            half8 bf = *(const half8*)(sb + kb * 32);
            acc4 = __builtin_amdgcn_mfma_f32_16x16x32_f16(af, bf, acc4, 0, 0, 0);
        }
        int n = n0 + nt * 16 + pl;
        int o0 = ob * 16 + g * 4;
        float4 bb = *(const float4*)&c1b[o0];
        half4 hv;
        hv[0] = (_Float16)((float)Uh[(size_t)(o0 + 0) * NSP + n] * (acc4[0] + bb.x));
        hv[1] = (_Float16)((float)Uh[(size_t)(o0 + 1) * NSP + n] * (acc4[1] + bb.y));
        hv[2] = (_Float16)((float)Uh[(size_t)(o0 + 2) * NSP + n] * (acc4[2] + bb.z));
        hv[3] = (_Float16)((float)Uh[(size_t)(o0 + 3) * NSP + n] * (acc4[3] + bb.w));
        *(half4*)&Sh[(nt * 16 + pl) * 72 + o0] = hv;
    }
    __syncthreads();

    const half8* w2 = Wp2f + ob * 64 + lane;
    #pragma unroll
    for (int nt = 0; nt < 4; ++nt) {                 // GEMM2 + residual
        f32x4 acc4 = {0.f, 0.f, 0.f, 0.f};
        const _Float16* sb = &Sh[(nt * 16 + pl) * 72 + g * 8];
        #pragma unroll
        for (int kb = 0; kb < 2; ++kb) {
            half8 af = w2[kb * 256];
            half8 bf = *(const half8*)(sb + kb * 32);
            acc4 = __builtin_amdgcn_mfma_f32_16x16x32_f16(af, bf, acc4, 0, 0, 0);
        }
        int n = n0 + nt * 16 + pl;
        int o0 = ob * 16 + g * 4;
        float4 bb = *(const float4*)&p2b[o0];
        float4 xr = *(const float4*)&x[(size_t)n * 64 + o0];
        float4 ov;
        ov.x = acc4[0] + bb.x + xr.x;
        ov.y = acc4[1] + bb.y + xr.y;
        ov.z = acc4[2] + bb.z + xr.z;
        ov.w = acc4[3] + bb.w + xr.w;
        *(float4*)&out[(size_t)n * 64 + o0] = ov;
    }
}

// ---------------------------------------------------------------------------
extern "C" void kernel_launch(void* const* d_in, const int* in_sizes, int n_in,
                              void* d_out, int out_size, void* d_ws, size_t ws_size,
                              hipStream_t stream) {
    const float* x   = (const float*)d_in[0];
    const float* p1w = (const float*)d_in[1];
    const float* p1b = (const float*)d_in[2];
    const float* c0w = (const float*)d_in[3];
    const float* c0b = (const float*)d_in[4];
    const float* csw = (const float*)d_in[5];
    const float* csb = (const float*)d_in[6];
    const float* ofw = (const float*)d_in[7];
    const float* ofb = (const float*)d_in[8];
    const float* dcw = (const float*)d_in[9];
    const float* dcb = (const float*)d_in[10];
    const float* c1w = (const float*)d_in[11];
    const float* c1b = (const float*)d_in[12];
    const float* p2w = (const float*)d_in[13];
    const float* p2b = (const float*)d_in[14];
    float* out = (float*)d_out;

    char* ws = (char*)d_ws;
    const size_t CN2 = (size_t)NCH * NSP * 2;       // 4 MiB per [C][N] f16
    _Float16* Uh   = (_Float16*)(ws);
    _Float16* T0h  = (_Float16*)(ws + CN2);
    _Float16* T1h  = (_Float16*)(ws + 2 * CN2);
    _Float16* aTh  = (_Float16*)(ws + 3 * CN2);
    _Float16* OFFn = (_Float16*)(ws + 4 * CN2);     // [N][108] f16 = 7.08 MB
    _Float16* dcnT = (_Float16*)(ws + 4 * CN2 + (size_t)NSP * 108 * 2);
    _Float16* Wp   = dcnT + (size_t)NSP * 64;
    _Float16* Wp2  = Wp + 110592;
    _Float16* Wp1  = Wp2 + 165888;
    _Float16* Wc1  = Wp1 + 4096;
    _Float16* Wp2f = Wc1 + 4096;

    k_wpack_all<<<1128, 256, 0, stream>>>(p1w, c1w, p2w, dcw, ofw,
                                          Wp1, Wc1, Wp2f, Wp, Wp2);
    k_proj1m   <<<NSP / 64, 256, 0, stream>>>(x, (const half8*)Wp1, p1b, Uh);
    k_dw5      <<<1024, 256, 0, stream>>>(Uh, c0w, c0b, T0h);
    k_dw7      <<<768, 256, 0, stream>>>(T0h, csw, csb, T1h);
    k_tr       <<<NSP / 64, 256, 0, stream>>>(T1h, aTh);
    k_offg     <<<1024, 384, 0, stream>>>(aTh, (const half8*)Wp2, ofb, OFFn);
    k_deform   <<<1024, 256, 0, stream>>>(aTh, OFFn, (const half8*)Wp, dcb, dcnT);
    k_finalm   <<<NSP / 64, 256, 0, stream>>>(dcnT, Uh, x, (const half8*)Wc1, c1b,
                                              (const half8*)Wp2f, p2b, out);
}